// Round 9
// baseline (1139.266 us; speedup 1.0000x reference)
//
#include <hip/hip_runtime.h>
#include <hip/hip_bf16.h>

// ---------------- constants ----------------
#define Bq 32
#define Tq 16
#define Gq 512
#define NSEQ 528           // T + G
#define Cq 384
#define Hq 6
#define Sq 128
#define Kg 32              // GROUP_SIZE
#define ROWS (Bq*NSEQ)     // 16896
#define LROWS (Bq*Sq*Kg)   // 131072 local tokens

typedef unsigned short u16;
typedef short bf16x8 __attribute__((ext_vector_type(8)));   // 8 bf16 in 4 VGPRs
typedef float f32x4  __attribute__((ext_vector_type(4)));

__device__ __forceinline__ float gelu_f(float x){
    return 0.5f * x * (1.0f + erff(x * 0.70710678118654752f));
}
__device__ __forceinline__ u16 f2b(float x){
    union { float f; unsigned u; } v; v.f = x;
    return (u16)((v.u + 0x7fffu + ((v.u >> 16) & 1u)) >> 16);
}
__device__ __forceinline__ float b2f(u16 h){
    union { float f; unsigned u; } v; v.u = ((unsigned)h) << 16; return v.f;
}

// ---------------- merged prep: conv6 | conv_mask | build_ln ----------------
__global__ void __launch_bounds__(256) prep(const float* __restrict__ qkvw,
    const float* __restrict__ projw, const float* __restrict__ fc1w,
    const float* __restrict__ fc2w, const float* __restrict__ a1qkvw,
    const float* __restrict__ a1pw, u16* __restrict__ WB,
    const float* __restrict__ mask, u16* __restrict__ bias16,
    const float* __restrict__ xin, const float* __restrict__ pe,
    const float* __restrict__ gw, const float* __restrict__ bw,
    float* __restrict__ X, u16* __restrict__ out)
{
    int bid = blockIdx.x;
    if (bid < 9216){
        long i = (long)bid*256 + threadIdx.x;
        if (i >= 2359296) return;
        float v;
        if      (i <  442368) v = qkvw[i];
        else if (i <  589824) v = projw[i -  442368];
        else if (i < 1179648) v = fc1w[i -  589824];
        else if (i < 1769472) v = fc2w[i - 1179648];
        else if (i < 2211840) v = a1qkvw[i - 1769472];
        else                  v = a1pw[i - 2211840];
        WB[i] = f2b(v);
        return;
    }
    if (bid < 17408){
        long i = (long)(bid - 9216)*256 + threadIdx.x;
        if (i >= ((long)Bq*Gq*Gq >> 2)) return;
        float4 v = *(const float4*)(mask + i*4);
        ushort4 r;
        r.x = f2b(-100000.0f * v.x);
        r.y = f2b(-100000.0f * v.y);
        r.z = f2b(-100000.0f * v.z);
        r.w = f2b(-100000.0f * v.w);
        *(ushort4*)(bias16 + i*4) = r;
        return;
    }
    {
        int w = threadIdx.x >> 6, lane = threadIdx.x & 63;
        int row = (bid - 17408)*4 + w;
        if (row >= ROWS) return;
        int p = row % NSEQ; int b = row / NSEQ;
        const float* src = (p < Tq) ? (pe + (long)p*Cq)
                                    : (xin + ((long)b*Gq + (p - Tq))*Cq);
        float v[6]; float s = 0.f, s2 = 0.f;
#pragma unroll
        for (int j = 0; j < 6; j++){ float x = src[lane + 64*j]; v[j] = x; s += x; s2 += x*x; }
#pragma unroll
        for (int m = 1; m < 64; m <<= 1){ s += __shfl_xor(s, m); s2 += __shfl_xor(s2, m); }
        float mean = s * (1.f/384.f);
        float var  = s2 * (1.f/384.f) - mean*mean;
        float rs   = rsqrtf(var + 1e-5f);
        float* xrow = X + (long)row*Cq;
        u16* orow = out + (long)row*Cq;
#pragma unroll
        for (int j = 0; j < 6; j++){
            int c = lane + 64*j;
            xrow[c] = v[j];
            orow[c] = f2b((v[j] - mean) * rs * gw[c] + bw[c]);
        }
    }
}

// ---------------- LayerNorm, one wave per row, bf16 out ----------------
__global__ void __launch_bounds__(256) ln_rows(const float* __restrict__ in,
    const float* __restrict__ gw, const float* __restrict__ bw,
    u16* __restrict__ out, int rows)
{
    int w = threadIdx.x >> 6, lane = threadIdx.x & 63;
    int row = blockIdx.x*4 + w;
    if (row >= rows) return;
    const float* xr = in + (long)row*Cq;
    float v[6]; float s = 0.f, s2 = 0.f;
#pragma unroll
    for (int j = 0; j < 6; j++){ float x = xr[lane + 64*j]; v[j] = x; s += x; s2 += x*x; }
#pragma unroll
    for (int m = 1; m < 64; m <<= 1){ s += __shfl_xor(s, m); s2 += __shfl_xor(s2, m); }
    float mean = s * (1.f/384.f);
    float var  = s2 * (1.f/384.f) - mean*mean;
    float rs   = rsqrtf(var + 1e-5f);
    u16* orow = out + (long)row*Cq;
#pragma unroll
    for (int j = 0; j < 6; j++){
        int c = lane + 64*j;
        orow[c] = f2b((v[j] - mean) * rs * gw[c] + bw[c]);
    }
}

// ---------------- bf16 MFMA GEMM, no-LDS direct-fragment version ----------------
// Theory: LDS port was 5x oversubscribed vs matrix pipe (6 ds_read_b128 per
// 8 MFMA per wave). K is small and W/A tiles are L1/L2-resident, so load MFMA
// fragments straight from global (quarter-wave = 16 rows x 64B full lines),
// 2-deep software pipeline in registers, no barriers, no LDS.
// 512 threads / 8 waves (2m x 4n), 128x128 tile, acc[4][2]=32 AGPR.
__global__ void __launch_bounds__(512, 4) gemm_bf16(const u16* __restrict__ A,
    const u16* __restrict__ W, const float* __restrict__ bias,
    float* __restrict__ Cf, u16* __restrict__ Cb, int M, int N, int K, int epi)
{
    int t = threadIdx.x;
    int nx = gridDim.x;
    int nwg = nx * gridDim.y;
    int f = blockIdx.y*nx + blockIdx.x;
    int xcd = f & 7, i = f >> 3;
    int q = nwg >> 3, r = nwg & 7;
    int base = (xcd < r) ? xcd*(q+1) : r*(q+1) + (xcd - r)*q;
    int nf = base + i;
    int m0 = (nf / nx)*128, n0 = (nf % nx)*128;
    int wv = t >> 6, lane = t & 63;
    int wm = (wv >> 2)*64, wn = (wv & 3)*32;
    int fm = lane & 15;
    int fk = (lane >> 4) * 8;
    const u16* Abase = A + (long)(m0 + wm + fm)*K + fk;
    const u16* Wbase = W + (long)(n0 + wn + fm)*K + fk;
    f32x4 acc[4][2];
#pragma unroll
    for (int ii = 0; ii < 4; ii++)
#pragma unroll
        for (int j = 0; j < 2; j++) acc[ii][j] = (f32x4){0.f,0.f,0.f,0.f};

    auto LDF = [&](bf16x8* af, bf16x8* bf, int k0){
#pragma unroll
        for (int im = 0; im < 4; im++)
            af[im] = *(const bf16x8*)(Abase + (long)im*16*K + k0);
#pragma unroll
        for (int in = 0; in < 2; in++)
            bf[in] = *(const bf16x8*)(Wbase + (long)in*16*K + k0);
    };
    auto CMPF = [&](const bf16x8* af, const bf16x8* bf){
#pragma unroll
        for (int im = 0; im < 4; im++)
#pragma unroll
            for (int in = 0; in < 2; in++)
                acc[im][in] = __builtin_amdgcn_mfma_f32_16x16x32_bf16(af[im], bf[in], acc[im][in], 0, 0, 0);
    };

    bf16x8 a0[4], b0[2], a1[4], b1[2];
    LDF(a0, b0, 0);
    for (int k0 = 0; k0 < K; k0 += 64){
        if (k0 + 32 < K) LDF(a1, b1, k0 + 32);
        CMPF(a0, b0);
        if (k0 + 64 < K) LDF(a0, b0, k0 + 64);
        CMPF(a1, b1);
    }

    int lr = lane >> 4, lc = lane & 15;
#pragma unroll
    for (int im = 0; im < 4; im++){
#pragma unroll
        for (int in = 0; in < 2; in++){
#pragma unroll
            for (int r2 = 0; r2 < 4; r2++){
                int m = m0 + wm + im*16 + lr*4 + r2;
                int n = n0 + wn + in*16 + lc;
                float v = acc[im][in][r2];
                if (epi >= 1 && bias) v += bias[n];
                if (epi == 2) v = gelu_f(v);
                long off = (long)m*N + n;
                if (epi == 3) v += Cf[off];
                if (epi == 2 || epi == 4) Cb[off] = f2b(v);
                else                      Cf[off] = v;
            }
        }
    }
}

// ---------------- local proj GEMM with fused pool epilogue (no-LDS) ----------
__global__ void __launch_bounds__(512, 4) gemm_pool(const u16* __restrict__ A,
    const u16* __restrict__ W, const float* __restrict__ bias,
    const int* __restrict__ idx, const int* __restrict__ cidx,
    const u16* __restrict__ X16, const float* __restrict__ bng,
    const float* __restrict__ bnb, float* __restrict__ vis, int K)
{
    __shared__ int idxl[128];
    __shared__ int cidxl[4];
    int t = threadIdx.x;
    int blkf = blockIdx.x;
    int xcd = blkf & 7, slot = blkf >> 3;        // 3072 -> 384 slots/xcd
    int m0 = (xcd*128 + slot/3)*128;
    int n0 = (slot % 3)*128;
    if (t < 128) idxl[t] = idx[m0 + t];
    if (t < 4)   cidxl[t] = cidx[(m0 >> 5) + t];
    int wv = t >> 6, lane = t & 63;
    int wm = (wv >> 2)*64, wn = (wv & 3)*32;
    int fm = lane & 15;
    int fk = (lane >> 4) * 8;
    const u16* Abase = A + (long)(m0 + wm + fm)*K + fk;
    const u16* Wbase = W + (long)(n0 + wn + fm)*K + fk;
    f32x4 acc[4][2];
#pragma unroll
    for (int ii = 0; ii < 4; ii++)
#pragma unroll
        for (int j = 0; j < 2; j++) acc[ii][j] = (f32x4){0.f,0.f,0.f,0.f};

    auto LDF = [&](bf16x8* af, bf16x8* bf, int k0){
#pragma unroll
        for (int im = 0; im < 4; im++)
            af[im] = *(const bf16x8*)(Abase + (long)im*16*K + k0);
#pragma unroll
        for (int in = 0; in < 2; in++)
            bf[in] = *(const bf16x8*)(Wbase + (long)in*16*K + k0);
    };
    auto CMPF = [&](const bf16x8* af, const bf16x8* bf){
#pragma unroll
        for (int im = 0; im < 4; im++)
#pragma unroll
            for (int in = 0; in < 2; in++)
                acc[im][in] = __builtin_amdgcn_mfma_f32_16x16x32_bf16(af[im], bf[in], acc[im][in], 0, 0, 0);
    };

    bf16x8 a0[4], b0[2], a1[4], b1[2];
    LDF(a0, b0, 0);
    for (int k0 = 0; k0 < K; k0 += 64){
        if (k0 + 32 < K) LDF(a1, b1, k0 + 32);
        CMPF(a0, b0);
        if (k0 + 64 < K) LDF(a0, b0, k0 + 64);
        CMPF(a1, b1);
    }
    __syncthreads();                  // idxl/cidxl visible for the epilogue

    int lr = lane >> 4, lc = lane & 15;
#pragma unroll
    for (int in = 0; in < 2; in++){
        int c = n0 + wn + in*16 + lc;
        float pb = bias[c];
        float bg = bng[c], bb = bnb[c];
#pragma unroll
        for (int gl = 0; gl < 2; gl++){
            float vmax = -3e38f, vsum = 0.f;
#pragma unroll
            for (int i2 = 0; i2 < 2; i2++){
                int im = gl*2 + i2;
#pragma unroll
                for (int r = 0; r < 4; r++){
                    int rl = wm + im*16 + lr*4 + r;
                    float val = acc[im][in][r] + pb + b2f(X16[(long)idxl[rl]*Cq + c]);
                    vmax = fmaxf(vmax, val); vsum += val;
                }
            }
            vmax = fmaxf(vmax, __shfl_xor(vmax, 16)); vsum += __shfl_xor(vsum, 16);
            vmax = fmaxf(vmax, __shfl_xor(vmax, 32)); vsum += __shfl_xor(vsum, 32);
            if (lane < 16){
                int glb = (wm >> 5) + gl;
                float lcv = vmax + vsum*(1.f/32.f);
                float u = gelu_f(lcv*bg*0.9999950000374997f + bb);
                vis[((long)(m0 >> 5) + glb)*Cq + c] =
                    u + 0.4f*b2f(X16[(long)cidxl[glb]*Cq + c]);
            }
        }
    }
}

// ---------------- flash-style MFMA global attention v4 ----------------
// Register-prefetch staging + 2 barriers/iter + V column XOR swizzle.
__global__ void __launch_bounds__(256) attn_mfma(const u16* __restrict__ QKVg,
    const u16* __restrict__ bias16, u16* __restrict__ out)
{
    __shared__ u16 Ks[32*72];
    __shared__ u16 Vt[64*40];
    __shared__ u16 Bs[64*36];
    __shared__ u16 Pb[4][16*40];
    int blk = blockIdx.x;
    int xcd = blk & 7; int r0 = blk >> 3;
    int bb = r0 & 3;  int rr = r0 >> 2;
    int h = rr % 6;   int qt = rr / 6;
    int b = xcd + 8*bb;
    int t = threadIdx.x; int w = t >> 6; int lane = t & 63;
    int fr  = lane & 15;
    int fko = (lane >> 4) * 8;
    int colj = lane & 15;
    int rgrp = (lane >> 4) * 4;
    int qb0 = qt*64;
    int q0 = qb0 + w*16;

    int qr = q0 + fr; int qrc = qr < NSEQ ? qr : NSEQ-1;
    const u16* qbase = QKVg + (long)(b*NSEQ + qrc)*1152 + h*64;
    bf16x8 aq0 = *(const bf16x8*)(qbase + fko);
    bf16x8 aq1 = *(const bf16x8*)(qbase + 32 + fko);

    f32x4 oacc[4];
#pragma unroll
    for (int d = 0; d < 4; d++) oacc[d] = (f32x4){0.f,0.f,0.f,0.f};
    float lsum[4] = {0.f, 0.f, 0.f, 0.f};

    int skey = t >> 3;
    int sd8  = (t & 7) * 8;
    int jswz = skey ^ ((t & 3) << 3);      // (d>>3)&3 == t&3 for this thread
    int brow = t >> 2;
    int bc8  = (t & 3) * 8;

    bf16x8 kvR = {0,0,0,0,0,0,0,0}, vvR = {0,0,0,0,0,0,0,0};
    uint4  bzR = make_uint4(0u,0u,0u,0u);
    auto LD = [&](int kc){
        int j = kc*32 + skey;
        bf16x8 kv = {0,0,0,0,0,0,0,0};
        bf16x8 vv = {0,0,0,0,0,0,0,0};
        if (j < NSEQ){
            const u16* kb = QKVg + (long)(b*NSEQ + j)*1152 + 384 + h*64 + sd8;
            kv = *(const bf16x8*)kb;
            vv = *(const bf16x8*)(kb + 384);
        }
        int qi = qb0 + brow;
        int jj = kc*32 + bc8;
        uint4 bz = make_uint4(0u,0u,0u,0u);
        if (qi < Gq && jj < Gq)
            bz = *(const uint4*)(bias16 + ((long)b*Gq + qi)*Gq + jj);
        kvR = kv; vvR = vv; bzR = bz;
    };
    LD(0);

    for (int kc = 0; kc < 17; kc++){
        __syncthreads();               // prev PV done -> safe to overwrite stage
        *(bf16x8*)&Ks[skey*72 + sd8] = kvR;
#pragma unroll
        for (int e = 0; e < 8; e++) Vt[(sd8+e)*40 + jswz] = (u16)vvR[e];
        *(uint4*)&Bs[brow*36 + bc8] = bzR;
        if (kc < 16) LD(kc + 1);       // prefetch: in flight during compute
        __syncthreads();               // staged tile visible

        f32x4 s[2];
#pragma unroll
        for (int sub = 0; sub < 2; sub++){
            bf16x8 bk0 = *(const bf16x8*)&Ks[(sub*16 + fr)*72 + fko];
            bf16x8 bk1 = *(const bf16x8*)&Ks[(sub*16 + fr)*72 + 32 + fko];
            f32x4 z = (f32x4){0.f,0.f,0.f,0.f};
            z = __builtin_amdgcn_mfma_f32_16x16x32_bf16(aq0, bk0, z, 0, 0, 0);
            z = __builtin_amdgcn_mfma_f32_16x16x32_bf16(aq1, bk1, z, 0, 0, 0);
            s[sub] = z;
        }
#pragma unroll
        for (int sub = 0; sub < 2; sub++){
#pragma unroll
            for (int r = 0; r < 4; r++){
                int jj = kc*32 + sub*16 + colj;
                float sv = s[sub][r] * 0.125f
                         + b2f(Bs[(w*16 + rgrp + r)*36 + sub*16 + colj]);
                if (jj >= NSEQ) sv = -1e30f;
                float e = __expf(sv);
                lsum[r] += e;
                Pb[w][(rgrp + r)*40 + sub*16 + colj] = f2b(e);
            }
        }
        // no barrier: Pb[w] written and read by the same wave.
        bf16x8 ap = *(const bf16x8*)&Pb[w][fr*40 + fko];
#pragma unroll
        for (int d = 0; d < 4; d++){
            int D = d*16 + fr;
            int fkv = fko ^ (((D >> 3) & 3) << 3);
            bf16x8 bv = *(const bf16x8*)&Vt[D*40 + fkv];
            oacc[d] = __builtin_amdgcn_mfma_f32_16x16x32_bf16(ap, bv, oacc[d], 0, 0, 0);
        }
    }
#pragma unroll
    for (int r = 0; r < 4; r++){
#pragma unroll
        for (int mm = 1; mm < 16; mm <<= 1) lsum[r] += __shfl_xor(lsum[r], mm);
    }
#pragma unroll
    for (int r = 0; r < 4; r++){
        int qi = q0 + rgrp + r;
        if (qi < NSEQ){
            float inv = 1.0f / lsum[r];
#pragma unroll
            for (int d = 0; d < 4; d++)
                out[((long)(b*NSEQ + qi))*Cq + h*64 + d*16 + colj] = f2b(oacc[d][r]*inv);
        }
    }
}

// ---------------- fused adapter (one wave per row) ----------------
__global__ void __launch_bounds__(256) adapter_fused(const float* __restrict__ xfn,
    const float* __restrict__ resid,
    const float* __restrict__ dw, const float* __restrict__ db,
    const float* __restrict__ uw, const float* __restrict__ ub,
    const float* __restrict__ gatep,
    const float* __restrict__ lng, const float* __restrict__ lnb,
    float* __restrict__ Xout, u16* __restrict__ x16out,
    u16* __restrict__ ln16, int rows)
{
    int w = threadIdx.x >> 6, lane = threadIdx.x & 63;
    int row = blockIdx.x*4 + w;
    if (row >= rows) return;
    const float* xr = xfn + (long)row*Cq;
    float xv[6];
#pragma unroll
    for (int j = 0; j < 6; j++) xv[j] = xr[lane + 64*j];
    float hid[16];
#pragma unroll
    for (int r = 0; r < 16; r++){
        const float* dr = dw + r*Cq;
        float p = 0.f;
#pragma unroll
        for (int j = 0; j < 6; j++) p += xv[j]*dr[lane + 64*j];
#pragma unroll
        for (int mm = 1; mm < 64; mm <<= 1) p += __shfl_xor(p, mm);
        hid[r] = gelu_f(p + db[r]);
    }
    float gate = gatep ? gatep[0] : 1.0f;
    float ov[6];
    float s = 0.f, s2 = 0.f;
#pragma unroll
    for (int j = 0; j < 6; j++){
        int c = lane + 64*j;
        const float* uc = uw + c*16;
        float a = 0.f;
#pragma unroll
        for (int r = 0; r < 16; r++) a += hid[r]*uc[r];
        float v = gate * (a + ub[c] + xv[j]);
        if (resid) v += resid[(long)row*Cq + c];
        ov[j] = v;
        Xout[(long)row*Cq + c] = v;
        if (x16out) x16out[(long)row*Cq + c] = f2b(v);
        s += v; s2 += v*v;
    }
    if (lng){
#pragma unroll
        for (int m = 1; m < 64; m <<= 1){ s += __shfl_xor(s, m); s2 += __shfl_xor(s2, m); }
        float mean = s * (1.f/384.f);
        float var  = s2 * (1.f/384.f) - mean*mean;
        float rs   = rsqrtf(var + 1e-5f);
        u16* orow = ln16 + (long)row*Cq;
#pragma unroll
        for (int j = 0; j < 6; j++){
            int c = lane + 64*j;
            orow[c] = f2b((ov[j] - mean)*rs*lng[c] + lnb[c]);
        }
    }
}

// ---------------- local branch: MFMA attention, 1 group / 256-thr block ------
__global__ void __launch_bounds__(256) local_attn(const u16* __restrict__ QKVg,
    const int* __restrict__ idx, u16* __restrict__ aout16)
{
    __shared__ u16 Qs[32*72];
    __shared__ u16 Ksm[32*72];
    __shared__ u16 Vt[64*40];
    __shared__ float sc[32*36];
    __shared__ u16 Pa[32*40];
    __shared__ float linv[32];
    __shared__ int rows[32];
    int g = blockIdx.x;
    int t = threadIdx.x;
    int w = t >> 6, lane = t & 63;
    if (t < 32) rows[t] = idx[g*Kg + t];
    __syncthreads();
    int srow = t & 31;
    int d8   = (t >> 5) * 8;
    int jswz = srow ^ (((t >> 5) & 3) << 3);   // (d>>3)&3 == (t>>5)&3
    int fr = lane & 15, fko = (lane >> 4)*8;
    int colj = lane & 15, rgrp = (lane >> 4)*4;
    int it = w >> 1, jt = w & 1;
    int smrow = w*8 + (lane >> 3);
    int smc   = (lane & 7) * 4;

    const u16* rbase = QKVg + (long)rows[srow]*1152 + d8;
    bf16x8 qvR = *(const bf16x8*)(rbase);
    bf16x8 kvR = *(const bf16x8*)(rbase + 384);
    bf16x8 vvR = *(const bf16x8*)(rbase + 768);

    for (int h = 0; h < Hq; h++){
        *(bf16x8*)&Qs[srow*72 + d8]  = qvR;
        *(bf16x8*)&Ksm[srow*72 + d8] = kvR;
#pragma unroll
        for (int e = 0; e < 8; e++) Vt[(d8+e)*40 + jswz] = (u16)vvR[e];
        if (h < Hq-1){
            const u16* nb = rbase + (h+1)*64;
            qvR = *(const bf16x8*)(nb);
            kvR = *(const bf16x8*)(nb + 384);
            vvR = *(const bf16x8*)(nb + 768);
        }
        __syncthreads();
        {
            bf16x8 a0 = *(const bf16x8*)&Qs[(it*16+fr)*72 + fko];
            bf16x8 a1 = *(const bf16x8*)&Qs[(it*16+fr)*72 + 32 + fko];
            bf16x8 b0 = *(const bf16x8*)&Ksm[(jt*16+fr)*72 + fko];
            bf16x8 b1 = *(const bf16x8*)&Ksm[(jt*16+fr)*72 + 32 + fko];
            f32x4 z = (f32x4){0.f,0.f,0.f,0.f};
            z = __builtin_amdgcn_mfma_f32_16x16x32_bf16(a0, b0, z, 0, 0, 0);
            z = __builtin_amdgcn_mfma_f32_16x16x32_bf16(a1, b1, z, 0, 0, 0);
#pragma unroll
            for (int r = 0; r < 4; r++)
                sc[(it*16 + rgrp + r)*36 + jt*16 + colj] = z[r]*0.125f;
        }
        __syncthreads();
        {
            float4 s4 = *(const float4*)&sc[smrow*36 + smc];
            float mx = fmaxf(fmaxf(s4.x, s4.y), fmaxf(s4.z, s4.w));
#pragma unroll
            for (int mm = 1; mm < 8; mm <<= 1) mx = fmaxf(mx, __shfl_xor(mx, mm));
            float p0 = __expf(s4.x - mx), p1 = __expf(s4.y - mx);
            float p2 = __expf(s4.z - mx), p3 = __expf(s4.w - mx);
            float sm = p0 + p1 + p2 + p3;
#pragma unroll
            for (int mm = 1; mm < 8; mm <<= 1) sm += __shfl_xor(sm, mm);
            if ((lane & 7) == 0) linv[smrow] = 1.0f / sm;
            Pa[smrow*40 + smc + 0] = f2b(p0);
            Pa[smrow*40 + smc + 1] = f2b(p1);
            Pa[smrow*40 + smc + 2] = f2b(p2);
            Pa[smrow*40 + smc + 3] = f2b(p3);
        }
        __syncthreads();
        {
            bf16x8 ap = *(const bf16x8*)&Pa[(it*16+fr)*40 + fko];
#pragma unroll
            for (int dd = 0; dd < 2; dd++){
                int dt = jt + dd*2;
                int D = dt*16 + fr;
                int fkv = fko ^ (((D >> 3) & 3) << 3);
                bf16x8 bv = *(const bf16x8*)&Vt[D*40 + fkv];
                f32x4 o = (f32x4){0.f,0.f,0.f,0.f};
                o = __builtin_amdgcn_mfma_f32_16x16x32_bf16(ap, bv, o, 0, 0, 0);
#pragma unroll
                for (int r = 0; r < 4; r++){
                    int row = it*16 + rgrp + r;
                    aout16[((long)(g*32 + row))*Cq + h*64 + dt*16 + colj] =
                        f2b(o[r] * linv[row]);
                }
            }
        }
        __syncthreads();
    }
}

// ---------------- inverse-distance interp: 8 points/block share vis reads ----
__global__ void __launch_bounds__(128) interp_k(const float* __restrict__ Xf,
    const float* __restrict__ vis, const float* __restrict__ c1,
    const float* __restrict__ c2, float* __restrict__ newx)
{
    __shared__ float wsh[8*128];
    __shared__ float inv8[8];
    int blk = blockIdx.x;
    int b = blk >> 6, nt = blk & 63;
    int tid = threadIdx.x;
#pragma unroll
    for (int i = 0; i < 8; i++){
        int id = tid + i*128;
        int nl = id >> 7, s = id & 127;
        const float* p1 = c1 + ((long)b*Gq + nt*8 + nl)*3;
        const float* p2 = c2 + ((long)b*Sq + s)*3;
        float x1 = p1[0], y1 = p1[1], z1 = p1[2];
        float x2 = p2[0], y2 = p2[1], z2 = p2[2];
        float d = (x1*x1 + y1*y1 + z1*z1) + (x2*x2 + y2*y2 + z2*z2)
                - 2.f*(x1*x2 + y1*y2 + z1*z2);
        wsh[nl*128 + s] = 1.f/(d + 1e-8f);
    }
    __syncthreads();
    if (tid < 8){
        float sum = 0.f;
        for (int s = 0; s < Sq; s++) sum += wsh[tid*128 + s];
        inv8[tid] = 1.f/sum;
    }
    __syncthreads();
    float acc[8][3];
#pragma unroll
    for (int n = 0; n < 8; n++){ acc[n][0] = 0.f; acc[n][1] = 0.f; acc[n][2] = 0.f; }
    const float* vb = vis + (long)b*Sq*Cq + tid;
    for (int s = 0; s < Sq; s++){
        float v0 = vb[s*Cq], v1 = vb[s*Cq + 128], v2 = vb[s*Cq + 256];
#pragma unroll
        for (int n = 0; n < 8; n++){
            float wq = wsh[n*128 + s];
            acc[n][0] += wq*v0; acc[n][1] += wq*v1; acc[n][2] += wq*v2;
        }
    }
#pragma unroll
    for (int n = 0; n < 8; n++){
        int gn = nt*8 + n;
        const float* xr = Xf + ((long)(b*NSEQ + Tq + gn))*Cq;
        float* orow = newx + ((long)(b*Gq + gn))*Cq;
        float sf = 0.4f * inv8[n];
        orow[tid]       = xr[tid]       + sf*acc[n][0];
        orow[tid + 128] = xr[tid + 128] + sf*acc[n][1];
        orow[tid + 256] = xr[tid + 256] + sf*acc[n][2];
    }
}

// ---------------- launch ----------------
extern "C" void kernel_launch(void* const* d_in, const int* in_sizes, int n_in,
                              void* d_out, int out_size, void* d_ws, size_t ws_size,
                              hipStream_t stream)
{
    const float* x_in  = (const float*)d_in[0];
    const float* mask  = (const float*)d_in[1];
    const float* c1p   = (const float*)d_in[2];
    const float* c2p   = (const float*)d_in[3];
    const float* pe    = (const float*)d_in[5];
    const float* n1g   = (const float*)d_in[6];
    const float* n1b   = (const float*)d_in[7];
    const float* qkvw  = (const float*)d_in[8];
    const float* projw = (const float*)d_in[9];
    const float* projb = (const float*)d_in[10];
    const float* n2g   = (const float*)d_in[11];
    const float* n2b   = (const float*)d_in[12];
    const float* fc1w  = (const float*)d_in[13];
    const float* fc1b  = (const float*)d_in[14];
    const float* fc2w  = (const float*)d_in[15];
    const float* fc2b  = (const float*)d_in[16];
    const float* gate  = (const float*)d_in[17];
    const float* addw  = (const float*)d_in[18];
    const float* addb  = (const float*)d_in[19];
    const float* aduw  = (const float*)d_in[20];
    const float* adub  = (const float*)d_in[21];
    const float* ad1dw = (const float*)d_in[22];
    const float* ad1db = (const float*)d_in[23];
    const float* ad1uw = (const float*)d_in[24];
    const float* ad1ub = (const float*)d_in[25];
    const float* bng   = (const float*)d_in[26];
    const float* bnb   = (const float*)d_in[27];
    const float* a1qkvw= (const float*)d_in[28];
    const float* a1pw  = (const float*)d_in[29];
    const float* a1pb  = (const float*)d_in[30];
    const float* n3g   = (const float*)d_in[31];
    const float* n3b   = (const float*)d_in[32];
    const int*   idxp  = (const int*)d_in[33];
    const int*   cidxp = (const int*)d_in[34];

    // ---- workspace layout (bytes), total 252.4 MB ----
    char* w = (char*)d_ws;
    float* X    = (float*)w;                       // 16896x384 f32   [0, 25952256)
    u16*   WB   = (u16*)(w + 25952256);            // bf16 weights
    u16*   Bb16 = (u16*)(w + 30670848);            // 16896x384 bf16
    char*  R1   = w + 43646976;                    // 100663296 B (bias16 / hid16 / aout16)
    char*  R2   = R1 + 100663296;                  // 100663296 B (QKVg/C1/newx + X16)
    float* V    = (float*)(R2 + 100663296);        // 4096x384 f32

    u16* qkvw16  = WB;
    u16* projw16 = WB +  442368;
    u16* fc1w16  = WB +  589824;
    u16* fc2w16  = WB + 1179648;
    u16* a1qkv16 = WB + 1769472;
    u16* a1pw16  = WB + 2211840;

    u16*   bias16 = (u16*)R1;       // 32x512x512 bf16 (dead before fc1)
    u16*   hid16  = (u16*)R1;       // 16896x1536 bf16 (MLP phase)
    u16*   aout16 = (u16*)R1;       // 131072x384 bf16 (local phase)
    u16*   QKVg   = (u16*)R2;       // 16896x1152 bf16 [R2, R2+38.9MB)
    float* C1     = (float*)R2;     // 16896x384 f32 x_fn (dead after adapter#1)
    float* newx   = (float*)R2;     // 16384x384 f32 (interp out; QKVg dead then)
    u16*   X16    = (u16*)(R2 + 41943040);  // 16896x384 bf16 [40MB, 53MB) of R2

    prep<<<21632, 256, 0, stream>>>(qkvw, projw, fc1w, fc2w, a1qkvw, a1pw, WB,
                                    mask, bias16, x_in, pe, n1g, n1b, X, Bb16);
    gemm_bf16<<<dim3(9, 132), 512, 0, stream>>>(Bb16, qkvw16, nullptr, nullptr, QKVg,
                                                ROWS, 1152, Cq, 4);
    attn_mfma<<<1728, 256, 0, stream>>>(QKVg, bias16, Bb16);
    gemm_bf16<<<dim3(3, 132), 512, 0, stream>>>(Bb16, projw16, projb, X, nullptr,
                                                ROWS, Cq, Cq, 3);
    ln_rows<<<4224, 256, 0, stream>>>(X, n2g, n2b, Bb16, ROWS);
    gemm_bf16<<<dim3(12, 132), 512, 0, stream>>>(Bb16, fc1w16, fc1b, nullptr, hid16,
                                                 ROWS, 1536, Cq, 2);
    gemm_bf16<<<dim3(3, 132), 512, 0, stream>>>(hid16, fc2w16, fc2b, C1, nullptr,
                                                ROWS, Cq, 1536, 1);
    // fused: x = gate*adapter(x_fn)+x ; X16 = bf16(x); Bb16 = LN3(x)
    adapter_fused<<<4224, 256, 0, stream>>>(C1, X, addw, addb, aduw, adub, gate,
                                            n3g, n3b, X, X16, Bb16, ROWS);
    // local branch
    gemm_bf16<<<dim3(9, 132), 512, 0, stream>>>(Bb16, a1qkv16, nullptr, nullptr, QKVg,
                                                ROWS, 1152, Cq, 4);
    local_attn<<<4096, 256, 0, stream>>>(QKVg, idxp, aout16);
    gemm_pool<<<3072, 512, 0, stream>>>(aout16, a1pw16, a1pb, idxp, cidxp,
                                        X16, bng, bnb, V, Cq);
    interp_k<<<2048, 128, 0, stream>>>(X, V, c1p, c2p, newx);
    // fused final adapter -> d_out
    adapter_fused<<<4096, 256, 0, stream>>>(newx, nullptr, ad1dw, ad1db, ad1uw, ad1ub,
                                            nullptr, nullptr, nullptr,
                                            (float*)d_out, nullptr, nullptr, Bq*Gq);
}

// Round 10
// 789.602 us; speedup vs baseline: 1.4428x; 1.4428x over previous
//
#include <hip/hip_runtime.h>
#include <hip/hip_bf16.h>

// ---------------- constants ----------------
#define Bq 32
#define Tq 16
#define Gq 512
#define NSEQ 528           // T + G
#define Cq 384
#define Hq 6
#define Sq 128
#define Kg 32              // GROUP_SIZE
#define ROWS (Bq*NSEQ)     // 16896
#define LROWS (Bq*Sq*Kg)   // 131072 local tokens

typedef unsigned short u16;
typedef short bf16x8 __attribute__((ext_vector_type(8)));   // 8 bf16 in 4 VGPRs
typedef float f32x4  __attribute__((ext_vector_type(4)));

__device__ __forceinline__ float gelu_f(float x){
    return 0.5f * x * (1.0f + erff(x * 0.70710678118654752f));
}
__device__ __forceinline__ u16 f2b(float x){
    union { float f; unsigned u; } v; v.f = x;
    return (u16)((v.u + 0x7fffu + ((v.u >> 16) & 1u)) >> 16);
}
__device__ __forceinline__ float b2f(u16 h){
    union { float f; unsigned u; } v; v.u = ((unsigned)h) << 16; return v.f;
}

// async global->LDS, 16B per lane. dest = wave-uniform base + lane*16.
__device__ __forceinline__ void gload16(const u16* g, u16* l){
    __builtin_amdgcn_global_load_lds(
        (const __attribute__((address_space(1))) unsigned int*)(g),
        (__attribute__((address_space(3))) unsigned int*)(l), 16, 0, 0);
}

// ---------------- merged prep: weight PACK | conv_mask | build_ln ----------
// Weights are packed fragment-major: elem (n,k) of an NxK matrix goes to
// off + ((n>>4)*(K>>5) + (k>>5))*512 + (n&15)*32 + (k&31).  A wave's W-frag
// load is then one contiguous coalesced 1KB global read (no LDS for W).
__global__ void __launch_bounds__(256) prep(const float* __restrict__ qkvw,
    const float* __restrict__ projw, const float* __restrict__ fc1w,
    const float* __restrict__ fc2w, const float* __restrict__ a1qkvw,
    const float* __restrict__ a1pw, u16* __restrict__ WB,
    const float* __restrict__ mask, u16* __restrict__ bias16,
    const float* __restrict__ xin, const float* __restrict__ pe,
    const float* __restrict__ gw, const float* __restrict__ bw,
    float* __restrict__ X, u16* __restrict__ out)
{
    int bid = blockIdx.x;
    if (bid < 9216){
        long i = (long)bid*256 + threadIdx.x;
        if (i >= 2359296) return;
        const float* src; long li; int Kx; long off;
        if      (i <  442368){ src = qkvw;   li = i;           Kx = 384;  off = 0; }
        else if (i <  589824){ src = projw;  li = i -  442368; Kx = 384;  off =  442368; }
        else if (i < 1179648){ src = fc1w;   li = i -  589824; Kx = 384;  off =  589824; }
        else if (i < 1769472){ src = fc2w;   li = i - 1179648; Kx = 1536; off = 1179648; }
        else if (i < 2211840){ src = a1qkvw; li = i - 1769472; Kx = 384;  off = 1769472; }
        else                 { src = a1pw;   li = i - 2211840; Kx = 384;  off = 2211840; }
        int n = (int)(li / Kx), k = (int)(li % Kx);
        long d = off + ((long)(n >> 4)*(Kx >> 5) + (k >> 5))*512 + (n & 15)*32 + (k & 31);
        WB[d] = f2b(src[li]);
        return;
    }
    if (bid < 17408){
        long i = (long)(bid - 9216)*256 + threadIdx.x;
        if (i >= ((long)Bq*Gq*Gq >> 2)) return;
        float4 v = *(const float4*)(mask + i*4);
        ushort4 r;
        r.x = f2b(-100000.0f * v.x);
        r.y = f2b(-100000.0f * v.y);
        r.z = f2b(-100000.0f * v.z);
        r.w = f2b(-100000.0f * v.w);
        *(ushort4*)(bias16 + i*4) = r;
        return;
    }
    {
        int w = threadIdx.x >> 6, lane = threadIdx.x & 63;
        int row = (bid - 17408)*4 + w;
        if (row >= ROWS) return;
        int p = row % NSEQ; int b = row / NSEQ;
        const float* src = (p < Tq) ? (pe + (long)p*Cq)
                                    : (xin + ((long)b*Gq + (p - Tq))*Cq);
        float v[6]; float s = 0.f, s2 = 0.f;
#pragma unroll
        for (int j = 0; j < 6; j++){ float x = src[lane + 64*j]; v[j] = x; s += x; s2 += x*x; }
#pragma unroll
        for (int m = 1; m < 64; m <<= 1){ s += __shfl_xor(s, m); s2 += __shfl_xor(s2, m); }
        float mean = s * (1.f/384.f);
        float var  = s2 * (1.f/384.f) - mean*mean;
        float rs   = rsqrtf(var + 1e-5f);
        float* xrow = X + (long)row*Cq;
        u16* orow = out + (long)row*Cq;
#pragma unroll
        for (int j = 0; j < 6; j++){
            int c = lane + 64*j;
            xrow[c] = v[j];
            orow[c] = f2b((v[j] - mean) * rs * gw[c] + bw[c]);
        }
    }
}

// ---------------- LayerNorm, one wave per row, bf16 out ----------------
__global__ void __launch_bounds__(256) ln_rows(const float* __restrict__ in,
    const float* __restrict__ gw, const float* __restrict__ bw,
    u16* __restrict__ out, int rows)
{
    int w = threadIdx.x >> 6, lane = threadIdx.x & 63;
    int row = blockIdx.x*4 + w;
    if (row >= rows) return;
    const float* xr = in + (long)row*Cq;
    float v[6]; float s = 0.f, s2 = 0.f;
#pragma unroll
    for (int j = 0; j < 6; j++){ float x = xr[lane + 64*j]; v[j] = x; s += x; s2 += x*x; }
#pragma unroll
    for (int m = 1; m < 64; m <<= 1){ s += __shfl_xor(s, m); s2 += __shfl_xor(s2, m); }
    float mean = s * (1.f/384.f);
    float var  = s2 * (1.f/384.f) - mean*mean;
    float rs   = rsqrtf(var + 1e-5f);
    u16* orow = out + (long)row*Cq;
#pragma unroll
    for (int j = 0; j < 6; j++){
        int c = lane + 64*j;
        orow[c] = f2b((v[j] - mean) * rs * gw[c] + bw[c]);
    }
}

// ---------------- bf16 MFMA GEMM v2: 256x128 tile, W direct from packed ----
// LDS-read-port was the GEMM ceiling (48 b128/K-step vs 78cy MFMA -> 21%
// MfmaUtil). Two levers: (1) W-frags load straight from packed global
// (coalesced 1KB, L1-hot, parallel port to LDS); (2) 8 waves of 64x64
// (acc[4][4]) double FLOP per A-read. Only A goes through LDS (2x16KB dbuf).
// epi: 0 none->f32, 1 +bias->f32, 2 gelu(+bias)->bf16, 3 Cf+=acc+bias,
//      4 (+bias if given)->bf16
__global__ void __launch_bounds__(512, 4) gemm256(const u16* __restrict__ A,
    const u16* __restrict__ Wp, const float* __restrict__ bias,
    float* __restrict__ Cf, u16* __restrict__ Cb, int M, int N, int K, int epi)
{
    __shared__ u16 As0[256*32];
    __shared__ u16 As1[256*32];
    int t = threadIdx.x;
    int nx = gridDim.x;
    int nwg = nx * gridDim.y;
    int f = blockIdx.y*nx + blockIdx.x;
    int xcd = f & 7, i = f >> 3;
    int q = nwg >> 3, r = nwg & 7;
    int base = (xcd < r) ? xcd*(q+1) : r*(q+1) + (xcd - r)*q;
    int nf = base + i;
    int m0 = (nf / nx)*256, n0 = (nf % nx)*128;
    int wv = t >> 6, lane = t & 63;
    int wm = (wv >> 1)*64, wn = (wv & 1)*64;
    int fm = lane & 15;
    int fk = (lane >> 4) * 8;
    int fkp = (((lane >> 4) ^ ((fm >> 1) & 3)) & 3) * 8;
    int rs  = t >> 2;
    int kc8 = (((lane & 3) ^ ((lane >> 3) & 3))) * 8;
    const u16* Wbase = Wp + (long)((n0 + wn) >> 4)*K*16 + fm*32 + fk;
    f32x4 acc[4][4];
#pragma unroll
    for (int ii = 0; ii < 4; ii++)
#pragma unroll
        for (int j = 0; j < 4; j++) acc[ii][j] = (f32x4){0.f,0.f,0.f,0.f};

    auto STG = [&](u16* Ab, int k0){
        gload16(A + (long)(m0 + rs)*K + k0 + kc8, Ab + wv*512);
        gload16(A + (long)(m0 + 128 + rs)*K + k0 + kc8, Ab + 4096 + wv*512);
    };
    auto CMP = [&](const u16* Ab, int k0){
        bf16x8 af[4], bf[4];
#pragma unroll
        for (int in = 0; in < 4; in++)
            bf[in] = *(const bf16x8*)(Wbase + (long)in*K*16 + k0*16);
#pragma unroll
        for (int im = 0; im < 4; im++)
            af[im] = *(const bf16x8*)&Ab[(wm + im*16 + fm)*32 + fkp];
#pragma unroll
        for (int im = 0; im < 4; im++)
#pragma unroll
            for (int in = 0; in < 4; in++)
                acc[im][in] = __builtin_amdgcn_mfma_f32_16x16x32_bf16(af[im], bf[in], acc[im][in], 0, 0, 0);
    };

    int nt = K >> 5;                 // 12 or 48 -> always even
    STG(As0, 0);
    __syncthreads();
    for (int kt = 0; kt < nt; kt += 2){
        STG(As1, (kt+1)*32);
        CMP(As0, kt*32);
        __syncthreads();
        if (kt + 2 < nt) STG(As0, (kt+2)*32);
        CMP(As1, (kt+1)*32);
        __syncthreads();
    }

    int lr = lane >> 4, lc = lane & 15;
#pragma unroll
    for (int im = 0; im < 4; im++){
#pragma unroll
        for (int in = 0; in < 4; in++){
#pragma unroll
            for (int r2 = 0; r2 < 4; r2++){
                int m = m0 + wm + im*16 + lr*4 + r2;
                int n = n0 + wn + in*16 + lc;
                float v = acc[im][in][r2];
                if (epi >= 1 && bias) v += bias[n];
                if (epi == 2) v = gelu_f(v);
                long off = (long)m*N + n;
                if (epi == 3) v += Cf[off];
                if (epi == 2 || epi == 4) Cb[off] = f2b(v);
                else                      Cf[off] = v;
            }
        }
    }
}

// ---------------- local proj GEMM with fused pool epilogue (256-tile) -------
__global__ void __launch_bounds__(512, 4) gemm_pool(const u16* __restrict__ A,
    const u16* __restrict__ Wp, const float* __restrict__ bias,
    const int* __restrict__ idx, const int* __restrict__ cidx,
    const u16* __restrict__ X16, const float* __restrict__ bng,
    const float* __restrict__ bnb, float* __restrict__ vis, int K)
{
    __shared__ u16 As0[256*32];
    __shared__ u16 As1[256*32];
    __shared__ int idxl[256];
    __shared__ int cidxl[8];
    int t = threadIdx.x;
    int blkf = blockIdx.x;
    int xcd = blkf & 7, slot = blkf >> 3;        // 1536 -> 192 slots/xcd
    int m0 = (xcd*64 + slot/3)*256;
    int n0 = (slot % 3)*128;
    if (t < 256) idxl[t] = idx[m0 + t];
    if (t < 8)   cidxl[t] = cidx[(m0 >> 5) + t];
    int wv = t >> 6, lane = t & 63;
    int wm = (wv >> 1)*64, wn = (wv & 1)*64;
    int fm = lane & 15;
    int fk = (lane >> 4) * 8;
    int fkp = (((lane >> 4) ^ ((fm >> 1) & 3)) & 3) * 8;
    int rs  = t >> 2;
    int kc8 = (((lane & 3) ^ ((lane >> 3) & 3))) * 8;
    const u16* Wbase = Wp + (long)((n0 + wn) >> 4)*K*16 + fm*32 + fk;
    f32x4 acc[4][4];
#pragma unroll
    for (int ii = 0; ii < 4; ii++)
#pragma unroll
        for (int j = 0; j < 4; j++) acc[ii][j] = (f32x4){0.f,0.f,0.f,0.f};

    auto STG = [&](u16* Ab, int k0){
        gload16(A + (long)(m0 + rs)*K + k0 + kc8, Ab + wv*512);
        gload16(A + (long)(m0 + 128 + rs)*K + k0 + kc8, Ab + 4096 + wv*512);
    };
    auto CMP = [&](const u16* Ab, int k0){
        bf16x8 af[4], bf[4];
#pragma unroll
        for (int in = 0; in < 4; in++)
            bf[in] = *(const bf16x8*)(Wbase + (long)in*K*16 + k0*16);
#pragma unroll
        for (int im = 0; im < 4; im++)
            af[im] = *(const bf16x8*)&Ab[(wm + im*16 + fm)*32 + fkp];
#pragma unroll
        for (int im = 0; im < 4; im++)
#pragma unroll
            for (int in = 0; in < 4; in++)
                acc[im][in] = __builtin_amdgcn_mfma_f32_16x16x32_bf16(af[im], bf[in], acc[im][in], 0, 0, 0);
    };

    int nt = K >> 5;                 // K=384 -> 12
    STG(As0, 0);
    __syncthreads();
    for (int kt = 0; kt < nt; kt += 2){
        STG(As1, (kt+1)*32);
        CMP(As0, kt*32);
        __syncthreads();
        if (kt + 2 < nt) STG(As0, (kt+2)*32);
        CMP(As1, (kt+1)*32);
        __syncthreads();
    }

    int lr = lane >> 4, lc = lane & 15;
#pragma unroll
    for (int in = 0; in < 4; in++){
        int c = n0 + wn + in*16 + lc;
        float pb = bias[c];
        float bg = bng[c], bb = bnb[c];
#pragma unroll
        for (int gl = 0; gl < 2; gl++){
            float vmax = -3e38f, vsum = 0.f;
#pragma unroll
            for (int i2 = 0; i2 < 2; i2++){
                int im = gl*2 + i2;
#pragma unroll
                for (int r = 0; r < 4; r++){
                    int rl = wm + im*16 + lr*4 + r;
                    float val = acc[im][in][r] + pb + b2f(X16[(long)idxl[rl]*Cq + c]);
                    vmax = fmaxf(vmax, val); vsum += val;
                }
            }
            vmax = fmaxf(vmax, __shfl_xor(vmax, 16)); vsum += __shfl_xor(vsum, 16);
            vmax = fmaxf(vmax, __shfl_xor(vmax, 32)); vsum += __shfl_xor(vsum, 32);
            if (lane < 16){
                int glb = (wm >> 5) + gl;
                float lcv = vmax + vsum*(1.f/32.f);
                float u = gelu_f(lcv*bg*0.9999950000374997f + bb);
                vis[((long)(m0 >> 5) + glb)*Cq + c] =
                    u + 0.4f*b2f(X16[(long)cidxl[glb]*Cq + c]);
            }
        }
    }
}

// ---------------- flash-style MFMA global attention v4 ----------------
// Register-prefetch staging + 2 barriers/iter + V column XOR swizzle.
__global__ void __launch_bounds__(256) attn_mfma(const u16* __restrict__ QKVg,
    const u16* __restrict__ bias16, u16* __restrict__ out)
{
    __shared__ u16 Ks[32*72];
    __shared__ u16 Vt[64*40];
    __shared__ u16 Bs[64*36];
    __shared__ u16 Pb[4][16*40];
    int blk = blockIdx.x;
    int xcd = blk & 7; int r0 = blk >> 3;
    int bb = r0 & 3;  int rr = r0 >> 2;
    int h = rr % 6;   int qt = rr / 6;
    int b = xcd + 8*bb;
    int t = threadIdx.x; int w = t >> 6; int lane = t & 63;
    int fr  = lane & 15;
    int fko = (lane >> 4) * 8;
    int colj = lane & 15;
    int rgrp = (lane >> 4) * 4;
    int qb0 = qt*64;
    int q0 = qb0 + w*16;

    int qr = q0 + fr; int qrc = qr < NSEQ ? qr : NSEQ-1;
    const u16* qbase = QKVg + (long)(b*NSEQ + qrc)*1152 + h*64;
    bf16x8 aq0 = *(const bf16x8*)(qbase + fko);
    bf16x8 aq1 = *(const bf16x8*)(qbase + 32 + fko);

    f32x4 oacc[4];
#pragma unroll
    for (int d = 0; d < 4; d++) oacc[d] = (f32x4){0.f,0.f,0.f,0.f};
    float lsum[4] = {0.f, 0.f, 0.f, 0.f};

    int skey = t >> 3;
    int sd8  = (t & 7) * 8;
    int jswz = skey ^ ((t & 3) << 3);      // (d>>3)&3 == t&3 for this thread
    int brow = t >> 2;
    int bc8  = (t & 3) * 8;

    bf16x8 kvR = {0,0,0,0,0,0,0,0}, vvR = {0,0,0,0,0,0,0,0};
    uint4  bzR = make_uint4(0u,0u,0u,0u);
    auto LD = [&](int kc){
        int j = kc*32 + skey;
        bf16x8 kv = {0,0,0,0,0,0,0,0};
        bf16x8 vv = {0,0,0,0,0,0,0,0};
        if (j < NSEQ){
            const u16* kb = QKVg + (long)(b*NSEQ + j)*1152 + 384 + h*64 + sd8;
            kv = *(const bf16x8*)kb;
            vv = *(const bf16x8*)(kb + 384);
        }
        int qi = qb0 + brow;
        int jj = kc*32 + bc8;
        uint4 bz = make_uint4(0u,0u,0u,0u);
        if (qi < Gq && jj < Gq)
            bz = *(const uint4*)(bias16 + ((long)b*Gq + qi)*Gq + jj);
        kvR = kv; vvR = vv; bzR = bz;
    };
    LD(0);

    for (int kc = 0; kc < 17; kc++){
        __syncthreads();               // prev PV done -> safe to overwrite stage
        *(bf16x8*)&Ks[skey*72 + sd8] = kvR;
#pragma unroll
        for (int e = 0; e < 8; e++) Vt[(sd8+e)*40 + jswz] = (u16)vvR[e];
        *(uint4*)&Bs[brow*36 + bc8] = bzR;
        if (kc < 16) LD(kc + 1);       // prefetch: in flight during compute
        __syncthreads();               // staged tile visible

        f32x4 s[2];
#pragma unroll
        for (int sub = 0; sub < 2; sub++){
            bf16x8 bk0 = *(const bf16x8*)&Ks[(sub*16 + fr)*72 + fko];
            bf16x8 bk1 = *(const bf16x8*)&Ks[(sub*16 + fr)*72 + 32 + fko];
            f32x4 z = (f32x4){0.f,0.f,0.f,0.f};
            z = __builtin_amdgcn_mfma_f32_16x16x32_bf16(aq0, bk0, z, 0, 0, 0);
            z = __builtin_amdgcn_mfma_f32_16x16x32_bf16(aq1, bk1, z, 0, 0, 0);
            s[sub] = z;
        }
#pragma unroll
        for (int sub = 0; sub < 2; sub++){
#pragma unroll
            for (int r = 0; r < 4; r++){
                int jj = kc*32 + sub*16 + colj;
                float sv = s[sub][r] * 0.125f
                         + b2f(Bs[(w*16 + rgrp + r)*36 + sub*16 + colj]);
                if (jj >= NSEQ) sv = -1e30f;
                float e = __expf(sv);
                lsum[r] += e;
                Pb[w][(rgrp + r)*40 + sub*16 + colj] = f2b(e);
            }
        }
        // no barrier: Pb[w] written and read by the same wave.
        bf16x8 ap = *(const bf16x8*)&Pb[w][fr*40 + fko];
#pragma unroll
        for (int d = 0; d < 4; d++){
            int D = d*16 + fr;
            int fkv = fko ^ (((D >> 3) & 3) << 3);
            bf16x8 bv = *(const bf16x8*)&Vt[D*40 + fkv];
            oacc[d] = __builtin_amdgcn_mfma_f32_16x16x32_bf16(ap, bv, oacc[d], 0, 0, 0);
        }
    }
#pragma unroll
    for (int r = 0; r < 4; r++){
#pragma unroll
        for (int mm = 1; mm < 16; mm <<= 1) lsum[r] += __shfl_xor(lsum[r], mm);
    }
#pragma unroll
    for (int r = 0; r < 4; r++){
        int qi = q0 + rgrp + r;
        if (qi < NSEQ){
            float inv = 1.0f / lsum[r];
#pragma unroll
            for (int d = 0; d < 4; d++)
                out[((long)(b*NSEQ + qi))*Cq + h*64 + d*16 + colj] = f2b(oacc[d][r]*inv);
        }
    }
}

// ---------------- fused adapter (one wave per row) ----------------
__global__ void __launch_bounds__(256) adapter_fused(const float* __restrict__ xfn,
    const float* __restrict__ resid,
    const float* __restrict__ dw, const float* __restrict__ db,
    const float* __restrict__ uw, const float* __restrict__ ub,
    const float* __restrict__ gatep,
    const float* __restrict__ lng, const float* __restrict__ lnb,
    float* __restrict__ Xout, u16* __restrict__ x16out,
    u16* __restrict__ ln16, int rows)
{
    int w = threadIdx.x >> 6, lane = threadIdx.x & 63;
    int row = blockIdx.x*4 + w;
    if (row >= rows) return;
    const float* xr = xfn + (long)row*Cq;
    float xv[6];
#pragma unroll
    for (int j = 0; j < 6; j++) xv[j] = xr[lane + 64*j];
    float hid[16];
#pragma unroll
    for (int r = 0; r < 16; r++){
        const float* dr = dw + r*Cq;
        float p = 0.f;
#pragma unroll
        for (int j = 0; j < 6; j++) p += xv[j]*dr[lane + 64*j];
#pragma unroll
        for (int mm = 1; mm < 64; mm <<= 1) p += __shfl_xor(p, mm);
        hid[r] = gelu_f(p + db[r]);
    }
    float gate = gatep ? gatep[0] : 1.0f;
    float ov[6];
    float s = 0.f, s2 = 0.f;
#pragma unroll
    for (int j = 0; j < 6; j++){
        int c = lane + 64*j;
        const float* uc = uw + c*16;
        float a = 0.f;
#pragma unroll
        for (int r = 0; r < 16; r++) a += hid[r]*uc[r];
        float v = gate * (a + ub[c] + xv[j]);
        if (resid) v += resid[(long)row*Cq + c];
        ov[j] = v;
        Xout[(long)row*Cq + c] = v;
        if (x16out) x16out[(long)row*Cq + c] = f2b(v);
        s += v; s2 += v*v;
    }
    if (lng){
#pragma unroll
        for (int m = 1; m < 64; m <<= 1){ s += __shfl_xor(s, m); s2 += __shfl_xor(s2, m); }
        float mean = s * (1.f/384.f);
        float var  = s2 * (1.f/384.f) - mean*mean;
        float rs   = rsqrtf(var + 1e-5f);
        u16* orow = ln16 + (long)row*Cq;
#pragma unroll
        for (int j = 0; j < 6; j++){
            int c = lane + 64*j;
            orow[c] = f2b((ov[j] - mean)*rs*lng[c] + lnb[c]);
        }
    }
}

// ---------------- local branch: MFMA attention, 1 group / 256-thr block ------
__global__ void __launch_bounds__(256) local_attn(const u16* __restrict__ QKVg,
    const int* __restrict__ idx, u16* __restrict__ aout16)
{
    __shared__ u16 Qs[32*72];
    __shared__ u16 Ksm[32*72];
    __shared__ u16 Vt[64*40];
    __shared__ float sc[32*36];
    __shared__ u16 Pa[32*40];
    __shared__ float linv[32];
    __shared__ int rows[32];
    int g = blockIdx.x;
    int t = threadIdx.x;
    int w = t >> 6, lane = t & 63;
    if (t < 32) rows[t] = idx[g*Kg + t];
    __syncthreads();
    int srow = t & 31;
    int d8   = (t >> 5) * 8;
    int jswz = srow ^ (((t >> 5) & 3) << 3);   // (d>>3)&3 == (t>>5)&3
    int fr = lane & 15, fko = (lane >> 4)*8;
    int colj = lane & 15, rgrp = (lane >> 4)*4;
    int it = w >> 1, jt = w & 1;
    int smrow = w*8 + (lane >> 3);
    int smc   = (lane & 7) * 4;

    const u16* rbase = QKVg + (long)rows[srow]*1152 + d8;
    bf16x8 qvR = *(const bf16x8*)(rbase);
    bf16x8 kvR = *(const bf16x8*)(rbase + 384);
    bf16x8 vvR = *(const bf16x8*)(rbase + 768);

    for (int h = 0; h < Hq; h++){
        *(bf16x8*)&Qs[srow*72 + d8]  = qvR;
        *(bf16x8*)&Ksm[srow*72 + d8] = kvR;
#pragma unroll
        for (int e = 0; e < 8; e++) Vt[(d8+e)*40 + jswz] = (u16)vvR[e];
        if (h < Hq-1){
            const u16* nb = rbase + (h+1)*64;
            qvR = *(const bf16x8*)(nb);
            kvR = *(const bf16x8*)(nb + 384);
            vvR = *(const bf16x8*)(nb + 768);
        }
        __syncthreads();
        {
            bf16x8 a0 = *(const bf16x8*)&Qs[(it*16+fr)*72 + fko];
            bf16x8 a1 = *(const bf16x8*)&Qs[(it*16+fr)*72 + 32 + fko];
            bf16x8 b0 = *(const bf16x8*)&Ksm[(jt*16+fr)*72 + fko];
            bf16x8 b1 = *(const bf16x8*)&Ksm[(jt*16+fr)*72 + 32 + fko];
            f32x4 z = (f32x4){0.f,0.f,0.f,0.f};
            z = __builtin_amdgcn_mfma_f32_16x16x32_bf16(a0, b0, z, 0, 0, 0);
            z = __builtin_amdgcn_mfma_f32_16x16x32_bf16(a1, b1, z, 0, 0, 0);
#pragma unroll
            for (int r = 0; r < 4; r++)
                sc[(it*16 + rgrp + r)*36 + jt*16 + colj] = z[r]*0.125f;
        }
        __syncthreads();
        {
            float4 s4 = *(const float4*)&sc[smrow*36 + smc];
            float mx = fmaxf(fmaxf(s4.x, s4.y), fmaxf(s4.z, s4.w));
#pragma unroll
            for (int mm = 1; mm < 8; mm <<= 1) mx = fmaxf(mx, __shfl_xor(mx, mm));
            float p0 = __expf(s4.x - mx), p1 = __expf(s4.y - mx);
            float p2 = __expf(s4.z - mx), p3 = __expf(s4.w - mx);
            float sm = p0 + p1 + p2 + p3;
#pragma unroll
            for (int mm = 1; mm < 8; mm <<= 1) sm += __shfl_xor(sm, mm);
            if ((lane & 7) == 0) linv[smrow] = 1.0f / sm;
            Pa[smrow*40 + smc + 0] = f2b(p0);
            Pa[smrow*40 + smc + 1] = f2b(p1);
            Pa[smrow*40 + smc + 2] = f2b(p2);
            Pa[smrow*40 + smc + 3] = f2b(p3);
        }
        __syncthreads();
        {
            bf16x8 ap = *(const bf16x8*)&Pa[(it*16+fr)*40 + fko];
#pragma unroll
            for (int dd = 0; dd < 2; dd++){
                int dt = jt + dd*2;
                int D = dt*16 + fr;
                int fkv = fko ^ (((D >> 3) & 3) << 3);
                bf16x8 bv = *(const bf16x8*)&Vt[D*40 + fkv];
                f32x4 o = (f32x4){0.f,0.f,0.f,0.f};
                o = __builtin_amdgcn_mfma_f32_16x16x32_bf16(ap, bv, o, 0, 0, 0);
#pragma unroll
                for (int r = 0; r < 4; r++){
                    int row = it*16 + rgrp + r;
                    aout16[((long)(g*32 + row))*Cq + h*64 + dt*16 + colj] =
                        f2b(o[r] * linv[row]);
                }
            }
        }
        __syncthreads();
    }
}

// ---------------- inverse-distance interp: 8 points/block share vis reads ----
__global__ void __launch_bounds__(128) interp_k(const float* __restrict__ Xf,
    const float* __restrict__ vis, const float* __restrict__ c1,
    const float* __restrict__ c2, float* __restrict__ newx)
{
    __shared__ float wsh[8*128];
    __shared__ float inv8[8];
    int blk = blockIdx.x;
    int b = blk >> 6, nt = blk & 63;
    int tid = threadIdx.x;
#pragma unroll
    for (int i = 0; i < 8; i++){
        int id = tid + i*128;
        int nl = id >> 7, s = id & 127;
        const float* p1 = c1 + ((long)b*Gq + nt*8 + nl)*3;
        const float* p2 = c2 + ((long)b*Sq + s)*3;
        float x1 = p1[0], y1 = p1[1], z1 = p1[2];
        float x2 = p2[0], y2 = p2[1], z2 = p2[2];
        float d = (x1*x1 + y1*y1 + z1*z1) + (x2*x2 + y2*y2 + z2*z2)
                - 2.f*(x1*x2 + y1*y2 + z1*z2);
        wsh[nl*128 + s] = 1.f/(d + 1e-8f);
    }
    __syncthreads();
    if (tid < 8){
        float sum = 0.f;
        for (int s = 0; s < Sq; s++) sum += wsh[tid*128 + s];
        inv8[tid] = 1.f/sum;
    }
    __syncthreads();
    float acc[8][3];
#pragma unroll
    for (int n = 0; n < 8; n++){ acc[n][0] = 0.f; acc[n][1] = 0.f; acc[n][2] = 0.f; }
    const float* vb = vis + (long)b*Sq*Cq + tid;
    for (int s = 0; s < Sq; s++){
        float v0 = vb[s*Cq], v1 = vb[s*Cq + 128], v2 = vb[s*Cq + 256];
#pragma unroll
        for (int n = 0; n < 8; n++){
            float wq = wsh[n*128 + s];
            acc[n][0] += wq*v0; acc[n][1] += wq*v1; acc[n][2] += wq*v2;
        }
    }
#pragma unroll
    for (int n = 0; n < 8; n++){
        int gn = nt*8 + n;
        const float* xr = Xf + ((long)(b*NSEQ + Tq + gn))*Cq;
        float* orow = newx + ((long)(b*Gq + gn))*Cq;
        float sf = 0.4f * inv8[n];
        orow[tid]       = xr[tid]       + sf*acc[n][0];
        orow[tid + 128] = xr[tid + 128] + sf*acc[n][1];
        orow[tid + 256] = xr[tid + 256] + sf*acc[n][2];
    }
}

// ---------------- launch ----------------
extern "C" void kernel_launch(void* const* d_in, const int* in_sizes, int n_in,
                              void* d_out, int out_size, void* d_ws, size_t ws_size,
                              hipStream_t stream)
{
    const float* x_in  = (const float*)d_in[0];
    const float* mask  = (const float*)d_in[1];
    const float* c1p   = (const float*)d_in[2];
    const float* c2p   = (const float*)d_in[3];
    const float* pe    = (const float*)d_in[5];
    const float* n1g   = (const float*)d_in[6];
    const float* n1b   = (const float*)d_in[7];
    const float* qkvw  = (const float*)d_in[8];
    const float* projw = (const float*)d_in[9];
    const float* projb = (const float*)d_in[10];
    const float* n2g   = (const float*)d_in[11];
    const float* n2b   = (const float*)d_in[12];
    const float* fc1w  = (const float*)d_in[13];
    const float* fc1b  = (const float*)d_in[14];
    const float* fc2w  = (const float*)d_in[15];
    const float* fc2b  = (const float*)d_in[16];
    const float* gate  = (const float*)d_in[17];
    const float* addw  = (const float*)d_in[18];
    const float* addb  = (const float*)d_in[19];
    const float* aduw  = (const float*)d_in[20];
    const float* adub  = (const float*)d_in[21];
    const float* ad1dw = (const float*)d_in[22];
    const float* ad1db = (const float*)d_in[23];
    const float* ad1uw = (const float*)d_in[24];
    const float* ad1ub = (const float*)d_in[25];
    const float* bng   = (const float*)d_in[26];
    const float* bnb   = (const float*)d_in[27];
    const float* a1qkvw= (const float*)d_in[28];
    const float* a1pw  = (const float*)d_in[29];
    const float* a1pb  = (const float*)d_in[30];
    const float* n3g   = (const float*)d_in[31];
    const float* n3b   = (const float*)d_in[32];
    const int*   idxp  = (const int*)d_in[33];
    const int*   cidxp = (const int*)d_in[34];

    // ---- workspace layout (bytes), total 252.4 MB ----
    char* w = (char*)d_ws;
    float* X    = (float*)w;                       // 16896x384 f32   [0, 25952256)
    u16*   WB   = (u16*)(w + 25952256);            // bf16 weights (packed)
    u16*   Bb16 = (u16*)(w + 30670848);            // 16896x384 bf16
    char*  R1   = w + 43646976;                    // 100663296 B (bias16 / hid16 / aout16)
    char*  R2   = R1 + 100663296;                  // 100663296 B (QKVg/C1/newx + X16)
    float* V    = (float*)(R2 + 100663296);        // 4096x384 f32

    u16* qkvw16  = WB;
    u16* projw16 = WB +  442368;
    u16* fc1w16  = WB +  589824;
    u16* fc2w16  = WB + 1179648;
    u16* a1qkv16 = WB + 1769472;
    u16* a1pw16  = WB + 2211840;

    u16*   bias16 = (u16*)R1;       // 32x512x512 bf16 (dead before fc1)
    u16*   hid16  = (u16*)R1;       // 16896x1536 bf16 (MLP phase)
    u16*   aout16 = (u16*)R1;       // 131072x384 bf16 (local phase)
    u16*   QKVg   = (u16*)R2;       // 16896x1152 bf16 [R2, R2+38.9MB)
    float* C1     = (float*)R2;     // 16896x384 f32 x_fn (dead after adapter#1)
    float* newx   = (float*)R2;     // 16384x384 f32 (interp out; QKVg dead then)
    u16*   X16    = (u16*)(R2 + 41943040);  // 16896x384 bf16 [40MB, 53MB) of R2

    prep<<<21632, 256, 0, stream>>>(qkvw, projw, fc1w, fc2w, a1qkvw, a1pw, WB,
                                    mask, bias16, x_in, pe, n1g, n1b, X, Bb16);
    gemm256<<<dim3(9, 66), 512, 0, stream>>>(Bb16, qkvw16, nullptr, nullptr, QKVg,
                                             ROWS, 1152, Cq, 4);
    attn_mfma<<<1728, 256, 0, stream>>>(QKVg, bias16, Bb16);
    gemm256<<<dim3(3, 66), 512, 0, stream>>>(Bb16, projw16, projb, X, nullptr,
                                             ROWS, Cq, Cq, 3);
    ln_rows<<<4224, 256, 0, stream>>>(X, n2g, n2b, Bb16, ROWS);
    gemm256<<<dim3(12, 66), 512, 0, stream>>>(Bb16, fc1w16, fc1b, nullptr, hid16,
                                              ROWS, 1536, Cq, 2);
    gemm256<<<dim3(3, 66), 512, 0, stream>>>(hid16, fc2w16, fc2b, C1, nullptr,
                                             ROWS, Cq, 1536, 1);
    // fused: x = gate*adapter(x_fn)+x ; X16 = bf16(x); Bb16 = LN3(x)
    adapter_fused<<<4224, 256, 0, stream>>>(C1, X, addw, addb, aduw, adub, gate,
                                            n3g, n3b, X, X16, Bb16, ROWS);
    // local branch
    gemm256<<<dim3(9, 66), 512, 0, stream>>>(Bb16, a1qkv16, nullptr, nullptr, QKVg,
                                             ROWS, 1152, Cq, 4);
    local_attn<<<4096, 256, 0, stream>>>(QKVg, idxp, aout16);
    gemm_pool<<<1536, 512, 0, stream>>>(aout16, a1pw16, a1pb, idxp, cidxp,
                                        X16, bng, bnb, V, Cq);
    interp_k<<<2048, 128, 0, stream>>>(X, V, c1p, c2p, newx);
    // fused final adapter -> d_out
    adapter_fused<<<4096, 256, 0, stream>>>(newx, nullptr, ad1dw, ad1db, ad1uw, ad1ub,
                                            nullptr, nullptr, nullptr,
                                            (float*)d_out, nullptr, nullptr, Bq*Gq);
}

// Round 11
// 727.550 us; speedup vs baseline: 1.5659x; 1.0853x over previous
//
#include <hip/hip_runtime.h>
#include <hip/hip_bf16.h>

// ---------------- constants ----------------
#define Bq 32
#define Tq 16
#define Gq 512
#define NSEQ 528           // T + G
#define Cq 384
#define Hq 6
#define Sq 128
#define Kg 32              // GROUP_SIZE
#define ROWS (Bq*NSEQ)     // 16896
#define LROWS (Bq*Sq*Kg)   // 131072 local tokens

typedef unsigned short u16;
typedef short bf16x8 __attribute__((ext_vector_type(8)));   // 8 bf16 in 4 VGPRs
typedef float f32x4  __attribute__((ext_vector_type(4)));

__device__ __forceinline__ float gelu_f(float x){
    return 0.5f * x * (1.0f + erff(x * 0.70710678118654752f));
}
__device__ __forceinline__ u16 f2b(float x){
    union { float f; unsigned u; } v; v.f = x;
    return (u16)((v.u + 0x7fffu + ((v.u >> 16) & 1u)) >> 16);
}
__device__ __forceinline__ float b2f(u16 h){
    union { float f; unsigned u; } v; v.u = ((unsigned)h) << 16; return v.f;
}

// async global->LDS, 16B per lane. dest = wave-uniform base + lane*16.
__device__ __forceinline__ void gload16(const u16* g, u16* l){
    __builtin_amdgcn_global_load_lds(
        (const __attribute__((address_space(1))) unsigned int*)(g),
        (__attribute__((address_space(3))) unsigned int*)(l), 16, 0, 0);
}

// ---------------- merged prep: conv6 | conv_mask | build_ln ----------------
__global__ void __launch_bounds__(256) prep(const float* __restrict__ qkvw,
    const float* __restrict__ projw, const float* __restrict__ fc1w,
    const float* __restrict__ fc2w, const float* __restrict__ a1qkvw,
    const float* __restrict__ a1pw, u16* __restrict__ WB,
    const float* __restrict__ mask, u16* __restrict__ bias16,
    const float* __restrict__ xin, const float* __restrict__ pe,
    const float* __restrict__ gw, const float* __restrict__ bw,
    float* __restrict__ X, u16* __restrict__ out)
{
    int bid = blockIdx.x;
    if (bid < 9216){
        long i = (long)bid*256 + threadIdx.x;
        if (i >= 2359296) return;
        float v;
        if      (i <  442368) v = qkvw[i];
        else if (i <  589824) v = projw[i -  442368];
        else if (i < 1179648) v = fc1w[i -  589824];
        else if (i < 1769472) v = fc2w[i - 1179648];
        else if (i < 2211840) v = a1qkvw[i - 1769472];
        else                  v = a1pw[i - 2211840];
        WB[i] = f2b(v);
        return;
    }
    if (bid < 17408){
        long i = (long)(bid - 9216)*256 + threadIdx.x;
        if (i >= ((long)Bq*Gq*Gq >> 2)) return;
        float4 v = *(const float4*)(mask + i*4);
        ushort4 r;
        r.x = f2b(-100000.0f * v.x);
        r.y = f2b(-100000.0f * v.y);
        r.z = f2b(-100000.0f * v.z);
        r.w = f2b(-100000.0f * v.w);
        *(ushort4*)(bias16 + i*4) = r;
        return;
    }
    {
        int w = threadIdx.x >> 6, lane = threadIdx.x & 63;
        int row = (bid - 17408)*4 + w;
        if (row >= ROWS) return;
        int p = row % NSEQ; int b = row / NSEQ;
        const float* src = (p < Tq) ? (pe + (long)p*Cq)
                                    : (xin + ((long)b*Gq + (p - Tq))*Cq);
        float v[6]; float s = 0.f, s2 = 0.f;
#pragma unroll
        for (int j = 0; j < 6; j++){ float x = src[lane + 64*j]; v[j] = x; s += x; s2 += x*x; }
#pragma unroll
        for (int m = 1; m < 64; m <<= 1){ s += __shfl_xor(s, m); s2 += __shfl_xor(s2, m); }
        float mean = s * (1.f/384.f);
        float var  = s2 * (1.f/384.f) - mean*mean;
        float rs   = rsqrtf(var + 1e-5f);
        float* xrow = X + (long)row*Cq;
        u16* orow = out + (long)row*Cq;
#pragma unroll
        for (int j = 0; j < 6; j++){
            int c = lane + 64*j;
            xrow[c] = v[j];
            orow[c] = f2b((v[j] - mean) * rs * gw[c] + bw[c]);
        }
    }
}

// ---------------- LayerNorm, one wave per row, bf16 out ----------------
__global__ void __launch_bounds__(256) ln_rows(const float* __restrict__ in,
    const float* __restrict__ gw, const float* __restrict__ bw,
    u16* __restrict__ out, int rows)
{
    int w = threadIdx.x >> 6, lane = threadIdx.x & 63;
    int row = blockIdx.x*4 + w;
    if (row >= rows) return;
    const float* xr = in + (long)row*Cq;
    float v[6]; float s = 0.f, s2 = 0.f;
#pragma unroll
    for (int j = 0; j < 6; j++){ float x = xr[lane + 64*j]; v[j] = x; s += x; s2 += x*x; }
#pragma unroll
    for (int m = 1; m < 64; m <<= 1){ s += __shfl_xor(s, m); s2 += __shfl_xor(s2, m); }
    float mean = s * (1.f/384.f);
    float var  = s2 * (1.f/384.f) - mean*mean;
    float rs   = rsqrtf(var + 1e-5f);
    u16* orow = out + (long)row*Cq;
#pragma unroll
    for (int j = 0; j < 6; j++){
        int c = lane + 64*j;
        orow[c] = f2b((v[j] - mean) * rs * gw[c] + bw[c]);
    }
}

// ---------------- bf16 MFMA GEMM: C = epi(A @ W^T) ----------------
// 256 threads / 4 waves (2m x 2n), 128x64 tile, per-wave 64x32, acc[4][2].
// Same inner algebra/swizzle as the proven R8 config; smaller blocks give
// 4 independent barrier domains per CU (vs 2) for stall overlap.
// epi: 0 none->f32, 1 +bias->f32, 2 gelu(+bias)->bf16, 3 Cf+=acc+bias,
//      4 (+bias if given)->bf16
__global__ void __launch_bounds__(256, 4) gemm_bf16(const u16* __restrict__ A,
    const u16* __restrict__ W, const float* __restrict__ bias,
    float* __restrict__ Cf, u16* __restrict__ Cb, int M, int N, int K, int epi)
{
    __shared__ u16 As0[128*32];
    __shared__ u16 As1[128*32];
    __shared__ u16 Ws0[64*32];
    __shared__ u16 Ws1[64*32];
    int t = threadIdx.x;
    int nx = gridDim.x;
    int nwg = nx * gridDim.y;
    int f = blockIdx.y*nx + blockIdx.x;
    int xcd = f & 7, i = f >> 3;
    int q = nwg >> 3, r = nwg & 7;
    int base = (xcd < r) ? xcd*(q+1) : r*(q+1) + (xcd - r)*q;
    int nf = base + i;
    int m0 = (nf / nx)*128, n0 = (nf % nx)*64;
    int wv = t >> 6, lane = t & 63;
    int wm = (wv >> 1)*64, wn = (wv & 1)*32;
    int fm = lane & 15;
    int fkp = (((lane >> 4) ^ ((fm >> 1) & 3)) & 3) * 8;
    int rs  = t >> 2;                                  // 0..63
    int kc8 = (((lane & 3) ^ ((lane >> 3) & 3))) * 8;
    f32x4 acc[4][2];
#pragma unroll
    for (int ii = 0; ii < 4; ii++)
#pragma unroll
        for (int j = 0; j < 2; j++) acc[ii][j] = (f32x4){0.f,0.f,0.f,0.f};

    auto STG = [&](u16* Ab, u16* Wb, int k0){
        gload16(A + (long)(m0 + rs     )*K + k0 + kc8, Ab + wv*512);
        gload16(A + (long)(m0 + rs + 64)*K + k0 + kc8, Ab + 2048 + wv*512);
        gload16(W + (long)(n0 + rs     )*K + k0 + kc8, Wb + wv*512);
    };
    auto CMP = [&](const u16* Ab, const u16* Wb){
        bf16x8 af[4], bf[2];
#pragma unroll
        for (int im = 0; im < 4; im++) af[im] = *(const bf16x8*)&Ab[(wm + im*16 + fm)*32 + fkp];
#pragma unroll
        for (int in = 0; in < 2; in++) bf[in] = *(const bf16x8*)&Wb[(wn + in*16 + fm)*32 + fkp];
#pragma unroll
        for (int im = 0; im < 4; im++)
#pragma unroll
            for (int in = 0; in < 2; in++)
                acc[im][in] = __builtin_amdgcn_mfma_f32_16x16x32_bf16(af[im], bf[in], acc[im][in], 0, 0, 0);
    };

    int nt = K >> 5;                 // 12 or 48 -> always even
    STG(As0, Ws0, 0);
    __syncthreads();
    for (int kt = 0; kt < nt; kt += 2){
        STG(As1, Ws1, (kt+1)*32);
        CMP(As0, Ws0);
        __syncthreads();
        if (kt + 2 < nt) STG(As0, Ws0, (kt+2)*32);
        CMP(As1, Ws1);
        __syncthreads();
    }

    int lr = lane >> 4, lc = lane & 15;
#pragma unroll
    for (int im = 0; im < 4; im++){
#pragma unroll
        for (int in = 0; in < 2; in++){
#pragma unroll
            for (int r2 = 0; r2 < 4; r2++){
                int m = m0 + wm + im*16 + lr*4 + r2;
                int n = n0 + wn + in*16 + lc;
                float v = acc[im][in][r2];
                if (epi >= 1 && bias) v += bias[n];
                if (epi == 2) v = gelu_f(v);
                long off = (long)m*N + n;
                if (epi == 3) v += Cf[off];
                if (epi == 2 || epi == 4) Cb[off] = f2b(v);
                else                      Cf[off] = v;
            }
        }
    }
}

// ---------------- local proj GEMM with fused pool epilogue ----------------
// 256-thread / 128x64-tile variant; XCD swizzle grid (6 n-blocks of one m
// consecutive on one XCD). 6144 blocks = 1024 m-tiles x 6 n-tiles.
__global__ void __launch_bounds__(256, 4) gemm_pool(const u16* __restrict__ A,
    const u16* __restrict__ W, const float* __restrict__ bias,
    const int* __restrict__ idx, const int* __restrict__ cidx,
    const u16* __restrict__ X16, const float* __restrict__ bng,
    const float* __restrict__ bnb, float* __restrict__ vis, int K)
{
    __shared__ u16 As0[128*32];
    __shared__ u16 As1[128*32];
    __shared__ u16 Ws0[64*32];
    __shared__ u16 Ws1[64*32];
    __shared__ int idxl[128];
    __shared__ int cidxl[4];
    int t = threadIdx.x;
    int blkf = blockIdx.x;
    int xcd = blkf & 7, slot = blkf >> 3;        // 6144 -> 768 slots/xcd
    int m0 = (xcd*128 + slot/6)*128;
    int n0 = (slot % 6)*64;
    if (t < 128) idxl[t] = idx[m0 + t];
    if (t < 4)   cidxl[t] = cidx[(m0 >> 5) + t];
    int wv = t >> 6, lane = t & 63;
    int wm = (wv >> 1)*64, wn = (wv & 1)*32;
    int fm = lane & 15;
    int fkp = (((lane >> 4) ^ ((fm >> 1) & 3)) & 3) * 8;
    int rs  = t >> 2;
    int kc8 = (((lane & 3) ^ ((lane >> 3) & 3))) * 8;
    f32x4 acc[4][2];
#pragma unroll
    for (int ii = 0; ii < 4; ii++)
#pragma unroll
        for (int j = 0; j < 2; j++) acc[ii][j] = (f32x4){0.f,0.f,0.f,0.f};

    auto STG = [&](u16* Ab, u16* Wb, int k0){
        gload16(A + (long)(m0 + rs     )*K + k0 + kc8, Ab + wv*512);
        gload16(A + (long)(m0 + rs + 64)*K + k0 + kc8, Ab + 2048 + wv*512);
        gload16(W + (long)(n0 + rs     )*K + k0 + kc8, Wb + wv*512);
    };
    auto CMP = [&](const u16* Ab, const u16* Wb){
        bf16x8 af[4], bf[2];
#pragma unroll
        for (int im = 0; im < 4; im++) af[im] = *(const bf16x8*)&Ab[(wm + im*16 + fm)*32 + fkp];
#pragma unroll
        for (int in = 0; in < 2; in++) bf[in] = *(const bf16x8*)&Wb[(wn + in*16 + fm)*32 + fkp];
#pragma unroll
        for (int im = 0; im < 4; im++)
#pragma unroll
            for (int in = 0; in < 2; in++)
                acc[im][in] = __builtin_amdgcn_mfma_f32_16x16x32_bf16(af[im], bf[in], acc[im][in], 0, 0, 0);
    };

    int nt = K >> 5;                 // K=384 -> 12
    STG(As0, Ws0, 0);
    __syncthreads();
    for (int kt = 0; kt < nt; kt += 2){
        STG(As1, Ws1, (kt+1)*32);
        CMP(As0, Ws0);
        __syncthreads();
        if (kt + 2 < nt) STG(As0, Ws0, (kt+2)*32);
        CMP(As1, Ws1);
        __syncthreads();
    }

    int lr = lane >> 4, lc = lane & 15;
#pragma unroll
    for (int in = 0; in < 2; in++){
        int c = n0 + wn + in*16 + lc;
        float pb = bias[c];
        float bg = bng[c], bb = bnb[c];
#pragma unroll
        for (int gl = 0; gl < 2; gl++){
            float vmax = -3e38f, vsum = 0.f;
#pragma unroll
            for (int i2 = 0; i2 < 2; i2++){
                int im = gl*2 + i2;
#pragma unroll
                for (int r = 0; r < 4; r++){
                    int rl = wm + im*16 + lr*4 + r;
                    float val = acc[im][in][r] + pb + b2f(X16[(long)idxl[rl]*Cq + c]);
                    vmax = fmaxf(vmax, val); vsum += val;
                }
            }
            vmax = fmaxf(vmax, __shfl_xor(vmax, 16)); vsum += __shfl_xor(vsum, 16);
            vmax = fmaxf(vmax, __shfl_xor(vmax, 32)); vsum += __shfl_xor(vsum, 32);
            if (lane < 16){
                int glb = (wm >> 5) + gl;
                float lcv = vmax + vsum*(1.f/32.f);
                float u = gelu_f(lcv*bg*0.9999950000374997f + bb);
                vis[((long)(m0 >> 5) + glb)*Cq + c] =
                    u + 0.4f*b2f(X16[(long)cidxl[glb]*Cq + c]);
            }
        }
    }
}

// ---------------- flash-style MFMA global attention v4 ----------------
// Register-prefetch staging + 2 barriers/iter + V column XOR swizzle.
__global__ void __launch_bounds__(256) attn_mfma(const u16* __restrict__ QKVg,
    const u16* __restrict__ bias16, u16* __restrict__ out)
{
    __shared__ u16 Ks[32*72];
    __shared__ u16 Vt[64*40];
    __shared__ u16 Bs[64*36];
    __shared__ u16 Pb[4][16*40];
    int blk = blockIdx.x;
    int xcd = blk & 7; int r0 = blk >> 3;
    int bb = r0 & 3;  int rr = r0 >> 2;
    int h = rr % 6;   int qt = rr / 6;
    int b = xcd + 8*bb;
    int t = threadIdx.x; int w = t >> 6; int lane = t & 63;
    int fr  = lane & 15;
    int fko = (lane >> 4) * 8;
    int colj = lane & 15;
    int rgrp = (lane >> 4) * 4;
    int qb0 = qt*64;
    int q0 = qb0 + w*16;

    int qr = q0 + fr; int qrc = qr < NSEQ ? qr : NSEQ-1;
    const u16* qbase = QKVg + (long)(b*NSEQ + qrc)*1152 + h*64;
    bf16x8 aq0 = *(const bf16x8*)(qbase + fko);
    bf16x8 aq1 = *(const bf16x8*)(qbase + 32 + fko);

    f32x4 oacc[4];
#pragma unroll
    for (int d = 0; d < 4; d++) oacc[d] = (f32x4){0.f,0.f,0.f,0.f};
    float lsum[4] = {0.f, 0.f, 0.f, 0.f};

    int skey = t >> 3;
    int sd8  = (t & 7) * 8;
    int jswz = skey ^ ((t & 3) << 3);      // (d>>3)&3 == t&3 for this thread
    int brow = t >> 2;
    int bc8  = (t & 3) * 8;

    bf16x8 kvR = {0,0,0,0,0,0,0,0}, vvR = {0,0,0,0,0,0,0,0};
    uint4  bzR = make_uint4(0u,0u,0u,0u);
    auto LD = [&](int kc){
        int j = kc*32 + skey;
        bf16x8 kv = {0,0,0,0,0,0,0,0};
        bf16x8 vv = {0,0,0,0,0,0,0,0};
        if (j < NSEQ){
            const u16* kb = QKVg + (long)(b*NSEQ + j)*1152 + 384 + h*64 + sd8;
            kv = *(const bf16x8*)kb;
            vv = *(const bf16x8*)(kb + 384);
        }
        int qi = qb0 + brow;
        int jj = kc*32 + bc8;
        uint4 bz = make_uint4(0u,0u,0u,0u);
        if (qi < Gq && jj < Gq)
            bz = *(const uint4*)(bias16 + ((long)b*Gq + qi)*Gq + jj);
        kvR = kv; vvR = vv; bzR = bz;
    };
    LD(0);

    for (int kc = 0; kc < 17; kc++){
        __syncthreads();               // prev PV done -> safe to overwrite stage
        *(bf16x8*)&Ks[skey*72 + sd8] = kvR;
#pragma unroll
        for (int e = 0; e < 8; e++) Vt[(sd8+e)*40 + jswz] = (u16)vvR[e];
        *(uint4*)&Bs[brow*36 + bc8] = bzR;
        if (kc < 16) LD(kc + 1);       // prefetch: in flight during compute
        __syncthreads();               // staged tile visible

        f32x4 s[2];
#pragma unroll
        for (int sub = 0; sub < 2; sub++){
            bf16x8 bk0 = *(const bf16x8*)&Ks[(sub*16 + fr)*72 + fko];
            bf16x8 bk1 = *(const bf16x8*)&Ks[(sub*16 + fr)*72 + 32 + fko];
            f32x4 z = (f32x4){0.f,0.f,0.f,0.f};
            z = __builtin_amdgcn_mfma_f32_16x16x32_bf16(aq0, bk0, z, 0, 0, 0);
            z = __builtin_amdgcn_mfma_f32_16x16x32_bf16(aq1, bk1, z, 0, 0, 0);
            s[sub] = z;
        }
#pragma unroll
        for (int sub = 0; sub < 2; sub++){
#pragma unroll
            for (int r = 0; r < 4; r++){
                int jj = kc*32 + sub*16 + colj;
                float sv = s[sub][r] * 0.125f
                         + b2f(Bs[(w*16 + rgrp + r)*36 + sub*16 + colj]);
                if (jj >= NSEQ) sv = -1e30f;
                float e = __expf(sv);
                lsum[r] += e;
                Pb[w][(rgrp + r)*40 + sub*16 + colj] = f2b(e);
            }
        }
        // no barrier: Pb[w] written and read by the same wave.
        bf16x8 ap = *(const bf16x8*)&Pb[w][fr*40 + fko];
#pragma unroll
        for (int d = 0; d < 4; d++){
            int D = d*16 + fr;
            int fkv = fko ^ (((D >> 3) & 3) << 3);
            bf16x8 bv = *(const bf16x8*)&Vt[D*40 + fkv];
            oacc[d] = __builtin_amdgcn_mfma_f32_16x16x32_bf16(ap, bv, oacc[d], 0, 0, 0);
        }
    }
#pragma unroll
    for (int r = 0; r < 4; r++){
#pragma unroll
        for (int mm = 1; mm < 16; mm <<= 1) lsum[r] += __shfl_xor(lsum[r], mm);
    }
#pragma unroll
    for (int r = 0; r < 4; r++){
        int qi = q0 + rgrp + r;
        if (qi < NSEQ){
            float inv = 1.0f / lsum[r];
#pragma unroll
            for (int d = 0; d < 4; d++)
                out[((long)(b*NSEQ + qi))*Cq + h*64 + d*16 + colj] = f2b(oacc[d][r]*inv);
        }
    }
}

// ---------------- fused adapter (one wave per row) ----------------
__global__ void __launch_bounds__(256) adapter_fused(const float* __restrict__ xfn,
    const float* __restrict__ resid,
    const float* __restrict__ dw, const float* __restrict__ db,
    const float* __restrict__ uw, const float* __restrict__ ub,
    const float* __restrict__ gatep,
    const float* __restrict__ lng, const float* __restrict__ lnb,
    float* __restrict__ Xout, u16* __restrict__ x16out,
    u16* __restrict__ ln16, int rows)
{
    int w = threadIdx.x >> 6, lane = threadIdx.x & 63;
    int row = blockIdx.x*4 + w;
    if (row >= rows) return;
    const float* xr = xfn + (long)row*Cq;
    float xv[6];
#pragma unroll
    for (int j = 0; j < 6; j++) xv[j] = xr[lane + 64*j];
    float hid[16];
#pragma unroll
    for (int r = 0; r < 16; r++){
        const float* dr = dw + r*Cq;
        float p = 0.f;
#pragma unroll
        for (int j = 0; j < 6; j++) p += xv[j]*dr[lane + 64*j];
#pragma unroll
        for (int mm = 1; mm < 64; mm <<= 1) p += __shfl_xor(p, mm);
        hid[r] = gelu_f(p + db[r]);
    }
    float gate = gatep ? gatep[0] : 1.0f;
    float ov[6];
    float s = 0.f, s2 = 0.f;
#pragma unroll
    for (int j = 0; j < 6; j++){
        int c = lane + 64*j;
        const float* uc = uw + c*16;
        float a = 0.f;
#pragma unroll
        for (int r = 0; r < 16; r++) a += hid[r]*uc[r];
        float v = gate * (a + ub[c] + xv[j]);
        if (resid) v += resid[(long)row*Cq + c];
        ov[j] = v;
        Xout[(long)row*Cq + c] = v;
        if (x16out) x16out[(long)row*Cq + c] = f2b(v);
        s += v; s2 += v*v;
    }
    if (lng){
#pragma unroll
        for (int m = 1; m < 64; m <<= 1){ s += __shfl_xor(s, m); s2 += __shfl_xor(s2, m); }
        float mean = s * (1.f/384.f);
        float var  = s2 * (1.f/384.f) - mean*mean;
        float rs   = rsqrtf(var + 1e-5f);
        u16* orow = ln16 + (long)row*Cq;
#pragma unroll
        for (int j = 0; j < 6; j++){
            int c = lane + 64*j;
            orow[c] = f2b((ov[j] - mean)*rs*lng[c] + lnb[c]);
        }
    }
}

// ---------------- local branch: MFMA attention, 1 group / 256-thr block ------
__global__ void __launch_bounds__(256) local_attn(const u16* __restrict__ QKVg,
    const int* __restrict__ idx, u16* __restrict__ aout16)
{
    __shared__ u16 Qs[32*72];
    __shared__ u16 Ksm[32*72];
    __shared__ u16 Vt[64*40];
    __shared__ float sc[32*36];
    __shared__ u16 Pa[32*40];
    __shared__ float linv[32];
    __shared__ int rows[32];
    int g = blockIdx.x;
    int t = threadIdx.x;
    int w = t >> 6, lane = t & 63;
    if (t < 32) rows[t] = idx[g*Kg + t];
    __syncthreads();
    int srow = t & 31;
    int d8   = (t >> 5) * 8;
    int jswz = srow ^ (((t >> 5) & 3) << 3);   // (d>>3)&3 == (t>>5)&3
    int fr = lane & 15, fko = (lane >> 4)*8;
    int colj = lane & 15, rgrp = (lane >> 4)*4;
    int it = w >> 1, jt = w & 1;
    int smrow = w*8 + (lane >> 3);
    int smc   = (lane & 7) * 4;

    const u16* rbase = QKVg + (long)rows[srow]*1152 + d8;
    bf16x8 qvR = *(const bf16x8*)(rbase);
    bf16x8 kvR = *(const bf16x8*)(rbase + 384);
    bf16x8 vvR = *(const bf16x8*)(rbase + 768);

    for (int h = 0; h < Hq; h++){
        *(bf16x8*)&Qs[srow*72 + d8]  = qvR;
        *(bf16x8*)&Ksm[srow*72 + d8] = kvR;
#pragma unroll
        for (int e = 0; e < 8; e++) Vt[(d8+e)*40 + jswz] = (u16)vvR[e];
        if (h < Hq-1){
            const u16* nb = rbase + (h+1)*64;
            qvR = *(const bf16x8*)(nb);
            kvR = *(const bf16x8*)(nb + 384);
            vvR = *(const bf16x8*)(nb + 768);
        }
        __syncthreads();
        {
            bf16x8 a0 = *(const bf16x8*)&Qs[(it*16+fr)*72 + fko];
            bf16x8 a1 = *(const bf16x8*)&Qs[(it*16+fr)*72 + 32 + fko];
            bf16x8 b0 = *(const bf16x8*)&Ksm[(jt*16+fr)*72 + fko];
            bf16x8 b1 = *(const bf16x8*)&Ksm[(jt*16+fr)*72 + 32 + fko];
            f32x4 z = (f32x4){0.f,0.f,0.f,0.f};
            z = __builtin_amdgcn_mfma_f32_16x16x32_bf16(a0, b0, z, 0, 0, 0);
            z = __builtin_amdgcn_mfma_f32_16x16x32_bf16(a1, b1, z, 0, 0, 0);
#pragma unroll
            for (int r = 0; r < 4; r++)
                sc[(it*16 + rgrp + r)*36 + jt*16 + colj] = z[r]*0.125f;
        }
        __syncthreads();
        {
            float4 s4 = *(const float4*)&sc[smrow*36 + smc];
            float mx = fmaxf(fmaxf(s4.x, s4.y), fmaxf(s4.z, s4.w));
#pragma unroll
            for (int mm = 1; mm < 8; mm <<= 1) mx = fmaxf(mx, __shfl_xor(mx, mm));
            float p0 = __expf(s4.x - mx), p1 = __expf(s4.y - mx);
            float p2 = __expf(s4.z - mx), p3 = __expf(s4.w - mx);
            float sm = p0 + p1 + p2 + p3;
#pragma unroll
            for (int mm = 1; mm < 8; mm <<= 1) sm += __shfl_xor(sm, mm);
            if ((lane & 7) == 0) linv[smrow] = 1.0f / sm;
            Pa[smrow*40 + smc + 0] = f2b(p0);
            Pa[smrow*40 + smc + 1] = f2b(p1);
            Pa[smrow*40 + smc + 2] = f2b(p2);
            Pa[smrow*40 + smc + 3] = f2b(p3);
        }
        __syncthreads();
        {
            bf16x8 ap = *(const bf16x8*)&Pa[(it*16+fr)*40 + fko];
#pragma unroll
            for (int dd = 0; dd < 2; dd++){
                int dt = jt + dd*2;
                int D = dt*16 + fr;
                int fkv = fko ^ (((D >> 3) & 3) << 3);
                bf16x8 bv = *(const bf16x8*)&Vt[D*40 + fkv];
                f32x4 o = (f32x4){0.f,0.f,0.f,0.f};
                o = __builtin_amdgcn_mfma_f32_16x16x32_bf16(ap, bv, o, 0, 0, 0);
#pragma unroll
                for (int r = 0; r < 4; r++){
                    int row = it*16 + rgrp + r;
                    aout16[((long)(g*32 + row))*Cq + h*64 + dt*16 + colj] =
                        f2b(o[r] * linv[row]);
                }
            }
        }
        __syncthreads();
    }
}

// ---------------- inverse-distance interp: 8 points/block share vis reads ----
__global__ void __launch_bounds__(128) interp_k(const float* __restrict__ Xf,
    const float* __restrict__ vis, const float* __restrict__ c1,
    const float* __restrict__ c2, float* __restrict__ newx)
{
    __shared__ float wsh[8*128];
    __shared__ float inv8[8];
    int blk = blockIdx.x;
    int b = blk >> 6, nt = blk & 63;
    int tid = threadIdx.x;
#pragma unroll
    for (int i = 0; i < 8; i++){
        int id = tid + i*128;
        int nl = id >> 7, s = id & 127;
        const float* p1 = c1 + ((long)b*Gq + nt*8 + nl)*3;
        const float* p2 = c2 + ((long)b*Sq + s)*3;
        float x1 = p1[0], y1 = p1[1], z1 = p1[2];
        float x2 = p2[0], y2 = p2[1], z2 = p2[2];
        float d = (x1*x1 + y1*y1 + z1*z1) + (x2*x2 + y2*y2 + z2*z2)
                - 2.f*(x1*x2 + y1*y2 + z1*z2);
        wsh[nl*128 + s] = 1.f/(d + 1e-8f);
    }
    __syncthreads();
    if (tid < 8){
        float sum = 0.f;
        for (int s = 0; s < Sq; s++) sum += wsh[tid*128 + s];
        inv8[tid] = 1.f/sum;
    }
    __syncthreads();
    float acc[8][3];
#pragma unroll
    for (int n = 0; n < 8; n++){ acc[n][0] = 0.f; acc[n][1] = 0.f; acc[n][2] = 0.f; }
    const float* vb = vis + (long)b*Sq*Cq + tid;
    for (int s = 0; s < Sq; s++){
        float v0 = vb[s*Cq], v1 = vb[s*Cq + 128], v2 = vb[s*Cq + 256];
#pragma unroll
        for (int n = 0; n < 8; n++){
            float wq = wsh[n*128 + s];
            acc[n][0] += wq*v0; acc[n][1] += wq*v1; acc[n][2] += wq*v2;
        }
    }
#pragma unroll
    for (int n = 0; n < 8; n++){
        int gn = nt*8 + n;
        const float* xr = Xf + ((long)(b*NSEQ + Tq + gn))*Cq;
        float* orow = newx + ((long)(b*Gq + gn))*Cq;
        float sf = 0.4f * inv8[n];
        orow[tid]       = xr[tid]       + sf*acc[n][0];
        orow[tid + 128] = xr[tid + 128] + sf*acc[n][1];
        orow[tid + 256] = xr[tid + 256] + sf*acc[n][2];
    }
}

// ---------------- launch ----------------
extern "C" void kernel_launch(void* const* d_in, const int* in_sizes, int n_in,
                              void* d_out, int out_size, void* d_ws, size_t ws_size,
                              hipStream_t stream)
{
    const float* x_in  = (const float*)d_in[0];
    const float* mask  = (const float*)d_in[1];
    const float* c1p   = (const float*)d_in[2];
    const float* c2p   = (const float*)d_in[3];
    const float* pe    = (const float*)d_in[5];
    const float* n1g   = (const float*)d_in[6];
    const float* n1b   = (const float*)d_in[7];
    const float* qkvw  = (const float*)d_in[8];
    const float* projw = (const float*)d_in[9];
    const float* projb = (const float*)d_in[10];
    const float* n2g   = (const float*)d_in[11];
    const float* n2b   = (const float*)d_in[12];
    const float* fc1w  = (const float*)d_in[13];
    const float* fc1b  = (const float*)d_in[14];
    const float* fc2w  = (const float*)d_in[15];
    const float* fc2b  = (const float*)d_in[16];
    const float* gate  = (const float*)d_in[17];
    const float* addw  = (const float*)d_in[18];
    const float* addb  = (const float*)d_in[19];
    const float* aduw  = (const float*)d_in[20];
    const float* adub  = (const float*)d_in[21];
    const float* ad1dw = (const float*)d_in[22];
    const float* ad1db = (const float*)d_in[23];
    const float* ad1uw = (const float*)d_in[24];
    const float* ad1ub = (const float*)d_in[25];
    const float* bng   = (const float*)d_in[26];
    const float* bnb   = (const float*)d_in[27];
    const float* a1qkvw= (const float*)d_in[28];
    const float* a1pw  = (const float*)d_in[29];
    const float* a1pb  = (const float*)d_in[30];
    const float* n3g   = (const float*)d_in[31];
    const float* n3b   = (const float*)d_in[32];
    const int*   idxp  = (const int*)d_in[33];
    const int*   cidxp = (const int*)d_in[34];

    // ---- workspace layout (bytes), total 252.4 MB ----
    char* w = (char*)d_ws;
    float* X    = (float*)w;                       // 16896x384 f32   [0, 25952256)
    u16*   WB   = (u16*)(w + 25952256);            // bf16 weights
    u16*   Bb16 = (u16*)(w + 30670848);            // 16896x384 bf16
    char*  R1   = w + 43646976;                    // 100663296 B (bias16 / hid16 / aout16)
    char*  R2   = R1 + 100663296;                  // 100663296 B (QKVg/C1/newx + X16)
    float* V    = (float*)(R2 + 100663296);        // 4096x384 f32

    u16* qkvw16  = WB;
    u16* projw16 = WB +  442368;
    u16* fc1w16  = WB +  589824;
    u16* fc2w16  = WB + 1179648;
    u16* a1qkv16 = WB + 1769472;
    u16* a1pw16  = WB + 2211840;

    u16*   bias16 = (u16*)R1;       // 32x512x512 bf16 (dead before fc1)
    u16*   hid16  = (u16*)R1;       // 16896x1536 bf16 (MLP phase)
    u16*   aout16 = (u16*)R1;       // 131072x384 bf16 (local phase)
    u16*   QKVg   = (u16*)R2;       // 16896x1152 bf16 [R2, R2+38.9MB)
    float* C1     = (float*)R2;     // 16896x384 f32 x_fn (dead after adapter#1)
    float* newx   = (float*)R2;     // 16384x384 f32 (interp out; QKVg dead then)
    u16*   X16    = (u16*)(R2 + 41943040);  // 16896x384 bf16 [40MB, 53MB) of R2

    prep<<<21632, 256, 0, stream>>>(qkvw, projw, fc1w, fc2w, a1qkvw, a1pw, WB,
                                    mask, bias16, x_in, pe, n1g, n1b, X, Bb16);
    gemm_bf16<<<dim3(18, 132), 256, 0, stream>>>(Bb16, qkvw16, nullptr, nullptr, QKVg,
                                                 ROWS, 1152, Cq, 4);
    attn_mfma<<<1728, 256, 0, stream>>>(QKVg, bias16, Bb16);
    gemm_bf16<<<dim3(6, 132), 256, 0, stream>>>(Bb16, projw16, projb, X, nullptr,
                                                ROWS, Cq, Cq, 3);
    ln_rows<<<4224, 256, 0, stream>>>(X, n2g, n2b, Bb16, ROWS);
    gemm_bf16<<<dim3(24, 132), 256, 0, stream>>>(Bb16, fc1w16, fc1b, nullptr, hid16,
                                                 ROWS, 1536, Cq, 2);
    gemm_bf16<<<dim3(6, 132), 256, 0, stream>>>(hid16, fc2w16, fc2b, C1, nullptr,
                                                ROWS, Cq, 1536, 1);
    // fused: x = gate*adapter(x_fn)+x ; X16 = bf16(x); Bb16 = LN3(x)
    adapter_fused<<<4224, 256, 0, stream>>>(C1, X, addw, addb, aduw, adub, gate,
                                            n3g, n3b, X, X16, Bb16, ROWS);
    // local branch
    gemm_bf16<<<dim3(18, 132), 256, 0, stream>>>(Bb16, a1qkv16, nullptr, nullptr, QKVg,
                                                 ROWS, 1152, Cq, 4);
    local_attn<<<4096, 256, 0, stream>>>(QKVg, idxp, aout16);
    gemm_pool<<<6144, 256, 0, stream>>>(aout16, a1pw16, a1pb, idxp, cidxp,
                                        X16, bng, bnb, V, Cq);
    interp_k<<<2048, 128, 0, stream>>>(X, V, c1p, c2p, newx);
    // fused final adapter -> d_out
    adapter_fused<<<4096, 256, 0, stream>>>(newx, nullptr, ad1dw, ad1db, ad1uw, ad1ub,
                                            nullptr, nullptr, nullptr,
                                            (float*)d_out, nullptr, nullptr, Bq*Gq);
}

// Round 12
// 692.913 us; speedup vs baseline: 1.6442x; 1.0500x over previous
//
#include <hip/hip_runtime.h>
#include <hip/hip_bf16.h>

// ---------------- constants ----------------
#define Bq 32
#define Tq 16
#define Gq 512
#define NSEQ 528           // T + G
#define Cq 384
#define Hq 6
#define Sq 128
#define Kg 32              // GROUP_SIZE
#define ROWS (Bq*NSEQ)     // 16896
#define LROWS (Bq*Sq*Kg)   // 131072 local tokens

typedef unsigned short u16;
typedef short bf16x8 __attribute__((ext_vector_type(8)));   // 8 bf16 in 4 VGPRs
typedef float f32x4  __attribute__((ext_vector_type(4)));

__device__ __forceinline__ float gelu_f(float x){
    return 0.5f * x * (1.0f + erff(x * 0.70710678118654752f));
}
__device__ __forceinline__ u16 f2b(float x){
    union { float f; unsigned u; } v; v.f = x;
    return (u16)((v.u + 0x7fffu + ((v.u >> 16) & 1u)) >> 16);
}
__device__ __forceinline__ float b2f(u16 h){
    union { float f; unsigned u; } v; v.u = ((unsigned)h) << 16; return v.f;
}

// async global->LDS, 16B per lane. dest = wave-uniform base + lane*16.
__device__ __forceinline__ void gload16(const u16* g, u16* l){
    __builtin_amdgcn_global_load_lds(
        (const __attribute__((address_space(1))) unsigned int*)(g),
        (__attribute__((address_space(3))) unsigned int*)(l), 16, 0, 0);
}

// ---------------- merged prep: conv6 | conv_mask | build_ln ----------------
__global__ void __launch_bounds__(256) prep(const float* __restrict__ qkvw,
    const float* __restrict__ projw, const float* __restrict__ fc1w,
    const float* __restrict__ fc2w, const float* __restrict__ a1qkvw,
    const float* __restrict__ a1pw, u16* __restrict__ WB,
    const float* __restrict__ mask, u16* __restrict__ bias16,
    const float* __restrict__ xin, const float* __restrict__ pe,
    const float* __restrict__ gw, const float* __restrict__ bw,
    float* __restrict__ X, u16* __restrict__ out)
{
    int bid = blockIdx.x;
    if (bid < 9216){
        long i = (long)bid*256 + threadIdx.x;
        if (i >= 2359296) return;
        float v;
        if      (i <  442368) v = qkvw[i];
        else if (i <  589824) v = projw[i -  442368];
        else if (i < 1179648) v = fc1w[i -  589824];
        else if (i < 1769472) v = fc2w[i - 1179648];
        else if (i < 2211840) v = a1qkvw[i - 1769472];
        else                  v = a1pw[i - 2211840];
        WB[i] = f2b(v);
        return;
    }
    if (bid < 17408){
        long i = (long)(bid - 9216)*256 + threadIdx.x;
        if (i >= ((long)Bq*Gq*Gq >> 2)) return;
        float4 v = *(const float4*)(mask + i*4);
        ushort4 r;
        r.x = f2b(-100000.0f * v.x);
        r.y = f2b(-100000.0f * v.y);
        r.z = f2b(-100000.0f * v.z);
        r.w = f2b(-100000.0f * v.w);
        *(ushort4*)(bias16 + i*4) = r;
        return;
    }
    {
        int w = threadIdx.x >> 6, lane = threadIdx.x & 63;
        int row = (bid - 17408)*4 + w;
        if (row >= ROWS) return;
        int p = row % NSEQ; int b = row / NSEQ;
        const float* src = (p < Tq) ? (pe + (long)p*Cq)
                                    : (xin + ((long)b*Gq + (p - Tq))*Cq);
        float v[6]; float s = 0.f, s2 = 0.f;
#pragma unroll
        for (int j = 0; j < 6; j++){ float x = src[lane + 64*j]; v[j] = x; s += x; s2 += x*x; }
#pragma unroll
        for (int m = 1; m < 64; m <<= 1){ s += __shfl_xor(s, m); s2 += __shfl_xor(s2, m); }
        float mean = s * (1.f/384.f);
        float var  = s2 * (1.f/384.f) - mean*mean;
        float rs   = rsqrtf(var + 1e-5f);
        float* xrow = X + (long)row*Cq;
        u16* orow = out + (long)row*Cq;
#pragma unroll
        for (int j = 0; j < 6; j++){
            int c = lane + 64*j;
            xrow[c] = v[j];
            orow[c] = f2b((v[j] - mean) * rs * gw[c] + bw[c]);
        }
    }
}

// ---------------- LayerNorm, one wave per row, bf16 out ----------------
__global__ void __launch_bounds__(256) ln_rows(const float* __restrict__ in,
    const float* __restrict__ gw, const float* __restrict__ bw,
    u16* __restrict__ out, int rows)
{
    int w = threadIdx.x >> 6, lane = threadIdx.x & 63;
    int row = blockIdx.x*4 + w;
    if (row >= rows) return;
    const float* xr = in + (long)row*Cq;
    float v[6]; float s = 0.f, s2 = 0.f;
#pragma unroll
    for (int j = 0; j < 6; j++){ float x = xr[lane + 64*j]; v[j] = x; s += x; s2 += x*x; }
#pragma unroll
    for (int m = 1; m < 64; m <<= 1){ s += __shfl_xor(s, m); s2 += __shfl_xor(s2, m); }
    float mean = s * (1.f/384.f);
    float var  = s2 * (1.f/384.f) - mean*mean;
    float rs   = rsqrtf(var + 1e-5f);
    u16* orow = out + (long)row*Cq;
#pragma unroll
    for (int j = 0; j < 6; j++){
        int c = lane + 64*j;
        orow[c] = f2b((v[j] - mean) * rs * gw[c] + bw[c]);
    }
}

// ---------------- bf16 MFMA GEMM: C = epi(A @ W^T) ----------------
// R8-proven config: 512 threads / 8 waves (2m x 4n), 128x128 tile,
// acc[4][2]=32 AGPR, 2-buffer double-buffered gload_lds staging,
// XCD-aware bijective block remap. (7 structural variants measured worse.)
__global__ void __launch_bounds__(512, 4) gemm_bf16(const u16* __restrict__ A,
    const u16* __restrict__ W, const float* __restrict__ bias,
    float* __restrict__ Cf, u16* __restrict__ Cb, int M, int N, int K, int epi)
{
    __shared__ u16 As0[128*32];
    __shared__ u16 As1[128*32];
    __shared__ u16 Ws0[128*32];
    __shared__ u16 Ws1[128*32];
    int t = threadIdx.x;
    int nx = gridDim.x;
    int nwg = nx * gridDim.y;
    int f = blockIdx.y*nx + blockIdx.x;
    int xcd = f & 7, i = f >> 3;
    int q = nwg >> 3, r = nwg & 7;
    int base = (xcd < r) ? xcd*(q+1) : r*(q+1) + (xcd - r)*q;
    int nf = base + i;
    int m0 = (nf / nx)*128, n0 = (nf % nx)*128;
    int wv = t >> 6, lane = t & 63;
    int wm = (wv >> 2)*64, wn = (wv & 3)*32;
    int fm = lane & 15;
    int fkp = (((lane >> 4) ^ ((fm >> 1) & 3)) & 3) * 8;
    int rs  = t >> 2;
    int kc8 = (((lane & 3) ^ ((lane >> 3) & 3))) * 8;
    f32x4 acc[4][2];
#pragma unroll
    for (int ii = 0; ii < 4; ii++)
#pragma unroll
        for (int j = 0; j < 2; j++) acc[ii][j] = (f32x4){0.f,0.f,0.f,0.f};

    auto STG = [&](u16* Ab, u16* Wb, int k0){
        gload16(A + (long)(m0 + rs)*K + k0 + kc8, Ab + wv*512);
        gload16(W + (long)(n0 + rs)*K + k0 + kc8, Wb + wv*512);
    };
    auto CMP = [&](const u16* Ab, const u16* Wb){
        bf16x8 af[4], bf[2];
#pragma unroll
        for (int im = 0; im < 4; im++) af[im] = *(const bf16x8*)&Ab[(wm + im*16 + fm)*32 + fkp];
#pragma unroll
        for (int in = 0; in < 2; in++) bf[in] = *(const bf16x8*)&Wb[(wn + in*16 + fm)*32 + fkp];
#pragma unroll
        for (int im = 0; im < 4; im++)
#pragma unroll
            for (int in = 0; in < 2; in++)
                acc[im][in] = __builtin_amdgcn_mfma_f32_16x16x32_bf16(af[im], bf[in], acc[im][in], 0, 0, 0);
    };

    int nt = K >> 5;                 // 12 or 48 -> always even
    STG(As0, Ws0, 0);
    __syncthreads();
    for (int kt = 0; kt < nt; kt += 2){
        STG(As1, Ws1, (kt+1)*32);
        CMP(As0, Ws0);
        __syncthreads();
        if (kt + 2 < nt) STG(As0, Ws0, (kt+2)*32);
        CMP(As1, Ws1);
        __syncthreads();
    }

    int lr = lane >> 4, lc = lane & 15;
#pragma unroll
    for (int im = 0; im < 4; im++){
#pragma unroll
        for (int in = 0; in < 2; in++){
#pragma unroll
            for (int r2 = 0; r2 < 4; r2++){
                int m = m0 + wm + im*16 + lr*4 + r2;
                int n = n0 + wn + in*16 + lc;
                float v = acc[im][in][r2];
                if (epi >= 1 && bias) v += bias[n];
                if (epi == 2) v = gelu_f(v);
                long off = (long)m*N + n;
                if (epi == 3) v += Cf[off];
                if (epi == 2 || epi == 4) Cb[off] = f2b(v);
                else                      Cf[off] = v;
            }
        }
    }
}

// ---------------- local proj GEMM with fused pool epilogue ----------------
// R8 config + T14 epilogue-gather hoist: the 36 scattered X16 gathers depend
// only on idxl/cidxl (known at block start) -> issue them before the K-loop
// so their ~600cy latency hides under the 12 K-steps instead of serializing
// after the MFMAs.
__global__ void __launch_bounds__(512, 4) gemm_pool(const u16* __restrict__ A,
    const u16* __restrict__ W, const float* __restrict__ bias,
    const int* __restrict__ idx, const int* __restrict__ cidx,
    const u16* __restrict__ X16, const float* __restrict__ bng,
    const float* __restrict__ bnb, float* __restrict__ vis, int K)
{
    __shared__ u16 As0[128*32];
    __shared__ u16 As1[128*32];
    __shared__ u16 Ws0[128*32];
    __shared__ u16 Ws1[128*32];
    __shared__ int idxl[128];
    __shared__ int cidxl[4];
    int t = threadIdx.x;
    int blkf = blockIdx.x;
    int xcd = blkf & 7, slot = blkf >> 3;        // 3072 -> 384 slots/xcd
    int m0 = (xcd*128 + slot/3)*128;
    int n0 = (slot % 3)*128;
    if (t < 128) idxl[t] = idx[m0 + t];
    if (t < 4)   cidxl[t] = cidx[(m0 >> 5) + t];
    int wv = t >> 6, lane = t & 63;
    int wm = (wv >> 2)*64, wn = (wv & 3)*32;
    int fm = lane & 15;
    int fkp = (((lane >> 4) ^ ((fm >> 1) & 3)) & 3) * 8;
    int rs  = t >> 2;
    int kc8 = (((lane & 3) ^ ((lane >> 3) & 3))) * 8;
    int lr = lane >> 4, lc = lane & 15;
    f32x4 acc[4][2];
#pragma unroll
    for (int ii = 0; ii < 4; ii++)
#pragma unroll
        for (int j = 0; j < 2; j++) acc[ii][j] = (f32x4){0.f,0.f,0.f,0.f};

    auto STG = [&](u16* Ab, u16* Wb, int k0){
        gload16(A + (long)(m0 + rs)*K + k0 + kc8, Ab + wv*512);
        gload16(W + (long)(n0 + rs)*K + k0 + kc8, Wb + wv*512);
    };
    auto CMP = [&](const u16* Ab, const u16* Wb){
        bf16x8 af[4], bf[2];
#pragma unroll
        for (int im = 0; im < 4; im++) af[im] = *(const bf16x8*)&Ab[(wm + im*16 + fm)*32 + fkp];
#pragma unroll
        for (int in = 0; in < 2; in++) bf[in] = *(const bf16x8*)&Wb[(wn + in*16 + fm)*32 + fkp];
#pragma unroll
        for (int im = 0; im < 4; im++)
#pragma unroll
            for (int in = 0; in < 2; in++)
                acc[im][in] = __builtin_amdgcn_mfma_f32_16x16x32_bf16(af[im], bf[in], acc[im][in], 0, 0, 0);
    };

    int nt = K >> 5;                 // K=384 -> 12
    STG(As0, Ws0, 0);
    __syncthreads();                 // idxl/cidxl now visible

    // T14 hoist: issue all epilogue gathers now; latency hides under K-loop.
    u16 gv[2][4][4];
    u16 cg[2][2];
#pragma unroll
    for (int in = 0; in < 2; in++){
        int c = n0 + wn + in*16 + lc;
#pragma unroll
        for (int im = 0; im < 4; im++)
#pragma unroll
            for (int r = 0; r < 4; r++){
                int rl = wm + im*16 + lr*4 + r;
                gv[in][im][r] = X16[(long)idxl[rl]*Cq + c];
            }
#pragma unroll
        for (int gl = 0; gl < 2; gl++)
            cg[in][gl] = X16[(long)cidxl[(wm >> 5) + gl]*Cq + c];
    }

    for (int kt = 0; kt < nt; kt += 2){
        STG(As1, Ws1, (kt+1)*32);
        CMP(As0, Ws0);
        __syncthreads();
        if (kt + 2 < nt) STG(As0, Ws0, (kt+2)*32);
        CMP(As1, Ws1);
        __syncthreads();
    }

#pragma unroll
    for (int in = 0; in < 2; in++){
        int c = n0 + wn + in*16 + lc;
        float pb = bias[c];
        float bg = bng[c], bb = bnb[c];
#pragma unroll
        for (int gl = 0; gl < 2; gl++){
            float vmax = -3e38f, vsum = 0.f;
#pragma unroll
            for (int i2 = 0; i2 < 2; i2++){
                int im = gl*2 + i2;
#pragma unroll
                for (int r = 0; r < 4; r++){
                    float val = acc[im][in][r] + pb + b2f(gv[in][im][r]);
                    vmax = fmaxf(vmax, val); vsum += val;
                }
            }
            vmax = fmaxf(vmax, __shfl_xor(vmax, 16)); vsum += __shfl_xor(vsum, 16);
            vmax = fmaxf(vmax, __shfl_xor(vmax, 32)); vsum += __shfl_xor(vsum, 32);
            if (lane < 16){
                int glb = (wm >> 5) + gl;
                float lcv = vmax + vsum*(1.f/32.f);
                float u = gelu_f(lcv*bg*0.9999950000374997f + bb);
                vis[((long)(m0 >> 5) + glb)*Cq + c] =
                    u + 0.4f*b2f(cg[in][gl]);
            }
        }
    }
}

// ---------------- flash-style MFMA global attention v4 ----------------
// Register-prefetch staging + 2 barriers/iter + V column XOR swizzle.
__global__ void __launch_bounds__(256) attn_mfma(const u16* __restrict__ QKVg,
    const u16* __restrict__ bias16, u16* __restrict__ out)
{
    __shared__ u16 Ks[32*72];
    __shared__ u16 Vt[64*40];
    __shared__ u16 Bs[64*36];
    __shared__ u16 Pb[4][16*40];
    int blk = blockIdx.x;
    int xcd = blk & 7; int r0 = blk >> 3;
    int bb = r0 & 3;  int rr = r0 >> 2;
    int h = rr % 6;   int qt = rr / 6;
    int b = xcd + 8*bb;
    int t = threadIdx.x; int w = t >> 6; int lane = t & 63;
    int fr  = lane & 15;
    int fko = (lane >> 4) * 8;
    int colj = lane & 15;
    int rgrp = (lane >> 4) * 4;
    int qb0 = qt*64;
    int q0 = qb0 + w*16;

    int qr = q0 + fr; int qrc = qr < NSEQ ? qr : NSEQ-1;
    const u16* qbase = QKVg + (long)(b*NSEQ + qrc)*1152 + h*64;
    bf16x8 aq0 = *(const bf16x8*)(qbase + fko);
    bf16x8 aq1 = *(const bf16x8*)(qbase + 32 + fko);

    f32x4 oacc[4];
#pragma unroll
    for (int d = 0; d < 4; d++) oacc[d] = (f32x4){0.f,0.f,0.f,0.f};
    float lsum[4] = {0.f, 0.f, 0.f, 0.f};

    int skey = t >> 3;
    int sd8  = (t & 7) * 8;
    int jswz = skey ^ ((t & 3) << 3);      // (d>>3)&3 == t&3 for this thread
    int brow = t >> 2;
    int bc8  = (t & 3) * 8;

    bf16x8 kvR = {0,0,0,0,0,0,0,0}, vvR = {0,0,0,0,0,0,0,0};
    uint4  bzR = make_uint4(0u,0u,0u,0u);
    auto LD = [&](int kc){
        int j = kc*32 + skey;
        bf16x8 kv = {0,0,0,0,0,0,0,0};
        bf16x8 vv = {0,0,0,0,0,0,0,0};
        if (j < NSEQ){
            const u16* kb = QKVg + (long)(b*NSEQ + j)*1152 + 384 + h*64 + sd8;
            kv = *(const bf16x8*)kb;
            vv = *(const bf16x8*)(kb + 384);
        }
        int qi = qb0 + brow;
        int jj = kc*32 + bc8;
        uint4 bz = make_uint4(0u,0u,0u,0u);
        if (qi < Gq && jj < Gq)
            bz = *(const uint4*)(bias16 + ((long)b*Gq + qi)*Gq + jj);
        kvR = kv; vvR = vv; bzR = bz;
    };
    LD(0);

    for (int kc = 0; kc < 17; kc++){
        __syncthreads();               // prev PV done -> safe to overwrite stage
        *(bf16x8*)&Ks[skey*72 + sd8] = kvR;
#pragma unroll
        for (int e = 0; e < 8; e++) Vt[(sd8+e)*40 + jswz] = (u16)vvR[e];
        *(uint4*)&Bs[brow*36 + bc8] = bzR;
        if (kc < 16) LD(kc + 1);       // prefetch: in flight during compute
        __syncthreads();               // staged tile visible

        f32x4 s[2];
#pragma unroll
        for (int sub = 0; sub < 2; sub++){
            bf16x8 bk0 = *(const bf16x8*)&Ks[(sub*16 + fr)*72 + fko];
            bf16x8 bk1 = *(const bf16x8*)&Ks[(sub*16 + fr)*72 + 32 + fko];
            f32x4 z = (f32x4){0.f,0.f,0.f,0.f};
            z = __builtin_amdgcn_mfma_f32_16x16x32_bf16(aq0, bk0, z, 0, 0, 0);
            z = __builtin_amdgcn_mfma_f32_16x16x32_bf16(aq1, bk1, z, 0, 0, 0);
            s[sub] = z;
        }
#pragma unroll
        for (int sub = 0; sub < 2; sub++){
#pragma unroll
            for (int r = 0; r < 4; r++){
                int jj = kc*32 + sub*16 + colj;
                float sv = s[sub][r] * 0.125f
                         + b2f(Bs[(w*16 + rgrp + r)*36 + sub*16 + colj]);
                if (jj >= NSEQ) sv = -1e30f;
                float e = __expf(sv);
                lsum[r] += e;
                Pb[w][(rgrp + r)*40 + sub*16 + colj] = f2b(e);
            }
        }
        // no barrier: Pb[w] written and read by the same wave.
        bf16x8 ap = *(const bf16x8*)&Pb[w][fr*40 + fko];
#pragma unroll
        for (int d = 0; d < 4; d++){
            int D = d*16 + fr;
            int fkv = fko ^ (((D >> 3) & 3) << 3);
            bf16x8 bv = *(const bf16x8*)&Vt[D*40 + fkv];
            oacc[d] = __builtin_amdgcn_mfma_f32_16x16x32_bf16(ap, bv, oacc[d], 0, 0, 0);
        }
    }
#pragma unroll
    for (int r = 0; r < 4; r++){
#pragma unroll
        for (int mm = 1; mm < 16; mm <<= 1) lsum[r] += __shfl_xor(lsum[r], mm);
    }
#pragma unroll
    for (int r = 0; r < 4; r++){
        int qi = q0 + rgrp + r;
        if (qi < NSEQ){
            float inv = 1.0f / lsum[r];
#pragma unroll
            for (int d = 0; d < 4; d++)
                out[((long)(b*NSEQ + qi))*Cq + h*64 + d*16 + colj] = f2b(oacc[d][r]*inv);
        }
    }
}

// ---------------- fused adapter (one wave per row) ----------------
__global__ void __launch_bounds__(256) adapter_fused(const float* __restrict__ xfn,
    const float* __restrict__ resid,
    const float* __restrict__ dw, const float* __restrict__ db,
    const float* __restrict__ uw, const float* __restrict__ ub,
    const float* __restrict__ gatep,
    const float* __restrict__ lng, const float* __restrict__ lnb,
    float* __restrict__ Xout, u16* __restrict__ x16out,
    u16* __restrict__ ln16, int rows)
{
    int w = threadIdx.x >> 6, lane = threadIdx.x & 63;
    int row = blockIdx.x*4 + w;
    if (row >= rows) return;
    const float* xr = xfn + (long)row*Cq;
    float xv[6];
#pragma unroll
    for (int j = 0; j < 6; j++) xv[j] = xr[lane + 64*j];
    float hid[16];
#pragma unroll
    for (int r = 0; r < 16; r++){
        const float* dr = dw + r*Cq;
        float p = 0.f;
#pragma unroll
        for (int j = 0; j < 6; j++) p += xv[j]*dr[lane + 64*j];
#pragma unroll
        for (int mm = 1; mm < 64; mm <<= 1) p += __shfl_xor(p, mm);
        hid[r] = gelu_f(p + db[r]);
    }
    float gate = gatep ? gatep[0] : 1.0f;
    float ov[6];
    float s = 0.f, s2 = 0.f;
#pragma unroll
    for (int j = 0; j < 6; j++){
        int c = lane + 64*j;
        const float* uc = uw + c*16;
        float a = 0.f;
#pragma unroll
        for (int r = 0; r < 16; r++) a += hid[r]*uc[r];
        float v = gate * (a + ub[c] + xv[j]);
        if (resid) v += resid[(long)row*Cq + c];
        ov[j] = v;
        Xout[(long)row*Cq + c] = v;
        if (x16out) x16out[(long)row*Cq + c] = f2b(v);
        s += v; s2 += v*v;
    }
    if (lng){
#pragma unroll
        for (int m = 1; m < 64; m <<= 1){ s += __shfl_xor(s, m); s2 += __shfl_xor(s2, m); }
        float mean = s * (1.f/384.f);
        float var  = s2 * (1.f/384.f) - mean*mean;
        float rs   = rsqrtf(var + 1e-5f);
        u16* orow = ln16 + (long)row*Cq;
#pragma unroll
        for (int j = 0; j < 6; j++){
            int c = lane + 64*j;
            orow[c] = f2b((ov[j] - mean)*rs*lng[c] + lnb[c]);
        }
    }
}

// ---------------- local branch: MFMA attention, 1 group / 256-thr block ------
__global__ void __launch_bounds__(256) local_attn(const u16* __restrict__ QKVg,
    const int* __restrict__ idx, u16* __restrict__ aout16)
{
    __shared__ u16 Qs[32*72];
    __shared__ u16 Ksm[32*72];
    __shared__ u16 Vt[64*40];
    __shared__ float sc[32*36];
    __shared__ u16 Pa[32*40];
    __shared__ float linv[32];
    __shared__ int rows[32];
    int g = blockIdx.x;
    int t = threadIdx.x;
    int w = t >> 6, lane = t & 63;
    if (t < 32) rows[t] = idx[g*Kg + t];
    __syncthreads();
    int srow = t & 31;
    int d8   = (t >> 5) * 8;
    int jswz = srow ^ (((t >> 5) & 3) << 3);   // (d>>3)&3 == (t>>5)&3
    int fr = lane & 15, fko = (lane >> 4)*8;
    int colj = lane & 15, rgrp = (lane >> 4)*4;
    int it = w >> 1, jt = w & 1;
    int smrow = w*8 + (lane >> 3);
    int smc   = (lane & 7) * 4;

    const u16* rbase = QKVg + (long)rows[srow]*1152 + d8;
    bf16x8 qvR = *(const bf16x8*)(rbase);
    bf16x8 kvR = *(const bf16x8*)(rbase + 384);
    bf16x8 vvR = *(const bf16x8*)(rbase + 768);

    for (int h = 0; h < Hq; h++){
        *(bf16x8*)&Qs[srow*72 + d8]  = qvR;
        *(bf16x8*)&Ksm[srow*72 + d8] = kvR;
#pragma unroll
        for (int e = 0; e < 8; e++) Vt[(d8+e)*40 + jswz] = (u16)vvR[e];
        if (h < Hq-1){
            const u16* nb = rbase + (h+1)*64;
            qvR = *(const bf16x8*)(nb);
            kvR = *(const bf16x8*)(nb + 384);
            vvR = *(const bf16x8*)(nb + 768);
        }
        __syncthreads();
        {
            bf16x8 a0 = *(const bf16x8*)&Qs[(it*16+fr)*72 + fko];
            bf16x8 a1 = *(const bf16x8*)&Qs[(it*16+fr)*72 + 32 + fko];
            bf16x8 b0 = *(const bf16x8*)&Ksm[(jt*16+fr)*72 + fko];
            bf16x8 b1 = *(const bf16x8*)&Ksm[(jt*16+fr)*72 + 32 + fko];
            f32x4 z = (f32x4){0.f,0.f,0.f,0.f};
            z = __builtin_amdgcn_mfma_f32_16x16x32_bf16(a0, b0, z, 0, 0, 0);
            z = __builtin_amdgcn_mfma_f32_16x16x32_bf16(a1, b1, z, 0, 0, 0);
#pragma unroll
            for (int r = 0; r < 4; r++)
                sc[(it*16 + rgrp + r)*36 + jt*16 + colj] = z[r]*0.125f;
        }
        __syncthreads();
        {
            float4 s4 = *(const float4*)&sc[smrow*36 + smc];
            float mx = fmaxf(fmaxf(s4.x, s4.y), fmaxf(s4.z, s4.w));
#pragma unroll
            for (int mm = 1; mm < 8; mm <<= 1) mx = fmaxf(mx, __shfl_xor(mx, mm));
            float p0 = __expf(s4.x - mx), p1 = __expf(s4.y - mx);
            float p2 = __expf(s4.z - mx), p3 = __expf(s4.w - mx);
            float sm = p0 + p1 + p2 + p3;
#pragma unroll
            for (int mm = 1; mm < 8; mm <<= 1) sm += __shfl_xor(sm, mm);
            if ((lane & 7) == 0) linv[smrow] = 1.0f / sm;
            Pa[smrow*40 + smc + 0] = f2b(p0);
            Pa[smrow*40 + smc + 1] = f2b(p1);
            Pa[smrow*40 + smc + 2] = f2b(p2);
            Pa[smrow*40 + smc + 3] = f2b(p3);
        }
        __syncthreads();
        {
            bf16x8 ap = *(const bf16x8*)&Pa[(it*16+fr)*40 + fko];
#pragma unroll
            for (int dd = 0; dd < 2; dd++){
                int dt = jt + dd*2;
                int D = dt*16 + fr;
                int fkv = fko ^ (((D >> 3) & 3) << 3);
                bf16x8 bv = *(const bf16x8*)&Vt[D*40 + fkv];
                f32x4 o = (f32x4){0.f,0.f,0.f,0.f};
                o = __builtin_amdgcn_mfma_f32_16x16x32_bf16(ap, bv, o, 0, 0, 0);
#pragma unroll
                for (int r = 0; r < 4; r++){
                    int row = it*16 + rgrp + r;
                    aout16[((long)(g*32 + row))*Cq + h*64 + dt*16 + colj] =
                        f2b(o[r] * linv[row]);
                }
            }
        }
        __syncthreads();
    }
}

// ---------------- inverse-distance interp: 8 points/block share vis reads ----
__global__ void __launch_bounds__(128) interp_k(const float* __restrict__ Xf,
    const float* __restrict__ vis, const float* __restrict__ c1,
    const float* __restrict__ c2, float* __restrict__ newx)
{
    __shared__ float wsh[8*128];
    __shared__ float inv8[8];
    int blk = blockIdx.x;
    int b = blk >> 6, nt = blk & 63;
    int tid = threadIdx.x;
#pragma unroll
    for (int i = 0; i < 8; i++){
        int id = tid + i*128;
        int nl = id >> 7, s = id & 127;
        const float* p1 = c1 + ((long)b*Gq + nt*8 + nl)*3;
        const float* p2 = c2 + ((long)b*Sq + s)*3;
        float x1 = p1[0], y1 = p1[1], z1 = p1[2];
        float x2 = p2[0], y2 = p2[1], z2 = p2[2];
        float d = (x1*x1 + y1*y1 + z1*z1) + (x2*x2 + y2*y2 + z2*z2)
                - 2.f*(x1*x2 + y1*y2 + z1*z2);
        wsh[nl*128 + s] = 1.f/(d + 1e-8f);
    }
    __syncthreads();
    if (tid < 8){
        float sum = 0.f;
        for (int s = 0; s < Sq; s++) sum += wsh[tid*128 + s];
        inv8[tid] = 1.f/sum;
    }
    __syncthreads();
    float acc[8][3];
#pragma unroll
    for (int n = 0; n < 8; n++){ acc[n][0] = 0.f; acc[n][1] = 0.f; acc[n][2] = 0.f; }
    const float* vb = vis + (long)b*Sq*Cq + tid;
    for (int s = 0; s < Sq; s++){
        float v0 = vb[s*Cq], v1 = vb[s*Cq + 128], v2 = vb[s*Cq + 256];
#pragma unroll
        for (int n = 0; n < 8; n++){
            float wq = wsh[n*128 + s];
            acc[n][0] += wq*v0; acc[n][1] += wq*v1; acc[n][2] += wq*v2;
        }
    }
#pragma unroll
    for (int n = 0; n < 8; n++){
        int gn = nt*8 + n;
        const float* xr = Xf + ((long)(b*NSEQ + Tq + gn))*Cq;
        float* orow = newx + ((long)(b*Gq + gn))*Cq;
        float sf = 0.4f * inv8[n];
        orow[tid]       = xr[tid]       + sf*acc[n][0];
        orow[tid + 128] = xr[tid + 128] + sf*acc[n][1];
        orow[tid + 256] = xr[tid + 256] + sf*acc[n][2];
    }
}

// ---------------- launch ----------------
extern "C" void kernel_launch(void* const* d_in, const int* in_sizes, int n_in,
                              void* d_out, int out_size, void* d_ws, size_t ws_size,
                              hipStream_t stream)
{
    const float* x_in  = (const float*)d_in[0];
    const float* mask  = (const float*)d_in[1];
    const float* c1p   = (const float*)d_in[2];
    const float* c2p   = (const float*)d_in[3];
    const float* pe    = (const float*)d_in[5];
    const float* n1g   = (const float*)d_in[6];
    const float* n1b   = (const float*)d_in[7];
    const float* qkvw  = (const float*)d_in[8];
    const float* projw = (const float*)d_in[9];
    const float* projb = (const float*)d_in[10];
    const float* n2g   = (const float*)d_in[11];
    const float* n2b   = (const float*)d_in[12];
    const float* fc1w  = (const float*)d_in[13];
    const float* fc1b  = (const float*)d_in[14];
    const float* fc2w  = (const float*)d_in[15];
    const float* fc2b  = (const float*)d_in[16];
    const float* gate  = (const float*)d_in[17];
    const float* addw  = (const float*)d_in[18];
    const float* addb  = (const float*)d_in[19];
    const float* aduw  = (const float*)d_in[20];
    const float* adub  = (const float*)d_in[21];
    const float* ad1dw = (const float*)d_in[22];
    const float* ad1db = (const float*)d_in[23];
    const float* ad1uw = (const float*)d_in[24];
    const float* ad1ub = (const float*)d_in[25];
    const float* bng   = (const float*)d_in[26];
    const float* bnb   = (const float*)d_in[27];
    const float* a1qkvw= (const float*)d_in[28];
    const float* a1pw  = (const float*)d_in[29];
    const float* a1pb  = (const float*)d_in[30];
    const float* n3g   = (const float*)d_in[31];
    const float* n3b   = (const float*)d_in[32];
    const int*   idxp  = (const int*)d_in[33];
    const int*   cidxp = (const int*)d_in[34];

    // ---- workspace layout (bytes), total 252.4 MB ----
    char* w = (char*)d_ws;
    float* X    = (float*)w;                       // 16896x384 f32   [0, 25952256)
    u16*   WB   = (u16*)(w + 25952256);            // bf16 weights
    u16*   Bb16 = (u16*)(w + 30670848);            // 16896x384 bf16
    char*  R1   = w + 43646976;                    // 100663296 B (bias16 / hid16 / aout16)
    char*  R2   = R1 + 100663296;                  // 100663296 B (QKVg/C1/newx + X16)
    float* V    = (float*)(R2 + 100663296);        // 4096x384 f32

    u16* qkvw16  = WB;
    u16* projw16 = WB +  442368;
    u16* fc1w16  = WB +  589824;
    u16* fc2w16  = WB + 1179648;
    u16* a1qkv16 = WB + 1769472;
    u16* a1pw16  = WB + 2211840;

    u16*   bias16 = (u16*)R1;       // 32x512x512 bf16 (dead before fc1)
    u16*   hid16  = (u16*)R1;       // 16896x1536 bf16 (MLP phase)
    u16*   aout16 = (u16*)R1;       // 131072x384 bf16 (local phase)
    u16*   QKVg   = (u16*)R2;       // 16896x1152 bf16 [R2, R2+38.9MB)
    float* C1     = (float*)R2;     // 16896x384 f32 x_fn (dead after adapter#1)
    float* newx   = (float*)R2;     // 16384x384 f32 (interp out; QKVg dead then)
    u16*   X16    = (u16*)(R2 + 41943040);  // 16896x384 bf16 [40MB, 53MB) of R2

    prep<<<21632, 256, 0, stream>>>(qkvw, projw, fc1w, fc2w, a1qkvw, a1pw, WB,
                                    mask, bias16, x_in, pe, n1g, n1b, X, Bb16);
    gemm_bf16<<<dim3(9, 132), 512, 0, stream>>>(Bb16, qkvw16, nullptr, nullptr, QKVg,
                                                ROWS, 1152, Cq, 4);
    attn_mfma<<<1728, 256, 0, stream>>>(QKVg, bias16, Bb16);
    gemm_bf16<<<dim3(3, 132), 512, 0, stream>>>(Bb16, projw16, projb, X, nullptr,
                                                ROWS, Cq, Cq, 3);
    ln_rows<<<4224, 256, 0, stream>>>(X, n2g, n2b, Bb16, ROWS);
    gemm_bf16<<<dim3(12, 132), 512, 0, stream>>>(Bb16, fc1w16, fc1b, nullptr, hid16,
                                                 ROWS, 1536, Cq, 2);
    gemm_bf16<<<dim3(3, 132), 512, 0, stream>>>(hid16, fc2w16, fc2b, C1, nullptr,
                                                ROWS, Cq, 1536, 1);
    // fused: x = gate*adapter(x_fn)+x ; X16 = bf16(x); Bb16 = LN3(x)
    adapter_fused<<<4224, 256, 0, stream>>>(C1, X, addw, addb, aduw, adub, gate,
                                            n3g, n3b, X, X16, Bb16, ROWS);
    // local branch
    gemm_bf16<<<dim3(9, 132), 512, 0, stream>>>(Bb16, a1qkv16, nullptr, nullptr, QKVg,
                                                ROWS, 1152, Cq, 4);
    local_attn<<<4096, 256, 0, stream>>>(QKVg, idxp, aout16);
    gemm_pool<<<3072, 512, 0, stream>>>(aout16, a1pw16, a1pb, idxp, cidxp,
                                        X16, bng, bnb, V, Cq);
    interp_k<<<2048, 128, 0, stream>>>(X, V, c1p, c2p, newx);
    // fused final adapter -> d_out
    adapter_fused<<<4096, 256, 0, stream>>>(newx, nullptr, ad1dw, ad1db, ad1uw, ad1ub,
                                            nullptr, nullptr, nullptr,
                                            (float*)d_out, nullptr, nullptr, Bq*Gq);
}

// Round 13
// 657.142 us; speedup vs baseline: 1.7337x; 1.0544x over previous
//
#include <hip/hip_runtime.h>
#include <hip/hip_bf16.h>

// ---------------- constants ----------------
#define Bq 32
#define Tq 16
#define Gq 512
#define NSEQ 528           // T + G
#define Cq 384
#define Hq 6
#define Sq 128
#define Kg 32              // GROUP_SIZE
#define ROWS (Bq*NSEQ)     // 16896
#define LROWS (Bq*Sq*Kg)   // 131072 local tokens

typedef unsigned short u16;
typedef short bf16x8 __attribute__((ext_vector_type(8)));   // 8 bf16 in 4 VGPRs
typedef float f32x4  __attribute__((ext_vector_type(4)));

__device__ __forceinline__ float gelu_f(float x){
    return 0.5f * x * (1.0f + erff(x * 0.70710678118654752f));
}
__device__ __forceinline__ u16 f2b(float x){
    union { float f; unsigned u; } v; v.f = x;
    return (u16)((v.u + 0x7fffu + ((v.u >> 16) & 1u)) >> 16);
}
__device__ __forceinline__ float b2f(u16 h){
    union { float f; unsigned u; } v; v.u = ((unsigned)h) << 16; return v.f;
}

// async global->LDS, 16B per lane. dest = wave-uniform base + lane*16.
__device__ __forceinline__ void gload16(const u16* g, u16* l){
    __builtin_amdgcn_global_load_lds(
        (const __attribute__((address_space(1))) unsigned int*)(g),
        (__attribute__((address_space(3))) unsigned int*)(l), 16, 0, 0);
}

// ---------------- merged prep: conv6 | conv_mask | build_ln ----------------
__global__ void __launch_bounds__(256) prep(const float* __restrict__ qkvw,
    const float* __restrict__ projw, const float* __restrict__ fc1w,
    const float* __restrict__ fc2w, const float* __restrict__ a1qkvw,
    const float* __restrict__ a1pw, u16* __restrict__ WB,
    const float* __restrict__ mask, u16* __restrict__ bias16,
    const float* __restrict__ xin, const float* __restrict__ pe,
    const float* __restrict__ gw, const float* __restrict__ bw,
    float* __restrict__ X, u16* __restrict__ out)
{
    int bid = blockIdx.x;
    if (bid < 9216){
        long i = (long)bid*256 + threadIdx.x;
        if (i >= 2359296) return;
        float v;
        if      (i <  442368) v = qkvw[i];
        else if (i <  589824) v = projw[i -  442368];
        else if (i < 1179648) v = fc1w[i -  589824];
        else if (i < 1769472) v = fc2w[i - 1179648];
        else if (i < 2211840) v = a1qkvw[i - 1769472];
        else                  v = a1pw[i - 2211840];
        WB[i] = f2b(v);
        return;
    }
    if (bid < 17408){
        long i = (long)(bid - 9216)*256 + threadIdx.x;
        if (i >= ((long)Bq*Gq*Gq >> 2)) return;
        float4 v = *(const float4*)(mask + i*4);
        ushort4 r;
        r.x = f2b(-100000.0f * v.x);
        r.y = f2b(-100000.0f * v.y);
        r.z = f2b(-100000.0f * v.z);
        r.w = f2b(-100000.0f * v.w);
        *(ushort4*)(bias16 + i*4) = r;
        return;
    }
    {
        int w = threadIdx.x >> 6, lane = threadIdx.x & 63;
        int row = (bid - 17408)*4 + w;
        if (row >= ROWS) return;
        int p = row % NSEQ; int b = row / NSEQ;
        const float* src = (p < Tq) ? (pe + (long)p*Cq)
                                    : (xin + ((long)b*Gq + (p - Tq))*Cq);
        float v[6]; float s = 0.f, s2 = 0.f;
#pragma unroll
        for (int j = 0; j < 6; j++){ float x = src[lane + 64*j]; v[j] = x; s += x; s2 += x*x; }
#pragma unroll
        for (int m = 1; m < 64; m <<= 1){ s += __shfl_xor(s, m); s2 += __shfl_xor(s2, m); }
        float mean = s * (1.f/384.f);
        float var  = s2 * (1.f/384.f) - mean*mean;
        float rs   = rsqrtf(var + 1e-5f);
        float* xrow = X + (long)row*Cq;
        u16* orow = out + (long)row*Cq;
#pragma unroll
        for (int j = 0; j < 6; j++){
            int c = lane + 64*j;
            xrow[c] = v[j];
            orow[c] = f2b((v[j] - mean) * rs * gw[c] + bw[c]);
        }
    }
}

// ---------------- LayerNorm, one wave per row, bf16 out ----------------
__global__ void __launch_bounds__(256) ln_rows(const float* __restrict__ in,
    const float* __restrict__ gw, const float* __restrict__ bw,
    u16* __restrict__ out, int rows)
{
    int w = threadIdx.x >> 6, lane = threadIdx.x & 63;
    int row = blockIdx.x*4 + w;
    if (row >= rows) return;
    const float* xr = in + (long)row*Cq;
    float v[6]; float s = 0.f, s2 = 0.f;
#pragma unroll
    for (int j = 0; j < 6; j++){ float x = xr[lane + 64*j]; v[j] = x; s += x; s2 += x*x; }
#pragma unroll
    for (int m = 1; m < 64; m <<= 1){ s += __shfl_xor(s, m); s2 += __shfl_xor(s2, m); }
    float mean = s * (1.f/384.f);
    float var  = s2 * (1.f/384.f) - mean*mean;
    float rs   = rsqrtf(var + 1e-5f);
    u16* orow = out + (long)row*Cq;
#pragma unroll
    for (int j = 0; j < 6; j++){
        int c = lane + 64*j;
        orow[c] = f2b((v[j] - mean) * rs * gw[c] + bw[c]);
    }
}

// ---------------- bf16 MFMA GEMM: C = epi(A @ W^T) ----------------
// R8-proven config: 512 threads / 8 waves (2m x 4n), 128x128 tile,
// acc[4][2]=32 AGPR, 2-buffer double-buffered gload_lds staging,
// XCD-aware bijective block remap. (7 structural variants measured worse.)
__global__ void __launch_bounds__(512, 4) gemm_bf16(const u16* __restrict__ A,
    const u16* __restrict__ W, const float* __restrict__ bias,
    float* __restrict__ Cf, u16* __restrict__ Cb, int M, int N, int K, int epi)
{
    __shared__ u16 As0[128*32];
    __shared__ u16 As1[128*32];
    __shared__ u16 Ws0[128*32];
    __shared__ u16 Ws1[128*32];
    int t = threadIdx.x;
    int nx = gridDim.x;
    int nwg = nx * gridDim.y;
    int f = blockIdx.y*nx + blockIdx.x;
    int xcd = f & 7, i = f >> 3;
    int q = nwg >> 3, r = nwg & 7;
    int base = (xcd < r) ? xcd*(q+1) : r*(q+1) + (xcd - r)*q;
    int nf = base + i;
    int m0 = (nf / nx)*128, n0 = (nf % nx)*128;
    int wv = t >> 6, lane = t & 63;
    int wm = (wv >> 2)*64, wn = (wv & 3)*32;
    int fm = lane & 15;
    int fkp = (((lane >> 4) ^ ((fm >> 1) & 3)) & 3) * 8;
    int rs  = t >> 2;
    int kc8 = (((lane & 3) ^ ((lane >> 3) & 3))) * 8;
    f32x4 acc[4][2];
#pragma unroll
    for (int ii = 0; ii < 4; ii++)
#pragma unroll
        for (int j = 0; j < 2; j++) acc[ii][j] = (f32x4){0.f,0.f,0.f,0.f};

    auto STG = [&](u16* Ab, u16* Wb, int k0){
        gload16(A + (long)(m0 + rs)*K + k0 + kc8, Ab + wv*512);
        gload16(W + (long)(n0 + rs)*K + k0 + kc8, Wb + wv*512);
    };
    auto CMP = [&](const u16* Ab, const u16* Wb){
        bf16x8 af[4], bf[2];
#pragma unroll
        for (int im = 0; im < 4; im++) af[im] = *(const bf16x8*)&Ab[(wm + im*16 + fm)*32 + fkp];
#pragma unroll
        for (int in = 0; in < 2; in++) bf[in] = *(const bf16x8*)&Wb[(wn + in*16 + fm)*32 + fkp];
#pragma unroll
        for (int im = 0; im < 4; im++)
#pragma unroll
            for (int in = 0; in < 2; in++)
                acc[im][in] = __builtin_amdgcn_mfma_f32_16x16x32_bf16(af[im], bf[in], acc[im][in], 0, 0, 0);
    };

    int nt = K >> 5;                 // 12 or 48 -> always even
    STG(As0, Ws0, 0);
    __syncthreads();
    for (int kt = 0; kt < nt; kt += 2){
        STG(As1, Ws1, (kt+1)*32);
        CMP(As0, Ws0);
        __syncthreads();
        if (kt + 2 < nt) STG(As0, Ws0, (kt+2)*32);
        CMP(As1, Ws1);
        __syncthreads();
    }

    int lr = lane >> 4, lc = lane & 15;
#pragma unroll
    for (int im = 0; im < 4; im++){
#pragma unroll
        for (int in = 0; in < 2; in++){
#pragma unroll
            for (int r2 = 0; r2 < 4; r2++){
                int m = m0 + wm + im*16 + lr*4 + r2;
                int n = n0 + wn + in*16 + lc;
                float v = acc[im][in][r2];
                if (epi >= 1 && bias) v += bias[n];
                if (epi == 2) v = gelu_f(v);
                long off = (long)m*N + n;
                if (epi == 3) v += Cf[off];
                if (epi == 2 || epi == 4) Cb[off] = f2b(v);
                else                      Cf[off] = v;
            }
        }
    }
}

// ---------------- local proj GEMM with fused pool epilogue ----------------
// Pure R8 config (T14 hoist measured -10us, reverted).
__global__ void __launch_bounds__(512, 4) gemm_pool(const u16* __restrict__ A,
    const u16* __restrict__ W, const float* __restrict__ bias,
    const int* __restrict__ idx, const int* __restrict__ cidx,
    const u16* __restrict__ X16, const float* __restrict__ bng,
    const float* __restrict__ bnb, float* __restrict__ vis, int K)
{
    __shared__ u16 As0[128*32];
    __shared__ u16 As1[128*32];
    __shared__ u16 Ws0[128*32];
    __shared__ u16 Ws1[128*32];
    __shared__ int idxl[128];
    __shared__ int cidxl[4];
    int t = threadIdx.x;
    int blkf = blockIdx.x;
    int xcd = blkf & 7, slot = blkf >> 3;        // 3072 -> 384 slots/xcd
    int m0 = (xcd*128 + slot/3)*128;
    int n0 = (slot % 3)*128;
    if (t < 128) idxl[t] = idx[m0 + t];
    if (t < 4)   cidxl[t] = cidx[(m0 >> 5) + t];
    int wv = t >> 6, lane = t & 63;
    int wm = (wv >> 2)*64, wn = (wv & 3)*32;
    int fm = lane & 15;
    int fkp = (((lane >> 4) ^ ((fm >> 1) & 3)) & 3) * 8;
    int rs  = t >> 2;
    int kc8 = (((lane & 3) ^ ((lane >> 3) & 3))) * 8;
    f32x4 acc[4][2];
#pragma unroll
    for (int ii = 0; ii < 4; ii++)
#pragma unroll
        for (int j = 0; j < 2; j++) acc[ii][j] = (f32x4){0.f,0.f,0.f,0.f};

    auto STG = [&](u16* Ab, u16* Wb, int k0){
        gload16(A + (long)(m0 + rs)*K + k0 + kc8, Ab + wv*512);
        gload16(W + (long)(n0 + rs)*K + k0 + kc8, Wb + wv*512);
    };
    auto CMP = [&](const u16* Ab, const u16* Wb){
        bf16x8 af[4], bf[2];
#pragma unroll
        for (int im = 0; im < 4; im++) af[im] = *(const bf16x8*)&Ab[(wm + im*16 + fm)*32 + fkp];
#pragma unroll
        for (int in = 0; in < 2; in++) bf[in] = *(const bf16x8*)&Wb[(wn + in*16 + fm)*32 + fkp];
#pragma unroll
        for (int im = 0; im < 4; im++)
#pragma unroll
            for (int in = 0; in < 2; in++)
                acc[im][in] = __builtin_amdgcn_mfma_f32_16x16x32_bf16(af[im], bf[in], acc[im][in], 0, 0, 0);
    };

    int nt = K >> 5;                 // K=384 -> 12
    STG(As0, Ws0, 0);
    __syncthreads();
    for (int kt = 0; kt < nt; kt += 2){
        STG(As1, Ws1, (kt+1)*32);
        CMP(As0, Ws0);
        __syncthreads();
        if (kt + 2 < nt) STG(As0, Ws0, (kt+2)*32);
        CMP(As1, Ws1);
        __syncthreads();
    }

    int lr = lane >> 4, lc = lane & 15;
#pragma unroll
    for (int in = 0; in < 2; in++){
        int c = n0 + wn + in*16 + lc;
        float pb = bias[c];
        float bg = bng[c], bb = bnb[c];
#pragma unroll
        for (int gl = 0; gl < 2; gl++){
            float vmax = -3e38f, vsum = 0.f;
#pragma unroll
            for (int i2 = 0; i2 < 2; i2++){
                int im = gl*2 + i2;
#pragma unroll
                for (int r = 0; r < 4; r++){
                    int rl = wm + im*16 + lr*4 + r;
                    float val = acc[im][in][r] + pb + b2f(X16[(long)idxl[rl]*Cq + c]);
                    vmax = fmaxf(vmax, val); vsum += val;
                }
            }
            vmax = fmaxf(vmax, __shfl_xor(vmax, 16)); vsum += __shfl_xor(vsum, 16);
            vmax = fmaxf(vmax, __shfl_xor(vmax, 32)); vsum += __shfl_xor(vsum, 32);
            if (lane < 16){
                int glb = (wm >> 5) + gl;
                float lcv = vmax + vsum*(1.f/32.f);
                float u = gelu_f(lcv*bg*0.9999950000374997f + bb);
                vis[((long)(m0 >> 5) + glb)*Cq + c] =
                    u + 0.4f*b2f(X16[(long)cidxl[glb]*Cq + c]);
            }
        }
    }
}

// ---------------- flash-style MFMA global attention v4 ----------------
// Register-prefetch staging + 2 barriers/iter + V column XOR swizzle.
__global__ void __launch_bounds__(256) attn_mfma(const u16* __restrict__ QKVg,
    const u16* __restrict__ bias16, u16* __restrict__ out)
{
    __shared__ u16 Ks[32*72];
    __shared__ u16 Vt[64*40];
    __shared__ u16 Bs[64*36];
    __shared__ u16 Pb[4][16*40];
    int blk = blockIdx.x;
    int xcd = blk & 7; int r0 = blk >> 3;
    int bb = r0 & 3;  int rr = r0 >> 2;
    int h = rr % 6;   int qt = rr / 6;
    int b = xcd + 8*bb;
    int t = threadIdx.x; int w = t >> 6; int lane = t & 63;
    int fr  = lane & 15;
    int fko = (lane >> 4) * 8;
    int colj = lane & 15;
    int rgrp = (lane >> 4) * 4;
    int qb0 = qt*64;
    int q0 = qb0 + w*16;

    int qr = q0 + fr; int qrc = qr < NSEQ ? qr : NSEQ-1;
    const u16* qbase = QKVg + (long)(b*NSEQ + qrc)*1152 + h*64;
    bf16x8 aq0 = *(const bf16x8*)(qbase + fko);
    bf16x8 aq1 = *(const bf16x8*)(qbase + 32 + fko);

    f32x4 oacc[4];
#pragma unroll
    for (int d = 0; d < 4; d++) oacc[d] = (f32x4){0.f,0.f,0.f,0.f};
    float lsum[4] = {0.f, 0.f, 0.f, 0.f};

    int skey = t >> 3;
    int sd8  = (t & 7) * 8;
    int jswz = skey ^ ((t & 3) << 3);      // (d>>3)&3 == t&3 for this thread
    int brow = t >> 2;
    int bc8  = (t & 3) * 8;

    bf16x8 kvR = {0,0,0,0,0,0,0,0}, vvR = {0,0,0,0,0,0,0,0};
    uint4  bzR = make_uint4(0u,0u,0u,0u);
    auto LD = [&](int kc){
        int j = kc*32 + skey;
        bf16x8 kv = {0,0,0,0,0,0,0,0};
        bf16x8 vv = {0,0,0,0,0,0,0,0};
        if (j < NSEQ){
            const u16* kb = QKVg + (long)(b*NSEQ + j)*1152 + 384 + h*64 + sd8;
            kv = *(const bf16x8*)kb;
            vv = *(const bf16x8*)(kb + 384);
        }
        int qi = qb0 + brow;
        int jj = kc*32 + bc8;
        uint4 bz = make_uint4(0u,0u,0u,0u);
        if (qi < Gq && jj < Gq)
            bz = *(const uint4*)(bias16 + ((long)b*Gq + qi)*Gq + jj);
        kvR = kv; vvR = vv; bzR = bz;
    };
    LD(0);

    for (int kc = 0; kc < 17; kc++){
        __syncthreads();               // prev PV done -> safe to overwrite stage
        *(bf16x8*)&Ks[skey*72 + sd8] = kvR;
#pragma unroll
        for (int e = 0; e < 8; e++) Vt[(sd8+e)*40 + jswz] = (u16)vvR[e];
        *(uint4*)&Bs[brow*36 + bc8] = bzR;
        if (kc < 16) LD(kc + 1);       // prefetch: in flight during compute
        __syncthreads();               // staged tile visible

        f32x4 s[2];
#pragma unroll
        for (int sub = 0; sub < 2; sub++){
            bf16x8 bk0 = *(const bf16x8*)&Ks[(sub*16 + fr)*72 + fko];
            bf16x8 bk1 = *(const bf16x8*)&Ks[(sub*16 + fr)*72 + 32 + fko];
            f32x4 z = (f32x4){0.f,0.f,0.f,0.f};
            z = __builtin_amdgcn_mfma_f32_16x16x32_bf16(aq0, bk0, z, 0, 0, 0);
            z = __builtin_amdgcn_mfma_f32_16x16x32_bf16(aq1, bk1, z, 0, 0, 0);
            s[sub] = z;
        }
#pragma unroll
        for (int sub = 0; sub < 2; sub++){
#pragma unroll
            for (int r = 0; r < 4; r++){
                int jj = kc*32 + sub*16 + colj;
                float sv = s[sub][r] * 0.125f
                         + b2f(Bs[(w*16 + rgrp + r)*36 + sub*16 + colj]);
                if (jj >= NSEQ) sv = -1e30f;
                float e = __expf(sv);
                lsum[r] += e;
                Pb[w][(rgrp + r)*40 + sub*16 + colj] = f2b(e);
            }
        }
        // no barrier: Pb[w] written and read by the same wave.
        bf16x8 ap = *(const bf16x8*)&Pb[w][fr*40 + fko];
#pragma unroll
        for (int d = 0; d < 4; d++){
            int D = d*16 + fr;
            int fkv = fko ^ (((D >> 3) & 3) << 3);
            bf16x8 bv = *(const bf16x8*)&Vt[D*40 + fkv];
            oacc[d] = __builtin_amdgcn_mfma_f32_16x16x32_bf16(ap, bv, oacc[d], 0, 0, 0);
        }
    }
#pragma unroll
    for (int r = 0; r < 4; r++){
#pragma unroll
        for (int mm = 1; mm < 16; mm <<= 1) lsum[r] += __shfl_xor(lsum[r], mm);
    }
#pragma unroll
    for (int r = 0; r < 4; r++){
        int qi = q0 + rgrp + r;
        if (qi < NSEQ){
            float inv = 1.0f / lsum[r];
#pragma unroll
            for (int d = 0; d < 4; d++)
                out[((long)(b*NSEQ + qi))*Cq + h*64 + d*16 + colj] = f2b(oacc[d][r]*inv);
        }
    }
}

// ---------------- fused adapter (one wave per row) ----------------
// v = gate*(gelu(xfn@dw^T+db)@uw^T + ub + xfn) + resid; Xout=v;
// Stage-major butterfly: batch 8 partials, then 6 shfl stages over all 8
// (independent DS ops pipeline) -> serial DS depth cut ~8x vs per-r chains.
__global__ void __launch_bounds__(256) adapter_fused(const float* __restrict__ xfn,
    const float* __restrict__ resid,
    const float* __restrict__ dw, const float* __restrict__ db,
    const float* __restrict__ uw, const float* __restrict__ ub,
    const float* __restrict__ gatep,
    const float* __restrict__ lng, const float* __restrict__ lnb,
    float* __restrict__ Xout, u16* __restrict__ x16out,
    u16* __restrict__ ln16, int rows)
{
    int w = threadIdx.x >> 6, lane = threadIdx.x & 63;
    int row = blockIdx.x*4 + w;
    if (row >= rows) return;
    const float* xr = xfn + (long)row*Cq;
    float xv[6];
#pragma unroll
    for (int j = 0; j < 6; j++) xv[j] = xr[lane + 64*j];
    float hid[16];
#pragma unroll
    for (int rb = 0; rb < 2; rb++){
        float p[8];
#pragma unroll
        for (int rr = 0; rr < 8; rr++){
            const float* dr = dw + (rb*8 + rr)*Cq;
            float pp = 0.f;
#pragma unroll
            for (int j = 0; j < 6; j++) pp += xv[j]*dr[lane + 64*j];
            p[rr] = pp;
        }
#pragma unroll
        for (int mm = 1; mm < 64; mm <<= 1){
#pragma unroll
            for (int rr = 0; rr < 8; rr++) p[rr] += __shfl_xor(p[rr], mm);
        }
#pragma unroll
        for (int rr = 0; rr < 8; rr++) hid[rb*8 + rr] = gelu_f(p[rr] + db[rb*8 + rr]);
    }
    float gate = gatep ? gatep[0] : 1.0f;
    float ov[6];
    float s = 0.f, s2 = 0.f;
#pragma unroll
    for (int j = 0; j < 6; j++){
        int c = lane + 64*j;
        const float* uc = uw + c*16;
        float a = 0.f;
#pragma unroll
        for (int r = 0; r < 16; r++) a += hid[r]*uc[r];
        float v = gate * (a + ub[c] + xv[j]);
        if (resid) v += resid[(long)row*Cq + c];
        ov[j] = v;
        Xout[(long)row*Cq + c] = v;
        if (x16out) x16out[(long)row*Cq + c] = f2b(v);
        s += v; s2 += v*v;
    }
    if (lng){
#pragma unroll
        for (int m = 1; m < 64; m <<= 1){ s += __shfl_xor(s, m); s2 += __shfl_xor(s2, m); }
        float mean = s * (1.f/384.f);
        float var  = s2 * (1.f/384.f) - mean*mean;
        float rs   = rsqrtf(var + 1e-5f);
        u16* orow = ln16 + (long)row*Cq;
#pragma unroll
        for (int j = 0; j < 6; j++){
            int c = lane + 64*j;
            orow[c] = f2b((ov[j] - mean)*rs*lng[c] + lnb[c]);
        }
    }
}

// ---------------- local branch: MFMA attention, 1 group / 256-thr block ------
__global__ void __launch_bounds__(256) local_attn(const u16* __restrict__ QKVg,
    const int* __restrict__ idx, u16* __restrict__ aout16)
{
    __shared__ u16 Qs[32*72];
    __shared__ u16 Ksm[32*72];
    __shared__ u16 Vt[64*40];
    __shared__ float sc[32*36];
    __shared__ u16 Pa[32*40];
    __shared__ float linv[32];
    __shared__ int rows[32];
    int g = blockIdx.x;
    int t = threadIdx.x;
    int w = t >> 6, lane = t & 63;
    if (t < 32) rows[t] = idx[g*Kg + t];
    __syncthreads();
    int srow = t & 31;
    int d8   = (t >> 5) * 8;
    int jswz = srow ^ (((t >> 5) & 3) << 3);   // (d>>3)&3 == (t>>5)&3
    int fr = lane & 15, fko = (lane >> 4)*8;
    int colj = lane & 15, rgrp = (lane >> 4)*4;
    int it = w >> 1, jt = w & 1;
    int smrow = w*8 + (lane >> 3);
    int smc   = (lane & 7) * 4;

    const u16* rbase = QKVg + (long)rows[srow]*1152 + d8;
    bf16x8 qvR = *(const bf16x8*)(rbase);
    bf16x8 kvR = *(const bf16x8*)(rbase + 384);
    bf16x8 vvR = *(const bf16x8*)(rbase + 768);

    for (int h = 0; h < Hq; h++){
        *(bf16x8*)&Qs[srow*72 + d8]  = qvR;
        *(bf16x8*)&Ksm[srow*72 + d8] = kvR;
#pragma unroll
        for (int e = 0; e < 8; e++) Vt[(d8+e)*40 + jswz] = (u16)vvR[e];
        if (h < Hq-1){
            const u16* nb = rbase + (h+1)*64;
            qvR = *(const bf16x8*)(nb);
            kvR = *(const bf16x8*)(nb + 384);
            vvR = *(const bf16x8*)(nb + 768);
        }
        __syncthreads();
        {
            bf16x8 a0 = *(const bf16x8*)&Qs[(it*16+fr)*72 + fko];
            bf16x8 a1 = *(const bf16x8*)&Qs[(it*16+fr)*72 + 32 + fko];
            bf16x8 b0 = *(const bf16x8*)&Ksm[(jt*16+fr)*72 + fko];
            bf16x8 b1 = *(const bf16x8*)&Ksm[(jt*16+fr)*72 + 32 + fko];
            f32x4 z = (f32x4){0.f,0.f,0.f,0.f};
            z = __builtin_amdgcn_mfma_f32_16x16x32_bf16(a0, b0, z, 0, 0, 0);
            z = __builtin_amdgcn_mfma_f32_16x16x32_bf16(a1, b1, z, 0, 0, 0);
#pragma unroll
            for (int r = 0; r < 4; r++)
                sc[(it*16 + rgrp + r)*36 + jt*16 + colj] = z[r]*0.125f;
        }
        __syncthreads();
        {
            float4 s4 = *(const float4*)&sc[smrow*36 + smc];
            float mx = fmaxf(fmaxf(s4.x, s4.y), fmaxf(s4.z, s4.w));
#pragma unroll
            for (int mm = 1; mm < 8; mm <<= 1) mx = fmaxf(mx, __shfl_xor(mx, mm));
            float p0 = __expf(s4.x - mx), p1 = __expf(s4.y - mx);
            float p2 = __expf(s4.z - mx), p3 = __expf(s4.w - mx);
            float sm = p0 + p1 + p2 + p3;
#pragma unroll
            for (int mm = 1; mm < 8; mm <<= 1) sm += __shfl_xor(sm, mm);
            if ((lane & 7) == 0) linv[smrow] = 1.0f / sm;
            Pa[smrow*40 + smc + 0] = f2b(p0);
            Pa[smrow*40 + smc + 1] = f2b(p1);
            Pa[smrow*40 + smc + 2] = f2b(p2);
            Pa[smrow*40 + smc + 3] = f2b(p3);
        }
        __syncthreads();
        {
            bf16x8 ap = *(const bf16x8*)&Pa[(it*16+fr)*40 + fko];
#pragma unroll
            for (int dd = 0; dd < 2; dd++){
                int dt = jt + dd*2;
                int D = dt*16 + fr;
                int fkv = fko ^ (((D >> 3) & 3) << 3);
                bf16x8 bv = *(const bf16x8*)&Vt[D*40 + fkv];
                f32x4 o = (f32x4){0.f,0.f,0.f,0.f};
                o = __builtin_amdgcn_mfma_f32_16x16x32_bf16(ap, bv, o, 0, 0, 0);
#pragma unroll
                for (int r = 0; r < 4; r++){
                    int row = it*16 + rgrp + r;
                    aout16[((long)(g*32 + row))*Cq + h*64 + dt*16 + colj] =
                        f2b(o[r] * linv[row]);
                }
            }
        }
        __syncthreads();
    }
}

// ---------------- inverse-distance interp: 8 points/block share vis reads ----
__global__ void __launch_bounds__(128) interp_k(const float* __restrict__ Xf,
    const float* __restrict__ vis, const float* __restrict__ c1,
    const float* __restrict__ c2, float* __restrict__ newx)
{
    __shared__ float wsh[8*128];
    __shared__ float inv8[8];
    int blk = blockIdx.x;
    int b = blk >> 6, nt = blk & 63;
    int tid = threadIdx.x;
#pragma unroll
    for (int i = 0; i < 8; i++){
        int id = tid + i*128;
        int nl = id >> 7, s = id & 127;
        const float* p1 = c1 + ((long)b*Gq + nt*8 + nl)*3;
        const float* p2 = c2 + ((long)b*Sq + s)*3;
        float x1 = p1[0], y1 = p1[1], z1 = p1[2];
        float x2 = p2[0], y2 = p2[1], z2 = p2[2];
        float d = (x1*x1 + y1*y1 + z1*z1) + (x2*x2 + y2*y2 + z2*z2)
                - 2.f*(x1*x2 + y1*y2 + z1*z2);
        wsh[nl*128 + s] = 1.f/(d + 1e-8f);
    }
    __syncthreads();
    if (tid < 8){
        float sum = 0.f;
        for (int s = 0; s < Sq; s++) sum += wsh[tid*128 + s];
        inv8[tid] = 1.f/sum;
    }
    __syncthreads();
    float acc[8][3];
#pragma unroll
    for (int n = 0; n < 8; n++){ acc[n][0] = 0.f; acc[n][1] = 0.f; acc[n][2] = 0.f; }
    const float* vb = vis + (long)b*Sq*Cq + tid;
    for (int s = 0; s < Sq; s++){
        float v0 = vb[s*Cq], v1 = vb[s*Cq + 128], v2 = vb[s*Cq + 256];
#pragma unroll
        for (int n = 0; n < 8; n++){
            float wq = wsh[n*128 + s];
            acc[n][0] += wq*v0; acc[n][1] += wq*v1; acc[n][2] += wq*v2;
        }
    }
#pragma unroll
    for (int n = 0; n < 8; n++){
        int gn = nt*8 + n;
        const float* xr = Xf + ((long)(b*NSEQ + Tq + gn))*Cq;
        float* orow = newx + ((long)(b*Gq + gn))*Cq;
        float sf = 0.4f * inv8[n];
        orow[tid]       = xr[tid]       + sf*acc[n][0];
        orow[tid + 128] = xr[tid + 128] + sf*acc[n][1];
        orow[tid + 256] = xr[tid + 256] + sf*acc[n][2];
    }
}

// ---------------- launch ----------------
extern "C" void kernel_launch(void* const* d_in, const int* in_sizes, int n_in,
                              void* d_out, int out_size, void* d_ws, size_t ws_size,
                              hipStream_t stream)
{
    const float* x_in  = (const float*)d_in[0];
    const float* mask  = (const float*)d_in[1];
    const float* c1p   = (const float*)d_in[2];
    const float* c2p   = (const float*)d_in[3];
    const float* pe    = (const float*)d_in[5];
    const float* n1g   = (const float*)d_in[6];
    const float* n1b   = (const float*)d_in[7];
    const float* qkvw  = (const float*)d_in[8];
    const float* projw = (const float*)d_in[9];
    const float* projb = (const float*)d_in[10];
    const float* n2g   = (const float*)d_in[11];
    const float* n2b   = (const float*)d_in[12];
    const float* fc1w  = (const float*)d_in[13];
    const float* fc1b  = (const float*)d_in[14];
    const float* fc2w  = (const float*)d_in[15];
    const float* fc2b  = (const float*)d_in[16];
    const float* gate  = (const float*)d_in[17];
    const float* addw  = (const float*)d_in[18];
    const float* addb  = (const float*)d_in[19];
    const float* aduw  = (const float*)d_in[20];
    const float* adub  = (const float*)d_in[21];
    const float* ad1dw = (const float*)d_in[22];
    const float* ad1db = (const float*)d_in[23];
    const float* ad1uw = (const float*)d_in[24];
    const float* ad1ub = (const float*)d_in[25];
    const float* bng   = (const float*)d_in[26];
    const float* bnb   = (const float*)d_in[27];
    const float* a1qkvw= (const float*)d_in[28];
    const float* a1pw  = (const float*)d_in[29];
    const float* a1pb  = (const float*)d_in[30];
    const float* n3g   = (const float*)d_in[31];
    const float* n3b   = (const float*)d_in[32];
    const int*   idxp  = (const int*)d_in[33];
    const int*   cidxp = (const int*)d_in[34];

    // ---- workspace layout (bytes), total 252.4 MB ----
    char* w = (char*)d_ws;
    float* X    = (float*)w;                       // 16896x384 f32   [0, 25952256)
    u16*   WB   = (u16*)(w + 25952256);            // bf16 weights
    u16*   Bb16 = (u16*)(w + 30670848);            // 16896x384 bf16
    char*  R1   = w + 43646976;                    // 100663296 B (bias16 / hid16 / aout16)
    char*  R2   = R1 + 100663296;                  // 100663296 B (QKVg/C1/newx + X16)
    float* V    = (float*)(R2 + 100663296);        // 4096x384 f32

    u16* qkvw16  = WB;
    u16* projw16 = WB +  442368;
    u16* fc1w16  = WB +  589824;
    u16* fc2w16  = WB + 1179648;
    u16* a1qkv16 = WB + 1769472;
    u16* a1pw16  = WB + 2211840;

    u16*   bias16 = (u16*)R1;       // 32x512x512 bf16 (dead before fc1)
    u16*   hid16  = (u16*)R1;       // 16896x1536 bf16 (MLP phase)
    u16*   aout16 = (u16*)R1;       // 131072x384 bf16 (local phase)
    u16*   QKVg   = (u16*)R2;       // 16896x1152 bf16 [R2, R2+38.9MB)
    float* C1     = (float*)R2;     // 16896x384 f32 x_fn (dead after adapter#1)
    float* newx   = (float*)R2;     // 16384x384 f32 (interp out; QKVg dead then)
    u16*   X16    = (u16*)(R2 + 41943040);  // 16896x384 bf16 [40MB, 53MB) of R2

    prep<<<21632, 256, 0, stream>>>(qkvw, projw, fc1w, fc2w, a1qkvw, a1pw, WB,
                                    mask, bias16, x_in, pe, n1g, n1b, X, Bb16);
    gemm_bf16<<<dim3(9, 132), 512, 0, stream>>>(Bb16, qkvw16, nullptr, nullptr, QKVg,
                                                ROWS, 1152, Cq, 4);
    attn_mfma<<<1728, 256, 0, stream>>>(QKVg, bias16, Bb16);
    gemm_bf16<<<dim3(3, 132), 512, 0, stream>>>(Bb16, projw16, projb, X, nullptr,
                                                ROWS, Cq, Cq, 3);
    ln_rows<<<4224, 256, 0, stream>>>(X, n2g, n2b, Bb16, ROWS);
    gemm_bf16<<<dim3(12, 132), 512, 0, stream>>>(Bb16, fc1w16, fc1b, nullptr, hid16,
                                                 ROWS, 1536, Cq, 2);
    gemm_bf16<<<dim3(3, 132), 512, 0, stream>>>(hid16, fc2w16, fc2b, C1, nullptr,
                                                ROWS, Cq, 1536, 1);
    // fused: x = gate*adapter(x_fn)+x ; X16 = bf16(x); Bb16 = LN3(x)
    adapter_fused<<<4224, 256, 0, stream>>>(C1, X, addw, addb, aduw, adub, gate,
                                            n3g, n3b, X, X16, Bb16, ROWS);
    // local branch
    gemm_bf16<<<dim3(9, 132), 512, 0, stream>>>(Bb16, a1qkv16, nullptr, nullptr, QKVg,
                                                ROWS, 1152, Cq, 4);
    local_attn<<<4096, 256, 0, stream>>>(QKVg, idxp, aout16);
    gemm_pool<<<3072, 512, 0, stream>>>(aout16, a1pw16, a1pb, idxp, cidxp,
                                        X16, bng, bnb, V, Cq);
    interp_k<<<2048, 128, 0, stream>>>(X, V, c1p, c2p, newx);
    // fused final adapter -> d_out
    adapter_fused<<<4096, 256, 0, stream>>>(newx, nullptr, ad1dw, ad1db, ad1uw, ad1ub,
                                            nullptr, nullptr, nullptr,
                                            (float*)d_out, nullptr, nullptr, Bq*Gq);
}

// Round 14
// 651.470 us; speedup vs baseline: 1.7488x; 1.0087x over previous
//
#include <hip/hip_runtime.h>
#include <hip/hip_bf16.h>

// ---------------- constants ----------------
#define Bq 32
#define Tq 16
#define Gq 512
#define NSEQ 528           // T + G
#define Cq 384
#define Hq 6
#define Sq 128
#define Kg 32              // GROUP_SIZE
#define ROWS (Bq*NSEQ)     // 16896
#define LROWS (Bq*Sq*Kg)   // 131072 local tokens

typedef unsigned short u16;
typedef short bf16x8 __attribute__((ext_vector_type(8)));   // 8 bf16 in 4 VGPRs
typedef float f32x4  __attribute__((ext_vector_type(4)));

__device__ __forceinline__ float gelu_f(float x){
    return 0.5f * x * (1.0f + erff(x * 0.70710678118654752f));
}
__device__ __forceinline__ u16 f2b(float x){
    union { float f; unsigned u; } v; v.f = x;
    return (u16)((v.u + 0x7fffu + ((v.u >> 16) & 1u)) >> 16);
}
__device__ __forceinline__ float b2f(u16 h){
    union { float f; unsigned u; } v; v.u = ((unsigned)h) << 16; return v.f;
}

// async global->LDS, 16B per lane. dest = wave-uniform base + lane*16.
__device__ __forceinline__ void gload16(const u16* g, u16* l){
    __builtin_amdgcn_global_load_lds(
        (const __attribute__((address_space(1))) unsigned int*)(g),
        (__attribute__((address_space(3))) unsigned int*)(l), 16, 0, 0);
}

// ---------------- merged prep: conv6 | conv_mask | build_ln ----------------
__global__ void __launch_bounds__(256) prep(const float* __restrict__ qkvw,
    const float* __restrict__ projw, const float* __restrict__ fc1w,
    const float* __restrict__ fc2w, const float* __restrict__ a1qkvw,
    const float* __restrict__ a1pw, u16* __restrict__ WB,
    const float* __restrict__ mask, u16* __restrict__ bias16,
    const float* __restrict__ xin, const float* __restrict__ pe,
    const float* __restrict__ gw, const float* __restrict__ bw,
    float* __restrict__ X, u16* __restrict__ out)
{
    int bid = blockIdx.x;
    if (bid < 9216){
        long i = (long)bid*256 + threadIdx.x;
        if (i >= 2359296) return;
        float v;
        if      (i <  442368) v = qkvw[i];
        else if (i <  589824) v = projw[i -  442368];
        else if (i < 1179648) v = fc1w[i -  589824];
        else if (i < 1769472) v = fc2w[i - 1179648];
        else if (i < 2211840) v = a1qkvw[i - 1769472];
        else                  v = a1pw[i - 2211840];
        WB[i] = f2b(v);
        return;
    }
    if (bid < 17408){
        long i = (long)(bid - 9216)*256 + threadIdx.x;
        if (i >= ((long)Bq*Gq*Gq >> 2)) return;
        float4 v = *(const float4*)(mask + i*4);
        ushort4 r;
        r.x = f2b(-100000.0f * v.x);
        r.y = f2b(-100000.0f * v.y);
        r.z = f2b(-100000.0f * v.z);
        r.w = f2b(-100000.0f * v.w);
        *(ushort4*)(bias16 + i*4) = r;
        return;
    }
    {
        int w = threadIdx.x >> 6, lane = threadIdx.x & 63;
        int row = (bid - 17408)*4 + w;
        if (row >= ROWS) return;
        int p = row % NSEQ; int b = row / NSEQ;
        const float* src = (p < Tq) ? (pe + (long)p*Cq)
                                    : (xin + ((long)b*Gq + (p - Tq))*Cq);
        float v[6]; float s = 0.f, s2 = 0.f;
#pragma unroll
        for (int j = 0; j < 6; j++){ float x = src[lane + 64*j]; v[j] = x; s += x; s2 += x*x; }
#pragma unroll
        for (int m = 1; m < 64; m <<= 1){ s += __shfl_xor(s, m); s2 += __shfl_xor(s2, m); }
        float mean = s * (1.f/384.f);
        float var  = s2 * (1.f/384.f) - mean*mean;
        float rs   = rsqrtf(var + 1e-5f);
        float* xrow = X + (long)row*Cq;
        u16* orow = out + (long)row*Cq;
#pragma unroll
        for (int j = 0; j < 6; j++){
            int c = lane + 64*j;
            xrow[c] = v[j];
            orow[c] = f2b((v[j] - mean) * rs * gw[c] + bw[c]);
        }
    }
}

// ---------------- LayerNorm, one wave per row, bf16 out ----------------
__global__ void __launch_bounds__(256) ln_rows(const float* __restrict__ in,
    const float* __restrict__ gw, const float* __restrict__ bw,
    u16* __restrict__ out, int rows)
{
    int w = threadIdx.x >> 6, lane = threadIdx.x & 63;
    int row = blockIdx.x*4 + w;
    if (row >= rows) return;
    const float* xr = in + (long)row*Cq;
    float v[6]; float s = 0.f, s2 = 0.f;
#pragma unroll
    for (int j = 0; j < 6; j++){ float x = xr[lane + 64*j]; v[j] = x; s += x; s2 += x*x; }
#pragma unroll
    for (int m = 1; m < 64; m <<= 1){ s += __shfl_xor(s, m); s2 += __shfl_xor(s2, m); }
    float mean = s * (1.f/384.f);
    float var  = s2 * (1.f/384.f) - mean*mean;
    float rs   = rsqrtf(var + 1e-5f);
    u16* orow = out + (long)row*Cq;
#pragma unroll
    for (int j = 0; j < 6; j++){
        int c = lane + 64*j;
        orow[c] = f2b((v[j] - mean) * rs * gw[c] + bw[c]);
    }
}

// ---------------- bf16 MFMA GEMM: C = epi(A @ W^T) ----------------
// R8-proven config: 512 threads / 8 waves (2m x 4n), 128x128 tile,
// acc[4][2]=32 AGPR, 2-buffer double-buffered gload_lds staging,
// XCD-aware bijective block remap. (7 structural variants measured worse.)
__global__ void __launch_bounds__(512, 4) gemm_bf16(const u16* __restrict__ A,
    const u16* __restrict__ W, const float* __restrict__ bias,
    float* __restrict__ Cf, u16* __restrict__ Cb, int M, int N, int K, int epi)
{
    __shared__ u16 As0[128*32];
    __shared__ u16 As1[128*32];
    __shared__ u16 Ws0[128*32];
    __shared__ u16 Ws1[128*32];
    int t = threadIdx.x;
    int nx = gridDim.x;
    int nwg = nx * gridDim.y;
    int f = blockIdx.y*nx + blockIdx.x;
    int xcd = f & 7, i = f >> 3;
    int q = nwg >> 3, r = nwg & 7;
    int base = (xcd < r) ? xcd*(q+1) : r*(q+1) + (xcd - r)*q;
    int nf = base + i;
    int m0 = (nf / nx)*128, n0 = (nf % nx)*128;
    int wv = t >> 6, lane = t & 63;
    int wm = (wv >> 2)*64, wn = (wv & 3)*32;
    int fm = lane & 15;
    int fkp = (((lane >> 4) ^ ((fm >> 1) & 3)) & 3) * 8;
    int rs  = t >> 2;
    int kc8 = (((lane & 3) ^ ((lane >> 3) & 3))) * 8;
    f32x4 acc[4][2];
#pragma unroll
    for (int ii = 0; ii < 4; ii++)
#pragma unroll
        for (int j = 0; j < 2; j++) acc[ii][j] = (f32x4){0.f,0.f,0.f,0.f};

    auto STG = [&](u16* Ab, u16* Wb, int k0){
        gload16(A + (long)(m0 + rs)*K + k0 + kc8, Ab + wv*512);
        gload16(W + (long)(n0 + rs)*K + k0 + kc8, Wb + wv*512);
    };
    auto CMP = [&](const u16* Ab, const u16* Wb){
        bf16x8 af[4], bf[2];
#pragma unroll
        for (int im = 0; im < 4; im++) af[im] = *(const bf16x8*)&Ab[(wm + im*16 + fm)*32 + fkp];
#pragma unroll
        for (int in = 0; in < 2; in++) bf[in] = *(const bf16x8*)&Wb[(wn + in*16 + fm)*32 + fkp];
#pragma unroll
        for (int im = 0; im < 4; im++)
#pragma unroll
            for (int in = 0; in < 2; in++)
                acc[im][in] = __builtin_amdgcn_mfma_f32_16x16x32_bf16(af[im], bf[in], acc[im][in], 0, 0, 0);
    };

    int nt = K >> 5;                 // 12 or 48 -> always even
    STG(As0, Ws0, 0);
    __syncthreads();
    for (int kt = 0; kt < nt; kt += 2){
        STG(As1, Ws1, (kt+1)*32);
        CMP(As0, Ws0);
        __syncthreads();
        if (kt + 2 < nt) STG(As0, Ws0, (kt+2)*32);
        CMP(As1, Ws1);
        __syncthreads();
    }

    int lr = lane >> 4, lc = lane & 15;
#pragma unroll
    for (int im = 0; im < 4; im++){
#pragma unroll
        for (int in = 0; in < 2; in++){
#pragma unroll
            for (int r2 = 0; r2 < 4; r2++){
                int m = m0 + wm + im*16 + lr*4 + r2;
                int n = n0 + wn + in*16 + lc;
                float v = acc[im][in][r2];
                if (epi >= 1 && bias) v += bias[n];
                if (epi == 2) v = gelu_f(v);
                long off = (long)m*N + n;
                if (epi == 3) v += Cf[off];
                if (epi == 2 || epi == 4) Cb[off] = f2b(v);
                else                      Cf[off] = v;
            }
        }
    }
}

// ---------------- local proj GEMM with fused pool epilogue ----------------
__global__ void __launch_bounds__(512, 4) gemm_pool(const u16* __restrict__ A,
    const u16* __restrict__ W, const float* __restrict__ bias,
    const int* __restrict__ idx, const int* __restrict__ cidx,
    const u16* __restrict__ X16, const float* __restrict__ bng,
    const float* __restrict__ bnb, float* __restrict__ vis, int K)
{
    __shared__ u16 As0[128*32];
    __shared__ u16 As1[128*32];
    __shared__ u16 Ws0[128*32];
    __shared__ u16 Ws1[128*32];
    __shared__ int idxl[128];
    __shared__ int cidxl[4];
    int t = threadIdx.x;
    int blkf = blockIdx.x;
    int xcd = blkf & 7, slot = blkf >> 3;        // 3072 -> 384 slots/xcd
    int m0 = (xcd*128 + slot/3)*128;
    int n0 = (slot % 3)*128;
    if (t < 128) idxl[t] = idx[m0 + t];
    if (t < 4)   cidxl[t] = cidx[(m0 >> 5) + t];
    int wv = t >> 6, lane = t & 63;
    int wm = (wv >> 2)*64, wn = (wv & 3)*32;
    int fm = lane & 15;
    int fkp = (((lane >> 4) ^ ((fm >> 1) & 3)) & 3) * 8;
    int rs  = t >> 2;
    int kc8 = (((lane & 3) ^ ((lane >> 3) & 3))) * 8;
    f32x4 acc[4][2];
#pragma unroll
    for (int ii = 0; ii < 4; ii++)
#pragma unroll
        for (int j = 0; j < 2; j++) acc[ii][j] = (f32x4){0.f,0.f,0.f,0.f};

    auto STG = [&](u16* Ab, u16* Wb, int k0){
        gload16(A + (long)(m0 + rs)*K + k0 + kc8, Ab + wv*512);
        gload16(W + (long)(n0 + rs)*K + k0 + kc8, Wb + wv*512);
    };
    auto CMP = [&](const u16* Ab, const u16* Wb){
        bf16x8 af[4], bf[2];
#pragma unroll
        for (int im = 0; im < 4; im++) af[im] = *(const bf16x8*)&Ab[(wm + im*16 + fm)*32 + fkp];
#pragma unroll
        for (int in = 0; in < 2; in++) bf[in] = *(const bf16x8*)&Wb[(wn + in*16 + fm)*32 + fkp];
#pragma unroll
        for (int im = 0; im < 4; im++)
#pragma unroll
            for (int in = 0; in < 2; in++)
                acc[im][in] = __builtin_amdgcn_mfma_f32_16x16x32_bf16(af[im], bf[in], acc[im][in], 0, 0, 0);
    };

    int nt = K >> 5;                 // K=384 -> 12
    STG(As0, Ws0, 0);
    __syncthreads();
    for (int kt = 0; kt < nt; kt += 2){
        STG(As1, Ws1, (kt+1)*32);
        CMP(As0, Ws0);
        __syncthreads();
        if (kt + 2 < nt) STG(As0, Ws0, (kt+2)*32);
        CMP(As1, Ws1);
        __syncthreads();
    }

    int lr = lane >> 4, lc = lane & 15;
#pragma unroll
    for (int in = 0; in < 2; in++){
        int c = n0 + wn + in*16 + lc;
        float pb = bias[c];
        float bg = bng[c], bb = bnb[c];
#pragma unroll
        for (int gl = 0; gl < 2; gl++){
            float vmax = -3e38f, vsum = 0.f;
#pragma unroll
            for (int i2 = 0; i2 < 2; i2++){
                int im = gl*2 + i2;
#pragma unroll
                for (int r = 0; r < 4; r++){
                    int rl = wm + im*16 + lr*4 + r;
                    float val = acc[im][in][r] + pb + b2f(X16[(long)idxl[rl]*Cq + c]);
                    vmax = fmaxf(vmax, val); vsum += val;
                }
            }
            vmax = fmaxf(vmax, __shfl_xor(vmax, 16)); vsum += __shfl_xor(vsum, 16);
            vmax = fmaxf(vmax, __shfl_xor(vmax, 32)); vsum += __shfl_xor(vsum, 32);
            if (lane < 16){
                int glb = (wm >> 5) + gl;
                float lcv = vmax + vsum*(1.f/32.f);
                float u = gelu_f(lcv*bg*0.9999950000374997f + bb);
                vis[((long)(m0 >> 5) + glb)*Cq + c] =
                    u + 0.4f*b2f(X16[(long)cidxl[glb]*Cq + c]);
            }
        }
    }
}

// ---------------- flash-style MFMA global attention v4 + T5 setprio ----------
__global__ void __launch_bounds__(256) attn_mfma(const u16* __restrict__ QKVg,
    const u16* __restrict__ bias16, u16* __restrict__ out)
{
    __shared__ u16 Ks[32*72];
    __shared__ u16 Vt[64*40];
    __shared__ u16 Bs[64*36];
    __shared__ u16 Pb[4][16*40];
    int blk = blockIdx.x;
    int xcd = blk & 7; int r0 = blk >> 3;
    int bb = r0 & 3;  int rr = r0 >> 2;
    int h = rr % 6;   int qt = rr / 6;
    int b = xcd + 8*bb;
    int t = threadIdx.x; int w = t >> 6; int lane = t & 63;
    int fr  = lane & 15;
    int fko = (lane >> 4) * 8;
    int colj = lane & 15;
    int rgrp = (lane >> 4) * 4;
    int qb0 = qt*64;
    int q0 = qb0 + w*16;

    int qr = q0 + fr; int qrc = qr < NSEQ ? qr : NSEQ-1;
    const u16* qbase = QKVg + (long)(b*NSEQ + qrc)*1152 + h*64;
    bf16x8 aq0 = *(const bf16x8*)(qbase + fko);
    bf16x8 aq1 = *(const bf16x8*)(qbase + 32 + fko);

    f32x4 oacc[4];
#pragma unroll
    for (int d = 0; d < 4; d++) oacc[d] = (f32x4){0.f,0.f,0.f,0.f};
    float lsum[4] = {0.f, 0.f, 0.f, 0.f};

    int skey = t >> 3;
    int sd8  = (t & 7) * 8;
    int jswz = skey ^ ((t & 3) << 3);      // (d>>3)&3 == t&3 for this thread
    int brow = t >> 2;
    int bc8  = (t & 3) * 8;

    bf16x8 kvR = {0,0,0,0,0,0,0,0}, vvR = {0,0,0,0,0,0,0,0};
    uint4  bzR = make_uint4(0u,0u,0u,0u);
    auto LD = [&](int kc){
        int j = kc*32 + skey;
        bf16x8 kv = {0,0,0,0,0,0,0,0};
        bf16x8 vv = {0,0,0,0,0,0,0,0};
        if (j < NSEQ){
            const u16* kb = QKVg + (long)(b*NSEQ + j)*1152 + 384 + h*64 + sd8;
            kv = *(const bf16x8*)kb;
            vv = *(const bf16x8*)(kb + 384);
        }
        int qi = qb0 + brow;
        int jj = kc*32 + bc8;
        uint4 bz = make_uint4(0u,0u,0u,0u);
        if (qi < Gq && jj < Gq)
            bz = *(const uint4*)(bias16 + ((long)b*Gq + qi)*Gq + jj);
        kvR = kv; vvR = vv; bzR = bz;
    };
    LD(0);

    for (int kc = 0; kc < 17; kc++){
        __syncthreads();               // prev PV done -> safe to overwrite stage
        *(bf16x8*)&Ks[skey*72 + sd8] = kvR;
#pragma unroll
        for (int e = 0; e < 8; e++) Vt[(sd8+e)*40 + jswz] = (u16)vvR[e];
        *(uint4*)&Bs[brow*36 + bc8] = bzR;
        if (kc < 16) LD(kc + 1);       // prefetch: in flight during compute
        __syncthreads();               // staged tile visible

        f32x4 s[2];
        __builtin_amdgcn_s_setprio(1);
#pragma unroll
        for (int sub = 0; sub < 2; sub++){
            bf16x8 bk0 = *(const bf16x8*)&Ks[(sub*16 + fr)*72 + fko];
            bf16x8 bk1 = *(const bf16x8*)&Ks[(sub*16 + fr)*72 + 32 + fko];
            f32x4 z = (f32x4){0.f,0.f,0.f,0.f};
            z = __builtin_amdgcn_mfma_f32_16x16x32_bf16(aq0, bk0, z, 0, 0, 0);
            z = __builtin_amdgcn_mfma_f32_16x16x32_bf16(aq1, bk1, z, 0, 0, 0);
            s[sub] = z;
        }
        __builtin_amdgcn_s_setprio(0);
#pragma unroll
        for (int sub = 0; sub < 2; sub++){
#pragma unroll
            for (int r = 0; r < 4; r++){
                int jj = kc*32 + sub*16 + colj;
                float sv = s[sub][r] * 0.125f
                         + b2f(Bs[(w*16 + rgrp + r)*36 + sub*16 + colj]);
                if (jj >= NSEQ) sv = -1e30f;
                float e = __expf(sv);
                lsum[r] += e;
                Pb[w][(rgrp + r)*40 + sub*16 + colj] = f2b(e);
            }
        }
        // no barrier: Pb[w] written and read by the same wave.
        bf16x8 ap = *(const bf16x8*)&Pb[w][fr*40 + fko];
        __builtin_amdgcn_s_setprio(1);
#pragma unroll
        for (int d = 0; d < 4; d++){
            int D = d*16 + fr;
            int fkv = fko ^ (((D >> 3) & 3) << 3);
            bf16x8 bv = *(const bf16x8*)&Vt[D*40 + fkv];
            oacc[d] = __builtin_amdgcn_mfma_f32_16x16x32_bf16(ap, bv, oacc[d], 0, 0, 0);
        }
        __builtin_amdgcn_s_setprio(0);
    }
#pragma unroll
    for (int r = 0; r < 4; r++){
#pragma unroll
        for (int mm = 1; mm < 16; mm <<= 1) lsum[r] += __shfl_xor(lsum[r], mm);
    }
#pragma unroll
    for (int r = 0; r < 4; r++){
        int qi = q0 + rgrp + r;
        if (qi < NSEQ){
            float inv = 1.0f / lsum[r];
#pragma unroll
            for (int d = 0; d < 4; d++)
                out[((long)(b*NSEQ + qi))*Cq + h*64 + d*16 + colj] = f2b(oacc[d][r]*inv);
        }
    }
}

// ---------------- fused adapter (one wave per row) ----------------
// Stage-major butterfly (R13-proven, -36us).
__global__ void __launch_bounds__(256) adapter_fused(const float* __restrict__ xfn,
    const float* __restrict__ resid,
    const float* __restrict__ dw, const float* __restrict__ db,
    const float* __restrict__ uw, const float* __restrict__ ub,
    const float* __restrict__ gatep,
    const float* __restrict__ lng, const float* __restrict__ lnb,
    float* __restrict__ Xout, u16* __restrict__ x16out,
    u16* __restrict__ ln16, int rows)
{
    int w = threadIdx.x >> 6, lane = threadIdx.x & 63;
    int row = blockIdx.x*4 + w;
    if (row >= rows) return;
    const float* xr = xfn + (long)row*Cq;
    float xv[6];
#pragma unroll
    for (int j = 0; j < 6; j++) xv[j] = xr[lane + 64*j];
    float hid[16];
#pragma unroll
    for (int rb = 0; rb < 2; rb++){
        float p[8];
#pragma unroll
        for (int rr = 0; rr < 8; rr++){
            const float* dr = dw + (rb*8 + rr)*Cq;
            float pp = 0.f;
#pragma unroll
            for (int j = 0; j < 6; j++) pp += xv[j]*dr[lane + 64*j];
            p[rr] = pp;
        }
#pragma unroll
        for (int mm = 1; mm < 64; mm <<= 1){
#pragma unroll
            for (int rr = 0; rr < 8; rr++) p[rr] += __shfl_xor(p[rr], mm);
        }
#pragma unroll
        for (int rr = 0; rr < 8; rr++) hid[rb*8 + rr] = gelu_f(p[rr] + db[rb*8 + rr]);
    }
    float gate = gatep ? gatep[0] : 1.0f;
    float ov[6];
    float s = 0.f, s2 = 0.f;
#pragma unroll
    for (int j = 0; j < 6; j++){
        int c = lane + 64*j;
        const float* uc = uw + c*16;
        float a = 0.f;
#pragma unroll
        for (int r = 0; r < 16; r++) a += hid[r]*uc[r];
        float v = gate * (a + ub[c] + xv[j]);
        if (resid) v += resid[(long)row*Cq + c];
        ov[j] = v;
        Xout[(long)row*Cq + c] = v;
        if (x16out) x16out[(long)row*Cq + c] = f2b(v);
        s += v; s2 += v*v;
    }
    if (lng){
#pragma unroll
        for (int m = 1; m < 64; m <<= 1){ s += __shfl_xor(s, m); s2 += __shfl_xor(s2, m); }
        float mean = s * (1.f/384.f);
        float var  = s2 * (1.f/384.f) - mean*mean;
        float rs   = rsqrtf(var + 1e-5f);
        u16* orow = ln16 + (long)row*Cq;
#pragma unroll
        for (int j = 0; j < 6; j++){
            int c = lane + 64*j;
            orow[c] = f2b((ov[j] - mean)*rs*lng[c] + lnb[c]);
        }
    }
}

// ---------------- local branch: MFMA attention + T5 setprio ------------------
__global__ void __launch_bounds__(256) local_attn(const u16* __restrict__ QKVg,
    const int* __restrict__ idx, u16* __restrict__ aout16)
{
    __shared__ u16 Qs[32*72];
    __shared__ u16 Ksm[32*72];
    __shared__ u16 Vt[64*40];
    __shared__ float sc[32*36];
    __shared__ u16 Pa[32*40];
    __shared__ float linv[32];
    __shared__ int rows[32];
    int g = blockIdx.x;
    int t = threadIdx.x;
    int w = t >> 6, lane = t & 63;
    if (t < 32) rows[t] = idx[g*Kg + t];
    __syncthreads();
    int srow = t & 31;
    int d8   = (t >> 5) * 8;
    int jswz = srow ^ (((t >> 5) & 3) << 3);   // (d>>3)&3 == (t>>5)&3
    int fr = lane & 15, fko = (lane >> 4)*8;
    int colj = lane & 15, rgrp = (lane >> 4)*4;
    int it = w >> 1, jt = w & 1;
    int smrow = w*8 + (lane >> 3);
    int smc   = (lane & 7) * 4;

    const u16* rbase = QKVg + (long)rows[srow]*1152 + d8;
    bf16x8 qvR = *(const bf16x8*)(rbase);
    bf16x8 kvR = *(const bf16x8*)(rbase + 384);
    bf16x8 vvR = *(const bf16x8*)(rbase + 768);

    for (int h = 0; h < Hq; h++){
        *(bf16x8*)&Qs[srow*72 + d8]  = qvR;
        *(bf16x8*)&Ksm[srow*72 + d8] = kvR;
#pragma unroll
        for (int e = 0; e < 8; e++) Vt[(d8+e)*40 + jswz] = (u16)vvR[e];
        if (h < Hq-1){
            const u16* nb = rbase + (h+1)*64;
            qvR = *(const bf16x8*)(nb);
            kvR = *(const bf16x8*)(nb + 384);
            vvR = *(const bf16x8*)(nb + 768);
        }
        __syncthreads();
        {
            bf16x8 a0 = *(const bf16x8*)&Qs[(it*16+fr)*72 + fko];
            bf16x8 a1 = *(const bf16x8*)&Qs[(it*16+fr)*72 + 32 + fko];
            bf16x8 b0 = *(const bf16x8*)&Ksm[(jt*16+fr)*72 + fko];
            bf16x8 b1 = *(const bf16x8*)&Ksm[(jt*16+fr)*72 + 32 + fko];
            __builtin_amdgcn_s_setprio(1);
            f32x4 z = (f32x4){0.f,0.f,0.f,0.f};
            z = __builtin_amdgcn_mfma_f32_16x16x32_bf16(a0, b0, z, 0, 0, 0);
            z = __builtin_amdgcn_mfma_f32_16x16x32_bf16(a1, b1, z, 0, 0, 0);
            __builtin_amdgcn_s_setprio(0);
#pragma unroll
            for (int r = 0; r < 4; r++)
                sc[(it*16 + rgrp + r)*36 + jt*16 + colj] = z[r]*0.125f;
        }
        __syncthreads();
        {
            float4 s4 = *(const float4*)&sc[smrow*36 + smc];
            float mx = fmaxf(fmaxf(s4.x, s4.y), fmaxf(s4.z, s4.w));
#pragma unroll
            for (int mm = 1; mm < 8; mm <<= 1) mx = fmaxf(mx, __shfl_xor(mx, mm));
            float p0 = __expf(s4.x - mx), p1 = __expf(s4.y - mx);
            float p2 = __expf(s4.z - mx), p3 = __expf(s4.w - mx);
            float sm = p0 + p1 + p2 + p3;
#pragma unroll
            for (int mm = 1; mm < 8; mm <<= 1) sm += __shfl_xor(sm, mm);
            if ((lane & 7) == 0) linv[smrow] = 1.0f / sm;
            Pa[smrow*40 + smc + 0] = f2b(p0);
            Pa[smrow*40 + smc + 1] = f2b(p1);
            Pa[smrow*40 + smc + 2] = f2b(p2);
            Pa[smrow*40 + smc + 3] = f2b(p3);
        }
        __syncthreads();
        {
            bf16x8 ap = *(const bf16x8*)&Pa[(it*16+fr)*40 + fko];
            __builtin_amdgcn_s_setprio(1);
            f32x4 o0 = (f32x4){0.f,0.f,0.f,0.f};
            f32x4 o1 = (f32x4){0.f,0.f,0.f,0.f};
            {
                int dt = jt;
                int D = dt*16 + fr;
                int fkv = fko ^ (((D >> 3) & 3) << 3);
                bf16x8 bv = *(const bf16x8*)&Vt[D*40 + fkv];
                o0 = __builtin_amdgcn_mfma_f32_16x16x32_bf16(ap, bv, o0, 0, 0, 0);
            }
            {
                int dt = jt + 2;
                int D = dt*16 + fr;
                int fkv = fko ^ (((D >> 3) & 3) << 3);
                bf16x8 bv = *(const bf16x8*)&Vt[D*40 + fkv];
                o1 = __builtin_amdgcn_mfma_f32_16x16x32_bf16(ap, bv, o1, 0, 0, 0);
            }
            __builtin_amdgcn_s_setprio(0);
#pragma unroll
            for (int r = 0; r < 4; r++){
                int row = it*16 + rgrp + r;
                aout16[((long)(g*32 + row))*Cq + h*64 + jt*16 + colj] =
                    f2b(o0[r] * linv[row]);
                aout16[((long)(g*32 + row))*Cq + h*64 + (jt+2)*16 + colj] =
                    f2b(o1[r] * linv[row]);
            }
        }
        __syncthreads();
    }
}

// ---------------- inverse-distance interp: 8 points/block share vis reads ----
__global__ void __launch_bounds__(128) interp_k(const float* __restrict__ Xf,
    const float* __restrict__ vis, const float* __restrict__ c1,
    const float* __restrict__ c2, float* __restrict__ newx)
{
    __shared__ float wsh[8*128];
    __shared__ float inv8[8];
    int blk = blockIdx.x;
    int b = blk >> 6, nt = blk & 63;
    int tid = threadIdx.x;
#pragma unroll
    for (int i = 0; i < 8; i++){
        int id = tid + i*128;
        int nl = id >> 7, s = id & 127;
        const float* p1 = c1 + ((long)b*Gq + nt*8 + nl)*3;
        const float* p2 = c2 + ((long)b*Sq + s)*3;
        float x1 = p1[0], y1 = p1[1], z1 = p1[2];
        float x2 = p2[0], y2 = p2[1], z2 = p2[2];
        float d = (x1*x1 + y1*y1 + z1*z1) + (x2*x2 + y2*y2 + z2*z2)
                - 2.f*(x1*x2 + y1*y2 + z1*z2);
        wsh[nl*128 + s] = 1.f/(d + 1e-8f);
    }
    __syncthreads();
    if (tid < 8){
        float sum = 0.f;
        for (int s = 0; s < Sq; s++) sum += wsh[tid*128 + s];
        inv8[tid] = 1.f/sum;
    }
    __syncthreads();
    float acc[8][3];
#pragma unroll
    for (int n = 0; n < 8; n++){ acc[n][0] = 0.f; acc[n][1] = 0.f; acc[n][2] = 0.f; }
    const float* vb = vis + (long)b*Sq*Cq + tid;
    for (int s = 0; s < Sq; s++){
        float v0 = vb[s*Cq], v1 = vb[s*Cq + 128], v2 = vb[s*Cq + 256];
#pragma unroll
        for (int n = 0; n < 8; n++){
            float wq = wsh[n*128 + s];
            acc[n][0] += wq*v0; acc[n][1] += wq*v1; acc[n][2] += wq*v2;
        }
    }
#pragma unroll
    for (int n = 0; n < 8; n++){
        int gn = nt*8 + n;
        const float* xr = Xf + ((long)(b*NSEQ + Tq + gn))*Cq;
        float* orow = newx + ((long)(b*Gq + gn))*Cq;
        float sf = 0.4f * inv8[n];
        orow[tid]       = xr[tid]       + sf*acc[n][0];
        orow[tid + 128] = xr[tid + 128] + sf*acc[n][1];
        orow[tid + 256] = xr[tid + 256] + sf*acc[n][2];
    }
}

// ---------------- launch ----------------
extern "C" void kernel_launch(void* const* d_in, const int* in_sizes, int n_in,
                              void* d_out, int out_size, void* d_ws, size_t ws_size,
                              hipStream_t stream)
{
    const float* x_in  = (const float*)d_in[0];
    const float* mask  = (const float*)d_in[1];
    const float* c1p   = (const float*)d_in[2];
    const float* c2p   = (const float*)d_in[3];
    const float* pe    = (const float*)d_in[5];
    const float* n1g   = (const float*)d_in[6];
    const float* n1b   = (const float*)d_in[7];
    const float* qkvw  = (const float*)d_in[8];
    const float* projw = (const float*)d_in[9];
    const float* projb = (const float*)d_in[10];
    const float* n2g   = (const float*)d_in[11];
    const float* n2b   = (const float*)d_in[12];
    const float* fc1w  = (const float*)d_in[13];
    const float* fc1b  = (const float*)d_in[14];
    const float* fc2w  = (const float*)d_in[15];
    const float* fc2b  = (const float*)d_in[16];
    const float* gate  = (const float*)d_in[17];
    const float* addw  = (const float*)d_in[18];
    const float* addb  = (const float*)d_in[19];
    const float* aduw  = (const float*)d_in[20];
    const float* adub  = (const float*)d_in[21];
    const float* ad1dw = (const float*)d_in[22];
    const float* ad1db = (const float*)d_in[23];
    const float* ad1uw = (const float*)d_in[24];
    const float* ad1ub = (const float*)d_in[25];
    const float* bng   = (const float*)d_in[26];
    const float* bnb   = (const float*)d_in[27];
    const float* a1qkvw= (const float*)d_in[28];
    const float* a1pw  = (const float*)d_in[29];
    const float* a1pb  = (const float*)d_in[30];
    const float* n3g   = (const float*)d_in[31];
    const float* n3b   = (const float*)d_in[32];
    const int*   idxp  = (const int*)d_in[33];
    const int*   cidxp = (const int*)d_in[34];

    // ---- workspace layout (bytes), total 252.4 MB ----
    char* w = (char*)d_ws;
    float* X    = (float*)w;                       // 16896x384 f32   [0, 25952256)
    u16*   WB   = (u16*)(w + 25952256);            // bf16 weights
    u16*   Bb16 = (u16*)(w + 30670848);            // 16896x384 bf16
    char*  R1   = w + 43646976;                    // 100663296 B (bias16 / hid16 / aout16)
    char*  R2   = R1 + 100663296;                  // 100663296 B (QKVg/C1/newx + X16)
    float* V    = (float*)(R2 + 100663296);        // 4096x384 f32

    u16* qkvw16  = WB;
    u16* projw16 = WB +  442368;
    u16* fc1w16  = WB +  589824;
    u16* fc2w16  = WB + 1179648;
    u16* a1qkv16 = WB + 1769472;
    u16* a1pw16  = WB + 2211840;

    u16*   bias16 = (u16*)R1;       // 32x512x512 bf16 (dead before fc1)
    u16*   hid16  = (u16*)R1;       // 16896x1536 bf16 (MLP phase)
    u16*   aout16 = (u16*)R1;       // 131072x384 bf16 (local phase)
    u16*   QKVg   = (u16*)R2;       // 16896x1152 bf16 [R2, R2+38.9MB)
    float* C1     = (float*)R2;     // 16896x384 f32 x_fn (dead after adapter#1)
    float* newx   = (float*)R2;     // 16384x384 f32 (interp out; QKVg dead then)
    u16*   X16    = (u16*)(R2 + 41943040);  // 16896x384 bf16 [40MB, 53MB) of R2

    prep<<<21632, 256, 0, stream>>>(qkvw, projw, fc1w, fc2w, a1qkvw, a1pw, WB,
                                    mask, bias16, x_in, pe, n1g, n1b, X, Bb16);
    gemm_bf16<<<dim3(9, 132), 512, 0, stream>>>(Bb16, qkvw16, nullptr, nullptr, QKVg,
                                                ROWS, 1152, Cq, 4);
    attn_mfma<<<1728, 256, 0, stream>>>(QKVg, bias16, Bb16);
    gemm_bf16<<<dim3(3, 132), 512, 0, stream>>>(Bb16, projw16, projb, X, nullptr,
                                                ROWS, Cq, Cq, 3);
    ln_rows<<<4224, 256, 0, stream>>>(X, n2g, n2b, Bb16, ROWS);
    gemm_bf16<<<dim3(12, 132), 512, 0, stream>>>(Bb16, fc1w16, fc1b, nullptr, hid16,
                                                 ROWS, 1536, Cq, 2);
    gemm_bf16<<<dim3(3, 132), 512, 0, stream>>>(hid16, fc2w16, fc2b, C1, nullptr,
                                                ROWS, Cq, 1536, 1);
    // fused: x = gate*adapter(x_fn)+x ; X16 = bf16(x); Bb16 = LN3(x)
    adapter_fused<<<4224, 256, 0, stream>>>(C1, X, addw, addb, aduw, adub, gate,
                                            n3g, n3b, X, X16, Bb16, ROWS);
    // local branch
    gemm_bf16<<<dim3(9, 132), 512, 0, stream>>>(Bb16, a1qkv16, nullptr, nullptr, QKVg,
                                                ROWS, 1152, Cq, 4);
    local_attn<<<4096, 256, 0, stream>>>(QKVg, idxp, aout16);
    gemm_pool<<<3072, 512, 0, stream>>>(aout16, a1pw16, a1pb, idxp, cidxp,
                                        X16, bng, bnb, V, Cq);
    interp_k<<<2048, 128, 0, stream>>>(X, V, c1p, c2p, newx);
    // fused final adapter -> d_out
    adapter_fused<<<4096, 256, 0, stream>>>(newx, nullptr, ad1dw, ad1db, ad1uw, ad1ub,
                                            nullptr, nullptr, nullptr,
                                            (float*)d_out, nullptr, nullptr, Bq*Gq);
}